// Round 10
// baseline (397.416 us; speedup 1.0000x reference)
//
#include <hip/hip_runtime.h>
#include <stdint.h>

// ---------- device globals: dtype flag + BN stats ----------
__device__ int   g_isf32;
__device__ float g_stats[512];  // [0:128) s1sum, [128:256) s1sq, [256:384) s2sum, [384:512) s2sq

typedef __attribute__((ext_vector_type(8))) short bf16x8;
typedef __attribute__((ext_vector_type(4))) float f32x4;

// ---------- bf16 helpers ----------
__device__ __forceinline__ float bf2f(unsigned short u) {
  union { unsigned int i; float f; } v; v.i = ((unsigned int)u) << 16; return v.f;
}
__device__ __forceinline__ unsigned short f2bf(float f) {
  union { float f; unsigned int i; } v; v.f = f;
  unsigned int r = v.i + 0x7FFFu + ((v.i >> 16) & 1u);
  return (unsigned short)(r >> 16);
}
__device__ __forceinline__ unsigned int pk2(float a, float b) {
  return (unsigned int)f2bf(a) | ((unsigned int)f2bf(b) << 16);
}
// dtype-flex input load: f ? fp32 : bf16
__device__ __forceinline__ float ldi(const void* p, size_t i, int f) {
  return f ? ((const float*)p)[i] : bf2f(((const unsigned short*)p)[i]);
}

// ---------- K0: dtype detector + stats zeroing ----------
__global__ void k_detect(const unsigned short* __restrict__ x) {
  __shared__ int cnt;
  const int t = threadIdx.x;
  if (t == 0) cnt = 0;
  g_stats[t] = 0.f; g_stats[t + 256] = 0.f;
  __syncthreads();
  int c = 0;
  for (int j = 0; j < 16; j++) {
    unsigned short u = x[t * 16 + j];
    int e = (u >> 7) & 0xFF;
    if (e == 0xFF || (e != 0 && e <= 100)) c++;
  }
  atomicAdd(&cnt, c);
  __syncthreads();
  if (t == 0) g_isf32 = (cnt > 256) ? 1 : 0;
}

// ---------- K_prep: weights -> GEMM-friendly layouts ----------
// jobs: wdcnT 294912 | wctT 262144 | woffT 62208 | wdcnA 294912 | woffA 73728
__global__ void k_prep(const void* __restrict__ w_dcn, const void* __restrict__ w_ct,
                       const void* __restrict__ w_off,
                       float* __restrict__ wdcnT, float* __restrict__ wctT,
                       float* __restrict__ woffT, unsigned short* __restrict__ wdcnA,
                       unsigned short* __restrict__ woffA) {
  const int f = g_isf32;
  int idx = blockIdx.x * 256 + threadIdx.x;
  if (idx < 294912) {
    int k = idx / 32768, c = (idx >> 7) & 255, o = idx & 127;
    wdcnT[idx] = ldi(w_dcn, (size_t)(o * 256 + c) * 9 + k, f);
  }
  int i2 = idx - 294912;
  if (i2 >= 0 && i2 < 262144) {
    int kr = i2 >> 16, kc = (i2 >> 14) & 3, i = (i2 >> 7) & 127, o = i2 & 127;
    wctT[i2] = ldi(w_ct, (size_t)((i * 128 + o) * 4 + kr) * 4 + kc, f);
  }
  int i3 = idx - (294912 + 262144);
  if (i3 >= 0 && i3 < 62208) {
    int ci = i3 / 243, r = i3 - ci * 243, k = r / 27, c = r - (r / 27) * 27;
    woffT[i3] = ldi(w_off, (size_t)(c * 256 + ci) * 9 + k, f);
  }
  int i4 = idx - 619264;
  if (i4 >= 0 && i4 < 294912) {
    int o = i4 / 2304, rem = i4 - o * 2304;
    int k = rem >> 8, c = rem & 255;
    wdcnA[i4] = f2bf(ldi(w_dcn, (size_t)(o * 256 + c) * 9 + k, f));
  }
  int i5 = idx - 914176;
  if (i5 >= 0 && i5 < 73728) {       // woffA[m=32][k = tap*256 + ci] bf16, m>=27 zero
    int m = i5 / 2304, r = i5 - m * 2304;
    int tap = r >> 8, ci = r & 255;
    float v = (m < 27) ? ldi(w_off, (size_t)(m * 256 + ci) * 9 + tap, f) : 0.f;
    woffA[i5] = f2bf(v);
  }
}

// ---------- K_prep2: parity-decomposed ct-conv A matrices (fast path only) ----------
// Apar[par][o][tap*128 + i] bf16, par = py*2+px, tap = a*2+b
__global__ void k_prep2(const float* __restrict__ wctT, unsigned short* __restrict__ Apar) {
  int idx = blockIdx.x * 256 + threadIdx.x;   // 262144
  int par = idx >> 16, rem = idx & 65535;
  int o = rem >> 9, rem2 = rem & 511;
  int tap = rem2 >> 7, i = rem2 & 127;
  int py = par >> 1, px = par & 1, a = tap >> 1, bb = tap & 1;
  int kr = (py == 0) ? (a ? 3 : 1) : (a ? 2 : 0);
  int kc = (px == 0) ? (bb ? 3 : 1) : (bb ? 2 : 0);
  Apar[idx] = f2bf(wctT[((size_t)(kr * 4 + kc) * 128 + i) * 128 + o]);
}

// ---------- K_xt: x (NCHW) -> xT[b][h][w][256] bf16 (channel-last) ----------
// grid (64 h, 4 cq, 8 b); 64x64 LDS transpose tile (k_bn1t pattern).
__global__ __launch_bounds__(256) void k_xt(const void* __restrict__ x,
                                            unsigned short* __restrict__ xT) {
  const int f = g_isf32;
  const int h = blockIdx.x, cq = blockIdx.y, b = blockIdx.z;
  const int t = threadIdx.x;
  __shared__ unsigned short T[64][72];
  {
    int cl = t >> 2, q = t & 3;
    size_t base = ((size_t)((b * 256 + cq * 64 + cl) * 64 + h) << 6) + q * 16;
    unsigned short r[16];
    if (f) {
      const float4* p = (const float4*)((const float*)x + base);
      float4 v0 = p[0], v1 = p[1], v2 = p[2], v3 = p[3];
      float vv[16] = {v0.x, v0.y, v0.z, v0.w, v1.x, v1.y, v1.z, v1.w,
                      v2.x, v2.y, v2.z, v2.w, v3.x, v3.y, v3.z, v3.w};
#pragma unroll
      for (int j = 0; j < 16; j++) r[j] = f2bf(vv[j]);
    } else {
      const unsigned short* p = (const unsigned short*)x + base;
      *(uint4*)&r[0] = *(const uint4*)p;
      *(uint4*)&r[8] = *(const uint4*)(p + 8);
    }
    *(uint4*)&T[cl][q * 16]     = *(uint4*)&r[0];
    *(uint4*)&T[cl][q * 16 + 8] = *(uint4*)&r[8];
  }
  __syncthreads();
  {
    int pl = t >> 2, qc = t & 3;
    unsigned short r[16];
#pragma unroll
    for (int j = 0; j < 16; j++) r[j] = T[qc * 16 + j][pl];
    unsigned short* op = xT + ((size_t)((b * 64 + h) * 64 + pl) << 8) + cq * 64 + qc * 16;
    *(uint4*)op       = *(uint4*)&r[0];
    *(uint4*)(op + 8) = *(uint4*)&r[8];
  }
}

// ---------- K1 (fast): offset conv as MFMA GEMM ----------
// om[27][4096] = woffA[32][2304] x im2col(x).  grid (64 h, 8 b), 4 waves.
__global__ __launch_bounds__(256) void k_offmfma(
    const unsigned short* __restrict__ xT,
    const unsigned short* __restrict__ woffA,
    const void* __restrict__ b_off, float* __restrict__ om) {
  const int f = g_isf32;
  const int h = blockIdx.x, b = blockIdx.y;
  const int t = threadIdx.x;
  const int wv = t >> 6, L = t & 63, quad = L >> 4, l15 = L & 15;
  __shared__ unsigned short Bs[3][66][40];   // [row h-1..h+1][w-pad -1..64][ci 32 pad40]
  f32x4 acc[2] = {};
  const int sl = t >> 6, sw = t & 63;        // staging assignment (t<192)

  for (int cq = 0; cq < 8; cq++) {
    __syncthreads();
    if (t < 192) {
      int row = h - 1 + sl;
      uint4 q0 = make_uint4(0, 0, 0, 0), q1 = q0, q2 = q0, q3 = q0;
      if (row >= 0 && row < 64) {
        const unsigned short* src = xT + ((size_t)((b * 64 + row) * 64 + sw) << 8) + cq * 32;
        q0 = *(const uint4*)(src);
        q1 = *(const uint4*)(src + 8);
        q2 = *(const uint4*)(src + 16);
        q3 = *(const uint4*)(src + 24);
      }
      unsigned short* d = &Bs[sl][sw + 1][0];
      *(uint4*)(d)      = q0; *(uint4*)(d + 8)  = q1;
      *(uint4*)(d + 16) = q2; *(uint4*)(d + 24) = q3;
    } else if (t < 198) {
      int idx = t - 192;
      int zs = idx >> 1, zc = (idx & 1) ? 65 : 0;
      unsigned short* d = &Bs[zs][zc][0];
      uint4 z = make_uint4(0, 0, 0, 0);
      *(uint4*)(d) = z; *(uint4*)(d + 8) = z; *(uint4*)(d + 16) = z; *(uint4*)(d + 24) = z;
    }
    __syncthreads();
#pragma unroll
    for (int tap = 0; tap < 9; tap++) {
      const int dy = tap / 3, dx = tap - dy * 3;
      const int kb = tap * 256 + cq * 32 + quad * 8;
      bf16x8 a0 = *(const bf16x8*)(woffA + (size_t)l15 * 2304 + kb);
      bf16x8 a1 = *(const bf16x8*)(woffA + (size_t)(l15 + 16) * 2304 + kb);
      bf16x8 bv = *(const bf16x8*)&Bs[dy][wv * 16 + l15 + dx][quad * 8];
      acc[0] = __builtin_amdgcn_mfma_f32_16x16x32_bf16(a0, bv, acc[0], 0, 0, 0);
      acc[1] = __builtin_amdgcn_mfma_f32_16x16x32_bf16(a1, bv, acc[1], 0, 0, 0);
    }
  }
  const int w = wv * 16 + l15;
#pragma unroll
  for (int tm = 0; tm < 2; tm++) {
#pragma unroll
    for (int r = 0; r < 4; r++) {
      int m = tm * 16 + quad * 4 + r;
      if (m < 27) {
        float bo = ldi(b_off, m, f);
        om[(size_t)((b * 27 + m) * 64 + h) * 64 + w] = acc[tm][r] + bo;
      }
    }
  }
}

// ---------- K1 fallback: 3x3 offset conv, pad 1.  om (8,27,64,64) fp32 ----------
__global__ __launch_bounds__(256) void k_offconv(
    const void* __restrict__ x, const void* __restrict__ b_off,
    const float* __restrict__ woffT, float* __restrict__ om) {
  const int f = g_isf32;
  const int h = blockIdx.x, b = blockIdx.y;
  const int t = threadIdx.x;
  const int cg = t & 31, wg = t >> 5;
  const int w0 = wg * 8;
  __shared__ float xs[32 * 204];
  float acc[8];
#pragma unroll
  for (int i = 0; i < 8; i++) acc[i] = 0.f;

  for (int cb = 0; cb < 256; cb += 32) {
    __syncthreads();
    for (int e = t; e < 32 * 192; e += 256) {
      int ci = e / 192, r = e - ci * 192;
      int dh = r >> 6, w = r & 63;
      int row = h + dh - 1;
      float v = 0.f;
      if (row >= 0 && row < 64)
        v = ldi(x, ((size_t)((b * 256 + cb + ci) * 64 + row) << 6) + w, f);
      xs[ci * 204 + dh * 68 + w + 1] = v;
    }
    for (int e = t; e < 96; e += 256) {
      int base = (e / 3) * 204 + (e - (e / 3) * 3) * 68;
      xs[base] = 0.f; xs[base + 65] = 0.f; xs[base + 66] = 0.f; xs[base + 67] = 0.f;
    }
    __syncthreads();

    for (int ci = 0; ci < 32; ci++) {
      float xr[3][12];
#pragma unroll
      for (int dh = 0; dh < 3; dh++) {
        const float* p = &xs[ci * 204 + dh * 68 + w0];
        float4 q0 = *(const float4*)(p);
        float4 q1 = *(const float4*)(p + 4);
        float4 q2 = *(const float4*)(p + 8);
        xr[dh][0] = q0.x; xr[dh][1] = q0.y; xr[dh][2] = q0.z; xr[dh][3] = q0.w;
        xr[dh][4] = q1.x; xr[dh][5] = q1.y; xr[dh][6] = q1.z; xr[dh][7] = q1.w;
        xr[dh][8] = q2.x; xr[dh][9] = q2.y; xr[dh][10] = q2.z; xr[dh][11] = q2.w;
      }
      if (cg < 27) {
        const float* wp = &woffT[(size_t)(cb + ci) * 243 + cg];
#pragma unroll
        for (int k = 0; k < 9; k++) {
          float wk = wp[k * 27];
          const int dh = k / 3, dx = k - (k / 3) * 3;
#pragma unroll
          for (int wi = 0; wi < 8; wi++)
            acc[wi] = fmaf(wk, xr[dh][wi + dx], acc[wi]);
        }
      }
    }
  }
  if (cg < 27) {
    float bo = ldi(b_off, cg, f);
    float* op = &om[(size_t)((b * 27 + cg) * 64 + h) * 64 + w0];
#pragma unroll
    for (int wi = 0; wi < 8; wi++) op[wi] = acc[wi] + bo;
  }
}

// ---------- K2 (fast): FUSED deformable sampling + MFMA GEMM, v3 ----------
// h1[b](128,4096) = wdcnA(128,2304) x S_virtual(2304,4096).  grid (8 b, 128 nt).
// v3: A-fragments loaded DIRECTLY from global (L2-hot, block-invariant) with
// 1-step register prefetch -> As LDS staging eliminated; Bs double-buffered
// (2x32x40, 5KB) -> ONE barrier per K-step (72 vs 144).
__global__ __launch_bounds__(256) void k_dcnf(
    const unsigned short* __restrict__ xT,   // [b][64][64][256] bf16
    const unsigned short* __restrict__ A,    // wdcnA [128][2304] bf16
    const float* __restrict__ om,            // [b][27][4096] f32
    const void* __restrict__ b_dcn,
    unsigned short* __restrict__ h1) {       // [b][128][4096] bf16
  const int f = g_isf32;
  const int b = blockIdx.x, nt = blockIdx.y;   // b fastest -> XCD pinning
  const int t = threadIdx.x;
  const int wv = t >> 6, L = t & 63, quad = L >> 4, l15 = L & 15;
  const int wm = wv * 32;                      // wave's 32 output-channel rows
  __shared__ unsigned short Bs[2][32][40];     // double-buffered [pos][k pad40]
  __shared__ float          Wg[9][32][4];
  __shared__ unsigned short Wi[9][32][4];
  f32x4 acc[2][2] = {};
  const int p0 = nt * 32;

  // precompute per-(tap, pos) bilinear weights + clamped corner indices
  for (int e = t; e < 9 * 32; e += 256) {
    int k = e >> 5, p = e & 31;
    int pos = p0 + p;
    int hh = pos >> 6, ww = pos & 63;
    const float* ob = om + (size_t)(b * 27) * 4096 + pos;
    float oy = ob[(size_t)k * 4096];
    float ox = ob[(size_t)(k + 9) * 4096];
    float mm = ob[(size_t)(k + 18) * 4096];
    float msk = 1.f / (1.f + expf(-mm));
    float py = oy + (float)(hh - 1 + k / 3);
    float px = ox + (float)(ww - 1 + (k - (k / 3) * 3));
    float y0f = floorf(py), x0f = floorf(px);
    float ly = py - y0f, lx = px - x0f;
    int y0 = (int)y0f, x0 = (int)x0f;
    int y1 = y0 + 1, x1 = x0 + 1;
    float fy0 = (y0 >= 0 && y0 < 64) ? 1.f : 0.f;
    float fy1 = (y1 >= 0 && y1 < 64) ? 1.f : 0.f;
    float fx0 = (x0 >= 0 && x0 < 64) ? 1.f : 0.f;
    float fx1 = (x1 >= 0 && x1 < 64) ? 1.f : 0.f;
    int y0c = min(max(y0, 0), 63), y1c = min(max(y1, 0), 63);
    int x0c = min(max(x0, 0), 63), x1c = min(max(x1, 0), 63);
    Wg[k][p][0] = (1.f - ly) * (1.f - lx) * msk * fy0 * fx0;
    Wg[k][p][1] = (1.f - ly) * lx * msk * fy0 * fx1;
    Wg[k][p][2] = ly * (1.f - lx) * msk * fy1 * fx0;
    Wg[k][p][3] = ly * lx * msk * fy1 * fx1;
    Wi[k][p][0] = (unsigned short)(y0c * 64 + x0c);
    Wi[k][p][1] = (unsigned short)(y0c * 64 + x1c);
    Wi[k][p][2] = (unsigned short)(y1c * 64 + x0c);
    Wi[k][p][3] = (unsigned short)(y1c * 64 + x1c);
  }
  __syncthreads();   // Wg/Wi ready before first prefetch

  const unsigned short* xb = xT + ((size_t)b << 20);   // b * 4096 * 256
  const int sp = t >> 3, qc8 = t & 7;                  // pos 0..31, 4-ch segment
  const unsigned short* arow0 = A + (size_t)(wm + l15) * 2304 + quad * 8;
  const unsigned short* arow1 = A + (size_t)(wm + 16 + l15) * 2304 + quad * 8;

  // pipeline registers
  bf16x8 pa0, pa1, a0c, a1c;
  uint2 pu0, pu1, pu2, pu3;
  float4 pg;

#define DCNF_ISSUE(S) {                                                   \
    int tap_ = (S) >> 3, cq_ = (S) & 7;                                   \
    int kb_ = tap_ * 256 + cq_ * 32;                                      \
    pa0 = *(const bf16x8*)(arow0 + kb_);                                  \
    pa1 = *(const bf16x8*)(arow1 + kb_);                                  \
    pg  = *(const float4*)&Wg[tap_][sp][0];                               \
    uint2 wi2_ = *(const uint2*)&Wi[tap_][sp][0];                         \
    int i0_ = wi2_.x & 0xffff, i1_ = wi2_.x >> 16;                        \
    int i2_ = wi2_.y & 0xffff, i3_ = wi2_.y >> 16;                        \
    int cb_ = cq_ * 32 + qc8 * 4;                                         \
    pu0 = *(const uint2*)(xb + ((size_t)i0_ << 8) + cb_);                 \
    pu1 = *(const uint2*)(xb + ((size_t)i1_ << 8) + cb_);                 \
    pu2 = *(const uint2*)(xb + ((size_t)i2_ << 8) + cb_);                 \
    pu3 = *(const uint2*)(xb + ((size_t)i3_ << 8) + cb_);                 \
  }

#define DCNF_COMBINE(BUF) {                                               \
    unsigned short e0[4], e1[4], e2[4], e3[4];                            \
    *(uint2*)e0 = pu0; *(uint2*)e1 = pu1;                                 \
    *(uint2*)e2 = pu2; *(uint2*)e3 = pu3;                                 \
    float g0 = pg.x, g1 = pg.y, g2 = pg.z, g3 = pg.w;                     \
    unsigned int r0_, r1_;                                                \
    {                                                                     \
      float va = g0 * bf2f(e0[0]) + g1 * bf2f(e1[0])                      \
               + g2 * bf2f(e2[0]) + g3 * bf2f(e3[0]);                     \
      float vb = g0 * bf2f(e0[1]) + g1 * bf2f(e1[1])                      \
               + g2 * bf2f(e2[1]) + g3 * bf2f(e3[1]);                     \
      r0_ = pk2(va, vb);                                                  \
    }                                                                     \
    {                                                                     \
      float va = g0 * bf2f(e0[2]) + g1 * bf2f(e1[2])                      \
               + g2 * bf2f(e2[2]) + g3 * bf2f(e3[2]);                     \
      float vb = g0 * bf2f(e0[3]) + g1 * bf2f(e1[3])                      \
               + g2 * bf2f(e2[3]) + g3 * bf2f(e3[3]);                     \
      r1_ = pk2(va, vb);                                                  \
    }                                                                     \
    *(uint2*)&Bs[BUF][sp][qc8 * 4] = make_uint2(r0_, r1_);                \
  }

  // prologue: fill buffer 0, prefetch step 1
  DCNF_ISSUE(0);
  a0c = pa0; a1c = pa1;
  DCNF_COMBINE(0);
  DCNF_ISSUE(1);
  __syncthreads();

  for (int s = 0; s < 72; s++) {
    const int cur = s & 1;
    bf16x8 b0 = *(const bf16x8*)&Bs[cur][l15][quad * 8];
    bf16x8 b1 = *(const bf16x8*)&Bs[cur][16 + l15][quad * 8];
    acc[0][0] = __builtin_amdgcn_mfma_f32_16x16x32_bf16(a0c, b0, acc[0][0], 0, 0, 0);
    acc[0][1] = __builtin_amdgcn_mfma_f32_16x16x32_bf16(a0c, b1, acc[0][1], 0, 0, 0);
    acc[1][0] = __builtin_amdgcn_mfma_f32_16x16x32_bf16(a1c, b0, acc[1][0], 0, 0, 0);
    acc[1][1] = __builtin_amdgcn_mfma_f32_16x16x32_bf16(a1c, b1, acc[1][1], 0, 0, 0);
    if (s < 71) {
      a0c = pa0; a1c = pa1;      // A frags for step s+1 (prefetched)
      DCNF_COMBINE(cur ^ 1);     // B tile for step s+1 from prefetched corners
      if (s < 70) DCNF_ISSUE(s + 2);
    }
    __syncthreads();             // single barrier per K-step
  }
#undef DCNF_ISSUE
#undef DCNF_COMBINE

#pragma unroll
  for (int tm = 0; tm < 2; tm++) {
#pragma unroll
    for (int r = 0; r < 4; r++) {
      int m = wm + tm * 16 + quad * 4 + r;
      float bd = ldi(b_dcn, m, f);
#pragma unroll
      for (int tn = 0; tn < 2; tn++) {
        float v = acc[tm][tn][r] + bd;
        int n = p0 + tn * 16 + l15;
        h1[(size_t)(b * 128 + m) * 4096 + n] = f2bf(v);
      }
    }
  }
}

// ---------- K_stats1: per-channel sum/sumsq of h1 -> g_stats[0..255] ----------
__global__ __launch_bounds__(256) void k_stats1(const unsigned short* __restrict__ h1) {
  const int m = blockIdx.x, b = blockIdx.y;
  const int t = threadIdx.x;
  const unsigned short* p = h1 + (size_t)(b * 128 + m) * 4096 + t * 16;
  uint4 q0 = *(const uint4*)p;
  uint4 q1 = *(const uint4*)(p + 8);
  unsigned short e[16];
  *(uint4*)&e[0] = q0; *(uint4*)&e[8] = q1;
  float s = 0.f, q = 0.f;
#pragma unroll
  for (int j = 0; j < 16; j++) { float v = bf2f(e[j]); s += v; q += v * v; }
#pragma unroll
  for (int msk = 1; msk < 64; msk <<= 1) {
    s += __shfl_xor(s, msk, 64);
    q += __shfl_xor(q, msk, 64);
  }
  if ((t & 63) == 0) { atomicAdd(&g_stats[m], s); atomicAdd(&g_stats[128 + m], q); }
}

// ---------- K2 fallback: fused sampling + fp32 GEMM ----------
__global__ __launch_bounds__(256) void k_dcn(
    const void* __restrict__ x, const float* __restrict__ om,
    const float* __restrict__ wdcnT, const void* __restrict__ b_dcn,
    unsigned short* __restrict__ h1) {
  const int f = g_isf32;
  const int h = blockIdx.x, b = blockIdx.y;
  const int t = threadIdx.x;
  __shared__ float S[64 * 64];
  __shared__ int   midx[64][4];
  __shared__ float mwgt[64][4];
  const int og = t >> 4, pg = t & 15;
  const int pA = t & 63, cgA = t >> 6;
  float acc[8][4];
#pragma unroll
  for (int j = 0; j < 8; j++)
#pragma unroll
    for (int i = 0; i < 4; i++) acc[j][i] = 0.f;

  for (int k = 0; k < 9; k++) {
    if (t < 64) {
      const int w = t;
      const float* ob = &om[(size_t)(b * 27) * 4096 + h * 64 + w];
      float oy = ob[(size_t)k * 4096];
      float ox = ob[(size_t)(k + 9) * 4096];
      float mm = ob[(size_t)(k + 18) * 4096];
      float msk = 1.f / (1.f + expf(-mm));
      float py = oy + (float)(h - 1 + k / 3);
      float px = ox + (float)(w - 1 + (k - (k / 3) * 3));
      float y0f = floorf(py), x0f = floorf(px);
      float ly = py - y0f, lx = px - x0f;
      int y0 = (int)y0f, x0 = (int)x0f;
      int y1 = y0 + 1, x1 = x0 + 1;
      float fy0 = (y0 >= 0 && y0 < 64) ? 1.f : 0.f;
      float fy1 = (y1 >= 0 && y1 < 64) ? 1.f : 0.f;
      float fx0 = (x0 >= 0 && x0 < 64) ? 1.f : 0.f;
      float fx1 = (x1 >= 0 && x1 < 64) ? 1.f : 0.f;
      int y0c = min(max(y0, 0), 63), y1c = min(max(y1, 0), 63);
      int x0c = min(max(x0, 0), 63), x1c = min(max(x1, 0), 63);
      midx[w][0] = y0c * 64 + x0c;
      midx[w][1] = y0c * 64 + x1c;
      midx[w][2] = y1c * 64 + x0c;
      midx[w][3] = y1c * 64 + x1c;
      mwgt[w][0] = (1.f - ly) * (1.f - lx) * msk * fy0 * fx0;
      mwgt[w][1] = (1.f - ly) * lx * msk * fy0 * fx1;
      mwgt[w][2] = ly * (1.f - lx) * msk * fy1 * fx0;
      mwgt[w][3] = ly * lx * msk * fy1 * fx1;
    }
    for (int ch = 0; ch < 4; ch++) {
      __syncthreads();
      {
        const int i0 = midx[pA][0], i1 = midx[pA][1], i2 = midx[pA][2], i3 = midx[pA][3];
        const float g0 = mwgt[pA][0], g1 = mwgt[pA][1], g2 = mwgt[pA][2], g3 = mwgt[pA][3];
        const size_t cbase = (size_t)(b * 256 + ch * 64 + cgA * 16) * 4096;
        float* Sp = &S[(cgA * 16) * 64 + pA];
#pragma unroll 4
        for (int j = 0; j < 16; j++) {
          const size_t xo = cbase + (size_t)j * 4096;
          float v = g0 * ldi(x, xo + i0, f) + g1 * ldi(x, xo + i1, f)
                  + g2 * ldi(x, xo + i2, f) + g3 * ldi(x, xo + i3, f);
          Sp[j * 64] = v;
        }
      }
      __syncthreads();
      const float* wk = wdcnT + (size_t)k * 32768 + (size_t)(ch * 64) * 128;
#pragma unroll 2
      for (int c2 = 0; c2 < 64; c2++) {
        float4 a0 = *(const float4*)&wk[c2 * 128 + og * 8];
        float4 a1 = *(const float4*)&wk[c2 * 128 + og * 8 + 4];
        float4 s4 = *(const float4*)&S[c2 * 64 + pg * 4];
        float aa[8] = {a0.x, a0.y, a0.z, a0.w, a1.x, a1.y, a1.z, a1.w};
        float ss[4] = {s4.x, s4.y, s4.z, s4.w};
#pragma unroll
        for (int j = 0; j < 8; j++)
#pragma unroll
          for (int i = 0; i < 4; i++)
            acc[j][i] = fmaf(aa[j], ss[i], acc[j][i]);
      }
    }
  }
#pragma unroll
  for (int j = 0; j < 8; j++) {
    const int o = og * 8 + j;
    float bd = ldi(b_dcn, o, f);
    float v0 = acc[j][0] + bd, v1 = acc[j][1] + bd, v2 = acc[j][2] + bd, v3 = acc[j][3] + bd;
    float s = v0 + v1 + v2 + v3;
    float q = v0 * v0 + v1 * v1 + v2 * v2 + v3 * v3;
    uint2 pkv = make_uint2(pk2(v0, v1), pk2(v2, v3));
    *(uint2*)(h1 + (size_t)((b * 128 + o) * 64 + h) * 64 + pg * 4) = pkv;
#pragma unroll
    for (int m = 1; m < 16; m <<= 1) {
      s += __shfl_xor(s, m, 64);
      q += __shfl_xor(q, m, 64);
    }
    if (pg == 0) { atomicAdd(&g_stats[o], s); atomicAdd(&g_stats[128 + o], q); }
  }
}

// ---------- K3 (fast): BN1 + ReLU + transpose  h1[b][ch][pos] -> h1T[b][pos][ch] ----------
__global__ __launch_bounds__(256) void k_bn1t(
    const unsigned short* __restrict__ h1, const void* __restrict__ g1,
    const void* __restrict__ be1, unsigned short* __restrict__ h1T) {
  const int f = g_isf32;
  const int pt = blockIdx.x, chh = blockIdx.y, b = blockIdx.z;
  const int t = threadIdx.x;
  __shared__ unsigned short T[64][72];
  const int c0 = chh * 64, p0 = pt * 64;
  {
    int cl = t >> 2, q = t & 3;
    int o = c0 + cl;
    float mu = g_stats[o] * (1.f / 32768.f);
    float var = g_stats[128 + o] * (1.f / 32768.f) - mu * mu;
    float sc = rsqrtf(var + 1e-5f) * ldi(g1, o, f);
    float sh = ldi(be1, o, f) - mu * sc;
    const unsigned short* hp = h1 + (size_t)(b * 128 + o) * 4096 + p0 + q * 16;
    uint4 q0 = *(const uint4*)hp, q1 = *(const uint4*)(hp + 8);
    unsigned short e[16], r[16];
    *(uint4*)&e[0] = q0; *(uint4*)&e[8] = q1;
#pragma unroll
    for (int j = 0; j < 16; j++)
      r[j] = f2bf(fmaxf(fmaf(bf2f(e[j]), sc, sh), 0.f));
    *(uint4*)&T[cl][q * 16]     = *(uint4*)&r[0];
    *(uint4*)&T[cl][q * 16 + 8] = *(uint4*)&r[8];
  }
  __syncthreads();
  {
    int pl = t >> 2, qc = t & 3;
    unsigned short r[16];
#pragma unroll
    for (int j = 0; j < 16; j++) r[j] = T[qc * 16 + j][pl];
    unsigned short* op = h1T + (size_t)(b * 4096 + p0 + pl) * 128 + c0 + qc * 16;
    *(uint4*)op       = *(uint4*)&r[0];
    *(uint4*)(op + 8) = *(uint4*)&r[8];
  }
}

// ---------- K3 fallback: BN1 + ReLU in place on h1 ----------
__global__ void k_bn1(unsigned short* __restrict__ h1, const void* __restrict__ g1,
                      const void* __restrict__ be1) {
  const int f = g_isf32;
  int gid = blockIdx.x * 256 + threadIdx.x;
  size_t base = (size_t)gid * 8;
  int o = (int)((base >> 12) & 127);
  float mu = g_stats[o] * (1.f / 32768.f);
  float var = g_stats[128 + o] * (1.f / 32768.f) - mu * mu;
  float sc = rsqrtf(var + 1e-5f) * ldi(g1, o, f);
  float sh = ldi(be1, o, f) - mu * sc;
  uint4 p = *(const uint4*)(h1 + base);
  unsigned int pp[4] = {p.x, p.y, p.z, p.w};
  unsigned int r[4];
#pragma unroll
  for (int i = 0; i < 4; i++) {
    float f0 = fmaxf(fmaf(bf2f((unsigned short)(pp[i] & 0xffff)), sc, sh), 0.f);
    float f1 = fmaxf(fmaf(bf2f((unsigned short)(pp[i] >> 16)), sc, sh), 0.f);
    r[i] = pk2(f0, f1);
  }
  *(uint4*)(h1 + base) = make_uint4(r[0], r[1], r[2], r[3]);
}

// ---------- K4 (fast): parity-decomposed transposed conv as MFMA GEMM ----------
__global__ __launch_bounds__(256) void k_ctgemm(
    const unsigned short* __restrict__ h1T,  // [b][4096 pos][128 ch]
    const unsigned short* __restrict__ Apar,
    void* __restrict__ out2p) {
  const int f = g_isf32;
  const int nt = blockIdx.x, par = blockIdx.y, b = blockIdx.z;
  const int py = par >> 1, px = par & 1;
  const int t = threadIdx.x;
  const int wv = t >> 6, L = t & 63;
  const int quad = L >> 4, l15 = L & 15;
  const int wm = (wv >> 1) * 64, wn = (wv & 1) * 64;
  __shared__ unsigned short As[128][40];
  __shared__ unsigned short Bs[128][40];
  f32x4 acc[4][4] = {};
  const int y0 = nt * 2;
  const unsigned short* Ap = Apar + (size_t)par * 128 * 512;
  const unsigned short* hb = h1T + (size_t)b * 4096 * 128;
  const int sp = t >> 1, shalf = t & 1;
  const int srr = sp >> 6, sx = sp & 63;

  for (int kk = 0; kk < 512; kk += 32) {
    const int tap = kk >> 7, ic = kk & 127;
    const int a = tap >> 1, bb = tap & 1;
    const int ya = (py == 0) ? (a ? -1 : 0) : (a ? 0 : 1);
    const int xb = (px == 0) ? (bb ? -1 : 0) : (bb ? 0 : 1);
    __syncthreads();
    {   // A-tile 128x32
      int m = t >> 1, seg = t & 1;
      const unsigned short* ap = Ap + (size_t)m * 512 + kk + seg * 16;
      uint4 q0 = *(const uint4*)(ap);
      uint4 q1 = *(const uint4*)(ap + 8);
      *(uint4*)&As[m][seg * 16]     = q0;
      *(uint4*)&As[m][seg * 16 + 8] = q1;
    }
    {   // B-tile: 128 pos x 32 ch, vectorized from channel-last h1T, zero-padded
      int srcy = y0 + srr + ya;
      int srcx = sx + xb;
      uint4 q0 = make_uint4(0, 0, 0, 0), q1 = q0;
      if (srcy >= 0 && srcy < 64 && srcx >= 0 && srcx < 64) {
        const unsigned short* hp = hb + ((size_t)(srcy * 64 + srcx)) * 128 + ic + shalf * 16;
        q0 = *(const uint4*)(hp);
        q1 = *(const uint4*)(hp + 8);
      }
      *(uint4*)&Bs[sp][shalf * 16]     = q0;
      *(uint4*)&Bs[sp][shalf * 16 + 8] = q1;
    }
    __syncthreads();
    const int ar = quad * 8;
    bf16x8 af[4], bfr[4];
#pragma unroll
    for (int tm = 0; tm < 4; tm++) af[tm]  = *(const bf16x8*)&As[wm + tm * 16 + l15][ar];
#pragma unroll
    for (int tn = 0; tn < 4; tn++) bfr[tn] = *(const bf16x8*)&Bs[wn + tn * 16 + l15][ar];
#pragma unroll
    for (int tm = 0; tm < 4; tm++)
#pragma unroll
      for (int tn = 0; tn < 4; tn++)
        acc[tm][tn] = __builtin_amdgcn_mfma_f32_16x16x32_bf16(af[tm], bfr[tn], acc[tm][tn], 0, 0, 0);
  }

  const size_t obase = (size_t)((par * 8 + b) * 128) * 4096;
#pragma unroll
  for (int tm = 0; tm < 4; tm++) {
#pragma unroll
    for (int r = 0; r < 4; r++) {
      int m = wm + tm * 16 + quad * 4 + r;
#pragma unroll
      for (int tn = 0; tn < 4; tn++) {
        float v = acc[tm][tn][r];
        int n = wn + tn * 16 + l15;
        size_t ofs = obase + (size_t)m * 4096 + (size_t)((y0 + (n >> 6)) * 64 + (n & 63));
        if (f) ((float*)out2p)[ofs] = v;
        else   ((unsigned short*)out2p)[ofs] = f2bf(v);
      }
    }
  }
}

// ---------- K_stats2: per-channel sum/sumsq of out2p -> g_stats[256..511] ----------
__global__ __launch_bounds__(256) void k_stats2(const void* __restrict__ out2p) {
  const int f = g_isf32;
  const int m = blockIdx.x, pb = blockIdx.y;
  const int t = threadIdx.x;
  size_t base = ((size_t)pb * 128 + m) * 4096 + (size_t)t * 16;
  float s = 0.f, q = 0.f;
  if (f) {
    const float* p = (const float*)out2p + base;
#pragma unroll
    for (int j = 0; j < 4; j++) {
      float4 v = *(const float4*)(p + j * 4);
      s += v.x + v.y + v.z + v.w;
      q += v.x * v.x + v.y * v.y + v.z * v.z + v.w * v.w;
    }
  } else {
    const unsigned short* p = (const unsigned short*)out2p + base;
    uint4 q0 = *(const uint4*)p, q1 = *(const uint4*)(p + 8);
    unsigned short e[16];
    *(uint4*)&e[0] = q0; *(uint4*)&e[8] = q1;
#pragma unroll
    for (int j = 0; j < 16; j++) { float v = bf2f(e[j]); s += v; q += v * v; }
  }
#pragma unroll
  for (int msk = 1; msk < 64; msk <<= 1) {
    s += __shfl_xor(s, msk, 64);
    q += __shfl_xor(q, msk, 64);
  }
  if ((t & 63) == 0) { atomicAdd(&g_stats[256 + m], s); atomicAdd(&g_stats[384 + m], q); }
}

// ---------- K5 (fast): BN2 + ReLU + parity de-interleave -> d_out ----------
__global__ __launch_bounds__(256) void k_bn2f(
    const void* __restrict__ out2p, const void* __restrict__ g2,
    const void* __restrict__ be2, void* __restrict__ out) {
  const int f = g_isf32;
  const int m = blockIdx.x, b = blockIdx.y;
  const int t = threadIdx.x;
  float mu = g_stats[256 + m] * (1.f / 131072.f);
  float var = g_stats[384 + m] * (1.f / 131072.f) - mu * mu;
  float sc = rsqrtf(var + 1e-5f) * ldi(g2, m, f);
  float sh = ldi(be2, m, f) - mu * sc;
  const int row8 = t >> 3, xseg = t & 7;
  const int xh0 = xseg * 8;
#pragma unroll
  for (int pss = 0; pss < 4; pss++) {
    int yy = pss * 32 + row8;
    int y = yy >> 1, py = yy & 1;
    size_t s0 = ((size_t)((py * 2 + 0) * 8 + b) * 128 + m) * 4096 + (size_t)(y * 64 + xh0);
    size_t s1 = ((size_t)((py * 2 + 1) * 8 + b) * 128 + m) * 4096 + (size_t)(y * 64 + xh0);
    float v0[8], v1[8];
    if (f) {
      const float* p0 = (const float*)out2p + s0;
      const float* p1 = (const float*)out2p + s1;
      float4 a0 = *(const float4*)p0, a1 = *(const float4*)(p0 + 4);
      float4 c0 = *(const float4*)p1, c1 = *(const float4*)(p1 + 4);
      v0[0] = a0.x; v0[1] = a0.y; v0[2] = a0.z; v0[3] = a0.w;
      v0[4] = a1.x; v0[5] = a1.y; v0[6] = a1.z; v0[7] = a1.w;
      v1[0] = c0.x; v1[1] = c0.y; v1[2] = c0.z; v1[3] = c0.w;
      v1[4] = c1.x; v1[5] = c1.y; v1[6] = c1.z; v1[7] = c1.w;
    } else {
      const unsigned short* p0 = (const unsigned short*)out2p + s0;
      const unsigned short* p1 = (const unsigned short*)out2p + s1;
      uint4 u0 = *(const uint4*)p0, u1 = *(const uint4*)p1;
      unsigned short e0[8], e1[8];
      *(uint4*)&e0[0] = u0; *(uint4*)&e1[0] = u1;
#pragma unroll
      for (int j = 0; j < 8; j++) { v0[j] = bf2f(e0[j]); v1[j] = bf2f(e1[j]); }
    }
    float r[16];
#pragma unroll
    for (int i = 0; i < 8; i++) {
      r[2 * i]     = fmaxf(fmaf(v0[i], sc, sh), 0.f);
      r[2 * i + 1] = fmaxf(fmaf(v1[i], sc, sh), 0.f);
    }
    size_t ob = (size_t)(b * 128 + m) * 16384 + (size_t)yy * 128 + (size_t)(xh0 * 2);
    if (f) {
      float* op = (float*)out + ob;
#pragma unroll
      for (int v4 = 0; v4 < 4; v4++)
        ((float4*)op)[v4] = make_float4(r[4 * v4], r[4 * v4 + 1], r[4 * v4 + 2], r[4 * v4 + 3]);
    } else {
      unsigned short* op = (unsigned short*)out + ob;
      unsigned int w_[8];
#pragma unroll
      for (int i = 0; i < 8; i++) w_[i] = pk2(r[2 * i], r[2 * i + 1]);
      *(uint4*)(op)     = make_uint4(w_[0], w_[1], w_[2], w_[3]);
      *(uint4*)(op + 8) = make_uint4(w_[4], w_[5], w_[6], w_[7]);
    }
  }
}

// ---------- K4 fallback: fp32 VALU transposed conv ----------
__global__ __launch_bounds__(256) void k_ctconv(
    const unsigned short* __restrict__ h1n, const float* __restrict__ wctT,
    void* __restrict__ out2) {
  const int f = g_isf32;
  const int y = blockIdx.x, b = blockIdx.y;
  const int t = threadIdx.x;
  const int og = t >> 3, xg = t & 7;
  __shared__ float hs[2 * 32 * 68];
  int kr0, kr1, r0, r1;
  if ((y & 1) == 0) { kr0 = 1; r0 = y >> 1; kr1 = 3; r1 = (y >> 1) - 1; }
  else              { kr0 = 0; r0 = (y + 1) >> 1; kr1 = 2; r1 = (y - 1) >> 1; }
  float acc[4][16];
#pragma unroll
  for (int j = 0; j < 4; j++)
#pragma unroll
    for (int i = 0; i < 16; i++) acc[j][i] = 0.f;

  for (int ihc = 0; ihc < 4; ihc++) {
    __syncthreads();
    for (int e = t; e < 2 * 32 * 64; e += 256) {
      int rr = e >> 11, rem = e & 2047, il = rem >> 6, w = rem & 63;
      int i = ihc * 32 + il;
      int row = rr ? r1 : r0;
      float v = 0.f;
      if (row >= 0 && row < 64)
        v = bf2f(h1n[(size_t)((b * 128 + i) * 64 + row) * 64 + w]);
      hs[(rr * 32 + il) * 68 + w + 1] = v;
    }
    for (int e = t; e < 64; e += 256) {
      int base = e * 68;
      hs[base] = 0.f; hs[base + 65] = 0.f; hs[base + 66] = 0.f; hs[base + 67] = 0.f;
    }
    __syncthreads();
    for (int il = 0; il < 32; il++) {
      const int i = ihc * 32 + il;
      float br[2][12];
#pragma unroll
      for (int rr = 0; rr < 2; rr++) {
        const float* p = &hs[(rr * 32 + il) * 68 + xg * 8];
        float4 q0 = *(const float4*)(p);
        float4 q1 = *(const float4*)(p + 4);
        float4 q2 = *(const float4*)(p + 8);
        br[rr][0] = q0.x; br[rr][1] = q0.y; br[rr][2] = q0.z; br[rr][3] = q0.w;
        br[rr][4] = q1.x; br[rr][5] = q1.y; br[rr][6] = q1.z; br[rr][7] = q1.w;
        br[rr][8] = q2.x; br[rr][9] = q2.y; br[rr][10] = q2.z; br[rr][11] = q2.w;
      }
      float a[2][4][4];
#pragma unroll
      for (int rr = 0; rr < 2; rr++) {
        const int krr = rr ? kr1 : kr0;
#pragma unroll
        for (int kc = 0; kc < 4; kc++) {
          float4 av = *(const float4*)&wctT[((size_t)(krr * 4 + kc) * 128 + i) * 128 + og * 4];
          a[rr][kc][0] = av.x; a[rr][kc][1] = av.y; a[rr][kc][2] = av.z; a[rr][kc][3] = av.w;
        }
      }
#pragma unroll
      for (int xi = 0; xi < 16; xi++) {
        const int u = xi >> 1;
        const int kcA = (xi & 1) ? 0 : 1;
        const int lwA = (xi & 1) ? u + 2 : u + 1;
        const int kcB = (xi & 1) ? 2 : 3;
        const int lwB = (xi & 1) ? u + 1 : u;
#pragma unroll
        for (int rr = 0; rr < 2; rr++) {
#pragma unroll
          for (int j = 0; j < 4; j++) {
            acc[j][xi] = fmaf(a[rr][kcA][j], br[rr][lwA], acc[j][xi]);
            acc[j][xi] = fmaf(a[rr][kcB][j], br[rr][lwB], acc[j][xi]);
          }
        }
      }
    }
  }
#pragma unroll
  for (int j = 0; j < 4; j++) {
    const int o = og * 4 + j;
    float s = 0.f, q = 0.f;
#pragma unroll
    for (int xi = 0; xi < 16; xi++) { s += acc[j][xi]; q += acc[j][xi] * acc[j][xi]; }
    size_t ofs = (size_t)((b * 128 + o) * 128 + y) * 128 + xg * 16;
    if (f) {
      float* op = (float*)out2 + ofs;
#pragma unroll
      for (int v4 = 0; v4 < 4; v4++)
        ((float4*)op)[v4] = make_float4(acc[j][4 * v4], acc[j][4 * v4 + 1],
                                        acc[j][4 * v4 + 2], acc[j][4 * v4 + 3]);
    } else {
      unsigned int w_[8];
#pragma unroll
      for (int xi = 0; xi < 8; xi++) w_[xi] = pk2(acc[j][2 * xi], acc[j][2 * xi + 1]);
      unsigned short* op = (unsigned short*)out2 + ofs;
      *(uint4*)(op)     = make_uint4(w_[0], w_[1], w_[2], w_[3]);
      *(uint4*)(op + 8) = make_uint4(w_[4], w_[5], w_[6], w_[7]);
    }
#pragma unroll
    for (int m = 1; m < 8; m <<= 1) {
      s += __shfl_xor(s, m, 64);
      q += __shfl_xor(q, m, 64);
    }
    if (xg == 0) { atomicAdd(&g_stats[256 + o], s); atomicAdd(&g_stats[384 + o], q); }
  }
}

// ---------- K5 fallback: BN2 + ReLU in place on d_out ----------
__global__ void k_bn2(void* __restrict__ out2, const void* __restrict__ g2,
                      const void* __restrict__ be2) {
  const int f = g_isf32;
  int gid = blockIdx.x * 256 + threadIdx.x;
  size_t base = (size_t)gid * 8;
  int o = (int)((base >> 14) & 127);
  float mu = g_stats[256 + o] * (1.f / 131072.f);
  float var = g_stats[384 + o] * (1.f / 131072.f) - mu * mu;
  float sc = rsqrtf(var + 1e-5f) * ldi(g2, o, f);
  float sh = ldi(be2, o, f) - mu * sc;
  if (f) {
    float4* op = (float4*)out2 + gid * 2;
    float4 p0 = op[0], p1 = op[1];
    p0.x = fmaxf(fmaf(p0.x, sc, sh), 0.f); p0.y = fmaxf(fmaf(p0.y, sc, sh), 0.f);
    p0.z = fmaxf(fmaf(p0.z, sc, sh), 0.f); p0.w = fmaxf(fmaf(p0.w, sc, sh), 0.f);
    p1.x = fmaxf(fmaf(p1.x, sc, sh), 0.f); p1.y = fmaxf(fmaf(p1.y, sc, sh), 0.f);
    p1.z = fmaxf(fmaf(p1.z, sc, sh), 0.f); p1.w = fmaxf(fmaf(p1.w, sc, sh), 0.f);
    op[0] = p0; op[1] = p1;
  } else {
    unsigned short* ob = (unsigned short*)out2 + base;
    uint4 p = *(const uint4*)ob;
    unsigned int pp[4] = {p.x, p.y, p.z, p.w};
    unsigned int r[4];
#pragma unroll
    for (int i = 0; i < 4; i++) {
      float f0 = fmaxf(fmaf(bf2f((unsigned short)(pp[i] & 0xffff)), sc, sh), 0.f);
      float f1 = fmaxf(fmaf(bf2f((unsigned short)(pp[i] >> 16)), sc, sh), 0.f);
      r[i] = pk2(f0, f1);
    }
    *(uint4*)ob = make_uint4(r[0], r[1], r[2], r[3]);
  }
}

// ---------- launch ----------
extern "C" void kernel_launch(void* const* d_in, const int* in_sizes, int n_in,
                              void* d_out, int out_size, void* d_ws, size_t ws_size,
                              hipStream_t stream) {
  const void* x     = d_in[0];
  const void* w_off = d_in[1];
  const void* b_off = d_in[2];
  const void* w_dcn = d_in[3];
  const void* b_dcn = d_in[4];
  const void* g1    = d_in[5];
  const void* be1   = d_in[6];
  const void* w_ct  = d_in[7];
  const void* g2    = d_in[8];
  const void* be2   = d_in[9];

  char* ws = (char*)d_ws;
  const bool fast = ws_size >= (size_t)166000000;

  unsigned short* h1; float* om; float* wdcnT; float* wctT;
  float* woffT; unsigned short* wdcnA; unsigned short* AparB; unsigned short* h1T;
  void* out2p; unsigned short* xT; unsigned short* woffA;
  if (fast) {
    // fully disjoint fast-path layout (~108 MB total, no aliasing)
    xT    = (unsigned short*)(ws + 0);            //  16,777,216
    h1    = (unsigned short*)(ws + 16777216);     //   8,388,608
    h1T   = (unsigned short*)(ws + 25165824);     //   8,388,608
    out2p = (void*)(ws + 33554432);               // <=67,108,864
    om    = (float*)(ws + 100663296);             //   3,538,944
    wctT  = (float*)(ws + 104202240);             //   1,048,576
    AparB = (unsigned short*)(ws + 105250816);    //     524,288
    wdcnA = (unsigned short*)(ws + 105775104);    //     589,824
    woffA = (unsigned short*)(ws + 106364928);    //     147,456
    woffT = (float*)(ws + 106512384);             //     248,832 (k_prep writes; unused fast)
    wdcnT = (float*)(ws + 106761216);             //   1,179,648 (k_prep writes; unused fast)
  } else {
    h1    = (unsigned short*)(ws + 0);
    om    = (float*)(ws + 8388608);
    wdcnT = (float*)(ws + 11927552);
    wctT  = (float*)(ws + 13107200);
    woffT = (float*)(ws + 14155776);
    wdcnA = (unsigned short*)(ws + 14404608);
    woffA = (unsigned short*)(ws + 14994432);
    AparB = nullptr;
    h1T   = nullptr;
    out2p = nullptr;
    xT    = nullptr;
  }

  k_detect<<<dim3(1), 256, 0, stream>>>((const unsigned short*)x);
  k_prep<<<dim3(3859), 256, 0, stream>>>(w_dcn, w_ct, w_off, wdcnT, wctT, woffT, wdcnA, woffA);
  if (fast) {
    k_xt<<<dim3(64, 4, 8), 256, 0, stream>>>(x, xT);
    k_offmfma<<<dim3(64, 8), 256, 0, stream>>>(xT, woffA, b_off, om);
    k_prep2<<<dim3(1024), 256, 0, stream>>>(wctT, AparB);
    k_dcnf<<<dim3(8, 128), 256, 0, stream>>>(xT, wdcnA, om, b_dcn, h1);
    k_stats1<<<dim3(128, 8), 256, 0, stream>>>(h1);
    k_bn1t<<<dim3(64, 2, 8), 256, 0, stream>>>(h1, g1, be1, h1T);
    k_ctgemm<<<dim3(32, 4, 8), 256, 0, stream>>>(h1T, AparB, out2p);
    k_stats2<<<dim3(128, 32), 256, 0, stream>>>(out2p);
    k_bn2f<<<dim3(128, 8), 256, 0, stream>>>(out2p, g2, be2, d_out);
  } else {
    k_offconv<<<dim3(64, 8), 256, 0, stream>>>(x, b_off, woffT, om);
    k_dcn<<<dim3(64, 8), 256, 0, stream>>>(x, om, wdcnT, b_dcn, h1);
    k_bn1<<<dim3(2048), 256, 0, stream>>>(h1, g1, be1);
    k_ctconv<<<dim3(128, 8), 256, 0, stream>>>(h1, wctT, d_out);
    k_bn2<<<dim3(8192), 256, 0, stream>>>(d_out, g2, be2);
  }
}

// Round 11
// 362.676 us; speedup vs baseline: 1.0958x; 1.0958x over previous
//
#include <hip/hip_runtime.h>
#include <stdint.h>

// ---------- device globals: dtype flag + BN stats ----------
__device__ int   g_isf32;
__device__ float g_stats[512];  // [0:128) s1sum, [128:256) s1sq, [256:384) s2sum, [384:512) s2sq

typedef __attribute__((ext_vector_type(8))) short bf16x8;
typedef __attribute__((ext_vector_type(4))) float f32x4;

// ---------- bf16 helpers ----------
__device__ __forceinline__ float bf2f(unsigned short u) {
  union { unsigned int i; float f; } v; v.i = ((unsigned int)u) << 16; return v.f;
}
__device__ __forceinline__ unsigned short f2bf(float f) {
  union { float f; unsigned int i; } v; v.f = f;
  unsigned int r = v.i + 0x7FFFu + ((v.i >> 16) & 1u);
  return (unsigned short)(r >> 16);
}
__device__ __forceinline__ unsigned int pk2(float a, float b) {
  return (unsigned int)f2bf(a) | ((unsigned int)f2bf(b) << 16);
}
// dtype-flex input load: f ? fp32 : bf16
__device__ __forceinline__ float ldi(const void* p, size_t i, int f) {
  return f ? ((const float*)p)[i] : bf2f(((const unsigned short*)p)[i]);
}

// ---------- K0: dtype detector + stats zeroing ----------
__global__ void k_detect(const unsigned short* __restrict__ x) {
  __shared__ int cnt;
  const int t = threadIdx.x;
  if (t == 0) cnt = 0;
  g_stats[t] = 0.f; g_stats[t + 256] = 0.f;
  __syncthreads();
  int c = 0;
  for (int j = 0; j < 16; j++) {
    unsigned short u = x[t * 16 + j];
    int e = (u >> 7) & 0xFF;
    if (e == 0xFF || (e != 0 && e <= 100)) c++;
  }
  atomicAdd(&cnt, c);
  __syncthreads();
  if (t == 0) g_isf32 = (cnt > 256) ? 1 : 0;
}

// ---------- K_prep: weights -> GEMM-friendly layouts ----------
// jobs: wdcnT 294912 | wctT 262144 | woffT 62208 | wdcnA 294912 | woffA 73728
__global__ void k_prep(const void* __restrict__ w_dcn, const void* __restrict__ w_ct,
                       const void* __restrict__ w_off,
                       float* __restrict__ wdcnT, float* __restrict__ wctT,
                       float* __restrict__ woffT, unsigned short* __restrict__ wdcnA,
                       unsigned short* __restrict__ woffA) {
  const int f = g_isf32;
  int idx = blockIdx.x * 256 + threadIdx.x;
  if (idx < 294912) {
    int k = idx / 32768, c = (idx >> 7) & 255, o = idx & 127;
    wdcnT[idx] = ldi(w_dcn, (size_t)(o * 256 + c) * 9 + k, f);
  }
  int i2 = idx - 294912;
  if (i2 >= 0 && i2 < 262144) {
    int kr = i2 >> 16, kc = (i2 >> 14) & 3, i = (i2 >> 7) & 127, o = i2 & 127;
    wctT[i2] = ldi(w_ct, (size_t)((i * 128 + o) * 4 + kr) * 4 + kc, f);
  }
  int i3 = idx - (294912 + 262144);
  if (i3 >= 0 && i3 < 62208) {
    int ci = i3 / 243, r = i3 - ci * 243, k = r / 27, c = r - (r / 27) * 27;
    woffT[i3] = ldi(w_off, (size_t)(c * 256 + ci) * 9 + k, f);
  }
  int i4 = idx - 619264;
  if (i4 >= 0 && i4 < 294912) {
    int o = i4 / 2304, rem = i4 - o * 2304;
    int k = rem >> 8, c = rem & 255;
    wdcnA[i4] = f2bf(ldi(w_dcn, (size_t)(o * 256 + c) * 9 + k, f));
  }
  int i5 = idx - 914176;
  if (i5 >= 0 && i5 < 73728) {       // woffA[m=32][k = tap*256 + ci] bf16, m>=27 zero
    int m = i5 / 2304, r = i5 - m * 2304;
    int tap = r >> 8, ci = r & 255;
    float v = (m < 27) ? ldi(w_off, (size_t)(m * 256 + ci) * 9 + tap, f) : 0.f;
    woffA[i5] = f2bf(v);
  }
}

// ---------- K_prep2: parity-decomposed ct-conv A matrices (fast path only) ----------
// Apar[par][o][tap*128 + i] bf16, par = py*2+px, tap = a*2+b
__global__ void k_prep2(const float* __restrict__ wctT, unsigned short* __restrict__ Apar) {
  int idx = blockIdx.x * 256 + threadIdx.x;   // 262144
  int par = idx >> 16, rem = idx & 65535;
  int o = rem >> 9, rem2 = rem & 511;
  int tap = rem2 >> 7, i = rem2 & 127;
  int py = par >> 1, px = par & 1, a = tap >> 1, bb = tap & 1;
  int kr = (py == 0) ? (a ? 3 : 1) : (a ? 2 : 0);
  int kc = (px == 0) ? (bb ? 3 : 1) : (bb ? 2 : 0);
  Apar[idx] = f2bf(wctT[((size_t)(kr * 4 + kc) * 128 + i) * 128 + o]);
}

// ---------- K_xt: x (NCHW) -> xT[b][h][w][256] bf16 (channel-last) ----------
// grid (64 h, 4 cq, 8 b); 64x64 LDS transpose tile (k_bn1t pattern).
__global__ __launch_bounds__(256) void k_xt(const void* __restrict__ x,
                                            unsigned short* __restrict__ xT) {
  const int f = g_isf32;
  const int h = blockIdx.x, cq = blockIdx.y, b = blockIdx.z;
  const int t = threadIdx.x;
  __shared__ unsigned short T[64][72];
  {
    int cl = t >> 2, q = t & 3;
    size_t base = ((size_t)((b * 256 + cq * 64 + cl) * 64 + h) << 6) + q * 16;
    unsigned short r[16];
    if (f) {
      const float4* p = (const float4*)((const float*)x + base);
      float4 v0 = p[0], v1 = p[1], v2 = p[2], v3 = p[3];
      float vv[16] = {v0.x, v0.y, v0.z, v0.w, v1.x, v1.y, v1.z, v1.w,
                      v2.x, v2.y, v2.z, v2.w, v3.x, v3.y, v3.z, v3.w};
#pragma unroll
      for (int j = 0; j < 16; j++) r[j] = f2bf(vv[j]);
    } else {
      const unsigned short* p = (const unsigned short*)x + base;
      *(uint4*)&r[0] = *(const uint4*)p;
      *(uint4*)&r[8] = *(const uint4*)(p + 8);
    }
    *(uint4*)&T[cl][q * 16]     = *(uint4*)&r[0];
    *(uint4*)&T[cl][q * 16 + 8] = *(uint4*)&r[8];
  }
  __syncthreads();
  {
    int pl = t >> 2, qc = t & 3;
    unsigned short r[16];
#pragma unroll
    for (int j = 0; j < 16; j++) r[j] = T[qc * 16 + j][pl];
    unsigned short* op = xT + ((size_t)((b * 64 + h) * 64 + pl) << 8) + cq * 64 + qc * 16;
    *(uint4*)op       = *(uint4*)&r[0];
    *(uint4*)(op + 8) = *(uint4*)&r[8];
  }
}

// ---------- K1 (fast): offset conv as MFMA GEMM ----------
// om[27][4096] = woffA[32][2304] x im2col(x).  grid (64 h, 8 b), 4 waves.
__global__ __launch_bounds__(256) void k_offmfma(
    const unsigned short* __restrict__ xT,
    const unsigned short* __restrict__ woffA,
    const void* __restrict__ b_off, float* __restrict__ om) {
  const int f = g_isf32;
  const int h = blockIdx.x, b = blockIdx.y;
  const int t = threadIdx.x;
  const int wv = t >> 6, L = t & 63, quad = L >> 4, l15 = L & 15;
  __shared__ unsigned short Bs[3][66][40];   // [row h-1..h+1][w-pad -1..64][ci 32 pad40]
  f32x4 acc[2] = {};
  const int sl = t >> 6, sw = t & 63;        // staging assignment (t<192)

  for (int cq = 0; cq < 8; cq++) {
    __syncthreads();
    if (t < 192) {
      int row = h - 1 + sl;
      uint4 q0 = make_uint4(0, 0, 0, 0), q1 = q0, q2 = q0, q3 = q0;
      if (row >= 0 && row < 64) {
        const unsigned short* src = xT + ((size_t)((b * 64 + row) * 64 + sw) << 8) + cq * 32;
        q0 = *(const uint4*)(src);
        q1 = *(const uint4*)(src + 8);
        q2 = *(const uint4*)(src + 16);
        q3 = *(const uint4*)(src + 24);
      }
      unsigned short* d = &Bs[sl][sw + 1][0];
      *(uint4*)(d)      = q0; *(uint4*)(d + 8)  = q1;
      *(uint4*)(d + 16) = q2; *(uint4*)(d + 24) = q3;
    } else if (t < 198) {
      int idx = t - 192;
      int zs = idx >> 1, zc = (idx & 1) ? 65 : 0;
      unsigned short* d = &Bs[zs][zc][0];
      uint4 z = make_uint4(0, 0, 0, 0);
      *(uint4*)(d) = z; *(uint4*)(d + 8) = z; *(uint4*)(d + 16) = z; *(uint4*)(d + 24) = z;
    }
    __syncthreads();
#pragma unroll
    for (int tap = 0; tap < 9; tap++) {
      const int dy = tap / 3, dx = tap - dy * 3;
      const int kb = tap * 256 + cq * 32 + quad * 8;
      bf16x8 a0 = *(const bf16x8*)(woffA + (size_t)l15 * 2304 + kb);
      bf16x8 a1 = *(const bf16x8*)(woffA + (size_t)(l15 + 16) * 2304 + kb);
      bf16x8 bv = *(const bf16x8*)&Bs[dy][wv * 16 + l15 + dx][quad * 8];
      acc[0] = __builtin_amdgcn_mfma_f32_16x16x32_bf16(a0, bv, acc[0], 0, 0, 0);
      acc[1] = __builtin_amdgcn_mfma_f32_16x16x32_bf16(a1, bv, acc[1], 0, 0, 0);
    }
  }
  const int w = wv * 16 + l15;
#pragma unroll
  for (int tm = 0; tm < 2; tm++) {
#pragma unroll
    for (int r = 0; r < 4; r++) {
      int m = tm * 16 + quad * 4 + r;
      if (m < 27) {
        float bo = ldi(b_off, m, f);
        om[(size_t)((b * 27 + m) * 64 + h) * 64 + w] = acc[tm][r] + bo;
      }
    }
  }
}

// ---------- K1 fallback: 3x3 offset conv, pad 1.  om (8,27,64,64) fp32 ----------
__global__ __launch_bounds__(256) void k_offconv(
    const void* __restrict__ x, const void* __restrict__ b_off,
    const float* __restrict__ woffT, float* __restrict__ om) {
  const int f = g_isf32;
  const int h = blockIdx.x, b = blockIdx.y;
  const int t = threadIdx.x;
  const int cg = t & 31, wg = t >> 5;
  const int w0 = wg * 8;
  __shared__ float xs[32 * 204];
  float acc[8];
#pragma unroll
  for (int i = 0; i < 8; i++) acc[i] = 0.f;

  for (int cb = 0; cb < 256; cb += 32) {
    __syncthreads();
    for (int e = t; e < 32 * 192; e += 256) {
      int ci = e / 192, r = e - ci * 192;
      int dh = r >> 6, w = r & 63;
      int row = h + dh - 1;
      float v = 0.f;
      if (row >= 0 && row < 64)
        v = ldi(x, ((size_t)((b * 256 + cb + ci) * 64 + row) << 6) + w, f);
      xs[ci * 204 + dh * 68 + w + 1] = v;
    }
    for (int e = t; e < 96; e += 256) {
      int base = (e / 3) * 204 + (e - (e / 3) * 3) * 68;
      xs[base] = 0.f; xs[base + 65] = 0.f; xs[base + 66] = 0.f; xs[base + 67] = 0.f;
    }
    __syncthreads();

    for (int ci = 0; ci < 32; ci++) {
      float xr[3][12];
#pragma unroll
      for (int dh = 0; dh < 3; dh++) {
        const float* p = &xs[ci * 204 + dh * 68 + w0];
        float4 q0 = *(const float4*)(p);
        float4 q1 = *(const float4*)(p + 4);
        float4 q2 = *(const float4*)(p + 8);
        xr[dh][0] = q0.x; xr[dh][1] = q0.y; xr[dh][2] = q0.z; xr[dh][3] = q0.w;
        xr[dh][4] = q1.x; xr[dh][5] = q1.y; xr[dh][6] = q1.z; xr[dh][7] = q1.w;
        xr[dh][8] = q2.x; xr[dh][9] = q2.y; xr[dh][10] = q2.z; xr[dh][11] = q2.w;
      }
      if (cg < 27) {
        const float* wp = &woffT[(size_t)(cb + ci) * 243 + cg];
#pragma unroll
        for (int k = 0; k < 9; k++) {
          float wk = wp[k * 27];
          const int dh = k / 3, dx = k - (k / 3) * 3;
#pragma unroll
          for (int wi = 0; wi < 8; wi++)
            acc[wi] = fmaf(wk, xr[dh][wi + dx], acc[wi]);
        }
      }
    }
  }
  if (cg < 27) {
    float bo = ldi(b_off, cg, f);
    float* op = &om[(size_t)((b * 27 + cg) * 64 + h) * 64 + w0];
#pragma unroll
    for (int wi = 0; wi < 8; wi++) op[wi] = acc[wi] + bo;
  }
}

// ---------- K2 (fast): FUSED deformable sampling + MFMA GEMM, pipelined (R9) ----------
// h1[b](128,4096) = wdcnA(128,2304) x S_virtual(2304,4096).  grid (8 b, 128 nt).
// Software pipeline: step s+1's A-loads + corner gathers issue into REGISTERS
// right after step s's LDS writes, before the MFMA phase -> L2 latency hides
// under MFMA + barrier + other waves (T14 issue-early/write-late).
__global__ __launch_bounds__(256) void k_dcnf(
    const unsigned short* __restrict__ xT,   // [b][64][64][256] bf16
    const unsigned short* __restrict__ A,    // wdcnA [128][2304] bf16
    const float* __restrict__ om,            // [b][27][4096] f32
    const void* __restrict__ b_dcn,
    unsigned short* __restrict__ h1) {       // [b][128][4096] bf16
  const int f = g_isf32;
  const int b = blockIdx.x, nt = blockIdx.y;   // b fastest -> XCD pinning
  const int t = threadIdx.x;
  const int wv = t >> 6, L = t & 63, quad = L >> 4, l15 = L & 15;
  const int wm = wv * 32;                      // wave's 32 output-channel rows
  __shared__ unsigned short As[128][40];
  __shared__ unsigned short Bs[32][40];        // [pos][k pad40]
  __shared__ float          Wg[9][32][4];
  __shared__ unsigned short Wi[9][32][4];
  f32x4 acc[2][2] = {};
  const int p0 = nt * 32;

  // precompute per-(tap, pos) bilinear weights + clamped corner indices
  for (int e = t; e < 9 * 32; e += 256) {
    int k = e >> 5, p = e & 31;
    int pos = p0 + p;
    int hh = pos >> 6, ww = pos & 63;
    const float* ob = om + (size_t)(b * 27) * 4096 + pos;
    float oy = ob[(size_t)k * 4096];
    float ox = ob[(size_t)(k + 9) * 4096];
    float mm = ob[(size_t)(k + 18) * 4096];
    float msk = 1.f / (1.f + expf(-mm));
    float py = oy + (float)(hh - 1 + k / 3);
    float px = ox + (float)(ww - 1 + (k - (k / 3) * 3));
    float y0f = floorf(py), x0f = floorf(px);
    float ly = py - y0f, lx = px - x0f;
    int y0 = (int)y0f, x0 = (int)x0f;
    int y1 = y0 + 1, x1 = x0 + 1;
    float fy0 = (y0 >= 0 && y0 < 64) ? 1.f : 0.f;
    float fy1 = (y1 >= 0 && y1 < 64) ? 1.f : 0.f;
    float fx0 = (x0 >= 0 && x0 < 64) ? 1.f : 0.f;
    float fx1 = (x1 >= 0 && x1 < 64) ? 1.f : 0.f;
    int y0c = min(max(y0, 0), 63), y1c = min(max(y1, 0), 63);
    int x0c = min(max(x0, 0), 63), x1c = min(max(x1, 0), 63);
    Wg[k][p][0] = (1.f - ly) * (1.f - lx) * msk * fy0 * fx0;
    Wg[k][p][1] = (1.f - ly) * lx * msk * fy0 * fx1;
    Wg[k][p][2] = ly * (1.f - lx) * msk * fy1 * fx0;
    Wg[k][p][3] = ly * lx * msk * fy1 * fx1;
    Wi[k][p][0] = (unsigned short)(y0c * 64 + x0c);
    Wi[k][p][1] = (unsigned short)(y0c * 64 + x1c);
    Wi[k][p][2] = (unsigned short)(y1c * 64 + x0c);
    Wi[k][p][3] = (unsigned short)(y1c * 64 + x1c);
  }
  __syncthreads();   // Wg/Wi ready before first prefetch

  const unsigned short* xb = xT + ((size_t)b << 20);   // b * 4096 * 256
  const int sp = t >> 3, qc8 = t & 7;                  // pos 0..31, 4-ch segment
  const int am = t >> 1, aseg = t & 1;
  const unsigned short* aprow = A + (size_t)am * 2304 + aseg * 16;

  // pipeline registers
  uint4 pa0, pa1;
  uint2 pu0, pu1, pu2, pu3;
  float4 pg;

#define DCNF_ISSUE(S) {                                                   \
    int tap_ = (S) >> 3, cq_ = (S) & 7;                                   \
    int kb_ = tap_ * 256 + cq_ * 32;                                      \
    pa0 = *(const uint4*)(aprow + kb_);                                   \
    pa1 = *(const uint4*)(aprow + kb_ + 8);                               \
    pg  = *(const float4*)&Wg[tap_][sp][0];                               \
    uint2 wi2_ = *(const uint2*)&Wi[tap_][sp][0];                         \
    int i0_ = wi2_.x & 0xffff, i1_ = wi2_.x >> 16;                        \
    int i2_ = wi2_.y & 0xffff, i3_ = wi2_.y >> 16;                        \
    int cb_ = cq_ * 32 + qc8 * 4;                                         \
    pu0 = *(const uint2*)(xb + ((size_t)i0_ << 8) + cb_);                 \
    pu1 = *(const uint2*)(xb + ((size_t)i1_ << 8) + cb_);                 \
    pu2 = *(const uint2*)(xb + ((size_t)i2_ << 8) + cb_);                 \
    pu3 = *(const uint2*)(xb + ((size_t)i3_ << 8) + cb_);                 \
  }

  DCNF_ISSUE(0);
  for (int s = 0; s < 72; s++) {
    __syncthreads();   // previous MFMA reads done -> LDS writable
    // write A-tile from prefetch regs
    *(uint4*)&As[am][aseg * 16]     = pa0;
    *(uint4*)&As[am][aseg * 16 + 8] = pa1;
    // combine prefetched corners -> Bs
    {
      unsigned short e0[4], e1[4], e2[4], e3[4];
      *(uint2*)e0 = pu0; *(uint2*)e1 = pu1; *(uint2*)e2 = pu2; *(uint2*)e3 = pu3;
      float g0 = pg.x, g1 = pg.y, g2 = pg.z, g3 = pg.w;
      unsigned int r[2];
#pragma unroll
      for (int j = 0; j < 2; j++) {
        float va = g0 * bf2f(e0[2 * j])     + g1 * bf2f(e1[2 * j])
                 + g2 * bf2f(e2[2 * j])     + g3 * bf2f(e3[2 * j]);
        float vb = g0 * bf2f(e0[2 * j + 1]) + g1 * bf2f(e1[2 * j + 1])
                 + g2 * bf2f(e2[2 * j + 1]) + g3 * bf2f(e3[2 * j + 1]);
        r[j] = pk2(va, vb);
      }
      *(uint2*)&Bs[sp][qc8 * 4] = make_uint2(r[0], r[1]);
    }
    if (s < 71) DCNF_ISSUE(s + 1);   // prefetch next step (latency hides under MFMA)
    __syncthreads();   // LDS ready
    const int ar = quad * 8;
    bf16x8 af[2], bfr[2];
#pragma unroll
    for (int tm = 0; tm < 2; tm++) af[tm]  = *(const bf16x8*)&As[wm + tm * 16 + l15][ar];
#pragma unroll
    for (int tn = 0; tn < 2; tn++) bfr[tn] = *(const bf16x8*)&Bs[tn * 16 + l15][ar];
#pragma unroll
    for (int tm = 0; tm < 2; tm++)
#pragma unroll
      for (int tn = 0; tn < 2; tn++)
        acc[tm][tn] = __builtin_amdgcn_mfma_f32_16x16x32_bf16(af[tm], bfr[tn], acc[tm][tn], 0, 0, 0);
  }
#undef DCNF_ISSUE

#pragma unroll
  for (int tm = 0; tm < 2; tm++) {
#pragma unroll
    for (int r = 0; r < 4; r++) {
      int m = wm + tm * 16 + quad * 4 + r;
      float bd = ldi(b_dcn, m, f);
#pragma unroll
      for (int tn = 0; tn < 2; tn++) {
        float v = acc[tm][tn][r] + bd;
        int n = p0 + tn * 16 + l15;
        h1[(size_t)(b * 128 + m) * 4096 + n] = f2bf(v);
      }
    }
  }
}

// ---------- K_stats1: per-channel sum/sumsq of h1 -> g_stats[0..255] ----------
__global__ __launch_bounds__(256) void k_stats1(const unsigned short* __restrict__ h1) {
  const int m = blockIdx.x, b = blockIdx.y;
  const int t = threadIdx.x;
  const unsigned short* p = h1 + (size_t)(b * 128 + m) * 4096 + t * 16;
  uint4 q0 = *(const uint4*)p;
  uint4 q1 = *(const uint4*)(p + 8);
  unsigned short e[16];
  *(uint4*)&e[0] = q0; *(uint4*)&e[8] = q1;
  float s = 0.f, q = 0.f;
#pragma unroll
  for (int j = 0; j < 16; j++) { float v = bf2f(e[j]); s += v; q += v * v; }
#pragma unroll
  for (int msk = 1; msk < 64; msk <<= 1) {
    s += __shfl_xor(s, msk, 64);
    q += __shfl_xor(q, msk, 64);
  }
  if ((t & 63) == 0) { atomicAdd(&g_stats[m], s); atomicAdd(&g_stats[128 + m], q); }
}

// ---------- K2 fallback: fused sampling + fp32 GEMM ----------
__global__ __launch_bounds__(256) void k_dcn(
    const void* __restrict__ x, const float* __restrict__ om,
    const float* __restrict__ wdcnT, const void* __restrict__ b_dcn,
    unsigned short* __restrict__ h1) {
  const int f = g_isf32;
  const int h = blockIdx.x, b = blockIdx.y;
  const int t = threadIdx.x;
  __shared__ float S[64 * 64];
  __shared__ int   midx[64][4];
  __shared__ float mwgt[64][4];
  const int og = t >> 4, pg = t & 15;
  const int pA = t & 63, cgA = t >> 6;
  float acc[8][4];
#pragma unroll
  for (int j = 0; j < 8; j++)
#pragma unroll
    for (int i = 0; i < 4; i++) acc[j][i] = 0.f;

  for (int k = 0; k < 9; k++) {
    if (t < 64) {
      const int w = t;
      const float* ob = &om[(size_t)(b * 27) * 4096 + h * 64 + w];
      float oy = ob[(size_t)k * 4096];
      float ox = ob[(size_t)(k + 9) * 4096];
      float mm = ob[(size_t)(k + 18) * 4096];
      float msk = 1.f / (1.f + expf(-mm));
      float py = oy + (float)(h - 1 + k / 3);
      float px = ox + (float)(w - 1 + (k - (k / 3) * 3));
      float y0f = floorf(py), x0f = floorf(px);
      float ly = py - y0f, lx = px - x0f;
      int y0 = (int)y0f, x0 = (int)x0f;
      int y1 = y0 + 1, x1 = x0 + 1;
      float fy0 = (y0 >= 0 && y0 < 64) ? 1.f : 0.f;
      float fy1 = (y1 >= 0 && y1 < 64) ? 1.f : 0.f;
      float fx0 = (x0 >= 0 && x0 < 64) ? 1.f : 0.f;
      float fx1 = (x1 >= 0 && x1 < 64) ? 1.f : 0.f;
      int y0c = min(max(y0, 0), 63), y1c = min(max(y1, 0), 63);
      int x0c = min(max(x0, 0), 63), x1c = min(max(x1, 0), 63);
      midx[w][0] = y0c * 64 + x0c;
      midx[w][1] = y0c * 64 + x1c;
      midx[w][2] = y1c * 64 + x0c;
      midx[w][3] = y1c * 64 + x1c;
      mwgt[w][0] = (1.f - ly) * (1.f - lx) * msk * fy0 * fx0;
      mwgt[w][1] = (1.f - ly) * lx * msk * fy0 * fx1;
      mwgt[w][2] = ly * (1.f - lx) * msk * fy1 * fx0;
      mwgt[w][3] = ly * lx * msk * fy1 * fx1;
    }
    for (int ch = 0; ch < 4; ch++) {
      __syncthreads();
      {
        const int i0 = midx[pA][0], i1 = midx[pA][1], i2 = midx[pA][2], i3 = midx[pA][3];
        const float g0 = mwgt[pA][0], g1 = mwgt[pA][1], g2 = mwgt[pA][2], g3 = mwgt[pA][3];
        const size_t cbase = (size_t)(b * 256 + ch * 64 + cgA * 16) * 4096;
        float* Sp = &S[(cgA * 16) * 64 + pA];
#pragma unroll 4
        for (int j = 0; j < 16; j++) {
          const size_t xo = cbase + (size_t)j * 4096;
          float v = g0 * ldi(x, xo + i0, f) + g1 * ldi(x, xo + i1, f)
                  + g2 * ldi(x, xo + i2, f) + g3 * ldi(x, xo + i3, f);
          Sp[j * 64] = v;
        }
      }
      __syncthreads();
      const float* wk = wdcnT + (size_t)k * 32768 + (size_t)(ch * 64) * 128;
#pragma unroll 2
      for (int c2 = 0; c2 < 64; c2++) {
        float4 a0 = *(const float4*)&wk[c2 * 128 + og * 8];
        float4 a1 = *(const float4*)&wk[c2 * 128 + og * 8 + 4];
        float4 s4 = *(const float4*)&S[c2 * 64 + pg * 4];
        float aa[8] = {a0.x, a0.y, a0.z, a0.w, a1.x, a1.y, a1.z, a1.w};
        float ss[4] = {s4.x, s4.y, s4.z, s4.w};
#pragma unroll
        for (int j = 0; j < 8; j++)
#pragma unroll
          for (int i = 0; i < 4; i++)
            acc[j][i] = fmaf(aa[j], ss[i], acc[j][i]);
      }
    }
  }
#pragma unroll
  for (int j = 0; j < 8; j++) {
    const int o = og * 8 + j;
    float bd = ldi(b_dcn, o, f);
    float v0 = acc[j][0] + bd, v1 = acc[j][1] + bd, v2 = acc[j][2] + bd, v3 = acc[j][3] + bd;
    float s = v0 + v1 + v2 + v3;
    float q = v0 * v0 + v1 * v1 + v2 * v2 + v3 * v3;
    uint2 pkv = make_uint2(pk2(v0, v1), pk2(v2, v3));
    *(uint2*)(h1 + (size_t)((b * 128 + o) * 64 + h) * 64 + pg * 4) = pkv;
#pragma unroll
    for (int m = 1; m < 16; m <<= 1) {
      s += __shfl_xor(s, m, 64);
      q += __shfl_xor(q, m, 64);
    }
    if (pg == 0) { atomicAdd(&g_stats[o], s); atomicAdd(&g_stats[128 + o], q); }
  }
}

// ---------- K3 (fast): BN1 + ReLU + transpose  h1[b][ch][pos] -> h1T[b][pos][ch] ----------
__global__ __launch_bounds__(256) void k_bn1t(
    const unsigned short* __restrict__ h1, const void* __restrict__ g1,
    const void* __restrict__ be1, unsigned short* __restrict__ h1T) {
  const int f = g_isf32;
  const int pt = blockIdx.x, chh = blockIdx.y, b = blockIdx.z;
  const int t = threadIdx.x;
  __shared__ unsigned short T[64][72];
  const int c0 = chh * 64, p0 = pt * 64;
  {
    int cl = t >> 2, q = t & 3;
    int o = c0 + cl;
    float mu = g_stats[o] * (1.f / 32768.f);
    float var = g_stats[128 + o] * (1.f / 32768.f) - mu * mu;
    float sc = rsqrtf(var + 1e-5f) * ldi(g1, o, f);
    float sh = ldi(be1, o, f) - mu * sc;
    const unsigned short* hp = h1 + (size_t)(b * 128 + o) * 4096 + p0 + q * 16;
    uint4 q0 = *(const uint4*)hp, q1 = *(const uint4*)(hp + 8);
    unsigned short e[16], r[16];
    *(uint4*)&e[0] = q0; *(uint4*)&e[8] = q1;
#pragma unroll
    for (int j = 0; j < 16; j++)
      r[j] = f2bf(fmaxf(fmaf(bf2f(e[j]), sc, sh), 0.f));
    *(uint4*)&T[cl][q * 16]     = *(uint4*)&r[0];
    *(uint4*)&T[cl][q * 16 + 8] = *(uint4*)&r[8];
  }
  __syncthreads();
  {
    int pl = t >> 2, qc = t & 3;
    unsigned short r[16];
#pragma unroll
    for (int j = 0; j < 16; j++) r[j] = T[qc * 16 + j][pl];
    unsigned short* op = h1T + (size_t)(b * 4096 + p0 + pl) * 128 + c0 + qc * 16;
    *(uint4*)op       = *(uint4*)&r[0];
    *(uint4*)(op + 8) = *(uint4*)&r[8];
  }
}

// ---------- K3 fallback: BN1 + ReLU in place on h1 ----------
__global__ void k_bn1(unsigned short* __restrict__ h1, const void* __restrict__ g1,
                      const void* __restrict__ be1) {
  const int f = g_isf32;
  int gid = blockIdx.x * 256 + threadIdx.x;
  size_t base = (size_t)gid * 8;
  int o = (int)((base >> 12) & 127);
  float mu = g_stats[o] * (1.f / 32768.f);
  float var = g_stats[128 + o] * (1.f / 32768.f) - mu * mu;
  float sc = rsqrtf(var + 1e-5f) * ldi(g1, o, f);
  float sh = ldi(be1, o, f) - mu * sc;
  uint4 p = *(const uint4*)(h1 + base);
  unsigned int pp[4] = {p.x, p.y, p.z, p.w};
  unsigned int r[4];
#pragma unroll
  for (int i = 0; i < 4; i++) {
    float f0 = fmaxf(fmaf(bf2f((unsigned short)(pp[i] & 0xffff)), sc, sh), 0.f);
    float f1 = fmaxf(fmaf(bf2f((unsigned short)(pp[i] >> 16)), sc, sh), 0.f);
    r[i] = pk2(f0, f1);
  }
  *(uint4*)(h1 + base) = make_uint4(r[0], r[1], r[2], r[3]);
}

// ---------- K4 (fast): parity-decomposed transposed conv as MFMA GEMM, pipelined ----------
// grid (nt=32, par=4, b=8).  Register-prefetch of next step's A/B global loads
// issued right after LDS writes (R9 k_dcnf pattern): L2 latency hides under MFMA.
__global__ __launch_bounds__(256) void k_ctgemm(
    const unsigned short* __restrict__ h1T,  // [b][4096 pos][128 ch]
    const unsigned short* __restrict__ Apar,
    void* __restrict__ out2p) {
  const int f = g_isf32;
  const int nt = blockIdx.x, par = blockIdx.y, b = blockIdx.z;
  const int py = par >> 1, px = par & 1;
  const int t = threadIdx.x;
  const int wv = t >> 6, L = t & 63;
  const int quad = L >> 4, l15 = L & 15;
  const int wm = (wv >> 1) * 64, wn = (wv & 1) * 64;
  __shared__ unsigned short As[128][40];
  __shared__ unsigned short Bs[128][40];
  f32x4 acc[4][4] = {};
  const int y0 = nt * 2;
  const unsigned short* Ap = Apar + (size_t)par * 128 * 512;
  const unsigned short* hb = h1T + (size_t)b * 4096 * 128;
  const int sp = t >> 1, shalf = t & 1;
  const int srr = sp >> 6, sx = sp & 63;
  const int am = t >> 1, aseg = t & 1;

  uint4 pA0, pA1, pB0, pB1;

#define CT_ISSUE(STEP) {                                                  \
    int kk_ = (STEP) * 32;                                                \
    int tap_ = kk_ >> 7, ic_ = kk_ & 127;                                 \
    int a_ = tap_ >> 1, bb_ = tap_ & 1;                                   \
    int ya_ = (py == 0) ? (a_ ? -1 : 0) : (a_ ? 0 : 1);                   \
    int xb_ = (px == 0) ? (bb_ ? -1 : 0) : (bb_ ? 0 : 1);                 \
    const unsigned short* ap_ = Ap + (size_t)am * 512 + kk_ + aseg * 16;  \
    pA0 = *(const uint4*)(ap_);                                           \
    pA1 = *(const uint4*)(ap_ + 8);                                       \
    int srcy_ = y0 + srr + ya_;                                           \
    int srcx_ = sx + xb_;                                                 \
    pB0 = make_uint4(0, 0, 0, 0); pB1 = pB0;                              \
    if (srcy_ >= 0 && srcy_ < 64 && srcx_ >= 0 && srcx_ < 64) {           \
      const unsigned short* hp_ = hb + ((size_t)(srcy_ * 64 + srcx_)) * 128 + ic_ + shalf * 16; \
      pB0 = *(const uint4*)(hp_);                                         \
      pB1 = *(const uint4*)(hp_ + 8);                                     \
    }                                                                     \
  }

  CT_ISSUE(0);
  for (int step = 0; step < 16; step++) {
    __syncthreads();                     // prev MFMA done reading LDS
    *(uint4*)&As[am][aseg * 16]     = pA0;
    *(uint4*)&As[am][aseg * 16 + 8] = pA1;
    *(uint4*)&Bs[sp][shalf * 16]     = pB0;
    *(uint4*)&Bs[sp][shalf * 16 + 8] = pB1;
    if (step < 15) CT_ISSUE(step + 1);   // prefetch; latency hides under MFMA
    __syncthreads();
    const int ar = quad * 8;
    bf16x8 af[4], bfr[4];
#pragma unroll
    for (int tm = 0; tm < 4; tm++) af[tm]  = *(const bf16x8*)&As[wm + tm * 16 + l15][ar];
#pragma unroll
    for (int tn = 0; tn < 4; tn++) bfr[tn] = *(const bf16x8*)&Bs[wn + tn * 16 + l15][ar];
#pragma unroll
    for (int tm = 0; tm < 4; tm++)
#pragma unroll
      for (int tn = 0; tn < 4; tn++)
        acc[tm][tn] = __builtin_amdgcn_mfma_f32_16x16x32_bf16(af[tm], bfr[tn], acc[tm][tn], 0, 0, 0);
  }
#undef CT_ISSUE

  const size_t obase = (size_t)((par * 8 + b) * 128) * 4096;
#pragma unroll
  for (int tm = 0; tm < 4; tm++) {
#pragma unroll
    for (int r = 0; r < 4; r++) {
      int m = wm + tm * 16 + quad * 4 + r;
#pragma unroll
      for (int tn = 0; tn < 4; tn++) {
        float v = acc[tm][tn][r];
        int n = wn + tn * 16 + l15;
        size_t ofs = obase + (size_t)m * 4096 + (size_t)((y0 + (n >> 6)) * 64 + (n & 63));
        if (f) ((float*)out2p)[ofs] = v;
        else   ((unsigned short*)out2p)[ofs] = f2bf(v);
      }
    }
  }
}

// ---------- K_stats2: per-channel sum/sumsq of out2p -> g_stats[256..511] ----------
__global__ __launch_bounds__(256) void k_stats2(const void* __restrict__ out2p) {
  const int f = g_isf32;
  const int m = blockIdx.x, pb = blockIdx.y;
  const int t = threadIdx.x;
  size_t base = ((size_t)pb * 128 + m) * 4096 + (size_t)t * 16;
  float s = 0.f, q = 0.f;
  if (f) {
    const float* p = (const float*)out2p + base;
#pragma unroll
    for (int j = 0; j < 4; j++) {
      float4 v = *(const float4*)(p + j * 4);
      s += v.x + v.y + v.z + v.w;
      q += v.x * v.x + v.y * v.y + v.z * v.z + v.w * v.w;
    }
  } else {
    const unsigned short* p = (const unsigned short*)out2p + base;
    uint4 q0 = *(const uint4*)p, q1 = *(const uint4*)(p + 8);
    unsigned short e[16];
    *(uint4*)&e[0] = q0; *(uint4*)&e[8] = q1;
#pragma unroll
    for (int j = 0; j < 16; j++) { float v = bf2f(e[j]); s += v; q += v * v; }
  }
#pragma unroll
  for (int msk = 1; msk < 64; msk <<= 1) {
    s += __shfl_xor(s, msk, 64);
    q += __shfl_xor(q, msk, 64);
  }
  if ((t & 63) == 0) { atomicAdd(&g_stats[256 + m], s); atomicAdd(&g_stats[384 + m], q); }
}

// ---------- K5 (fast): BN2 + ReLU + parity de-interleave -> d_out ----------
__global__ __launch_bounds__(256) void k_bn2f(
    const void* __restrict__ out2p, const void* __restrict__ g2,
    const void* __restrict__ be2, void* __restrict__ out) {
  const int f = g_isf32;
  const int m = blockIdx.x, b = blockIdx.y;
  const int t = threadIdx.x;
  float mu = g_stats[256 + m] * (1.f / 131072.f);
  float var = g_stats[384 + m] * (1.f / 131072.f) - mu * mu;
  float sc = rsqrtf(var + 1e-5f) * ldi(g2, m, f);
  float sh = ldi(be2, m, f) - mu * sc;
  const int row8 = t >> 3, xseg = t & 7;
  const int xh0 = xseg * 8;
#pragma unroll
  for (int pss = 0; pss < 4; pss++) {
    int yy = pss * 32 + row8;
    int y = yy >> 1, py = yy & 1;
    size_t s0 = ((size_t)((py * 2 + 0) * 8 + b) * 128 + m) * 4096 + (size_t)(y * 64 + xh0);
    size_t s1 = ((size_t)((py * 2 + 1) * 8 + b) * 128 + m) * 4096 + (size_t)(y * 64 + xh0);
    float v0[8], v1[8];
    if (f) {
      const float* p0 = (const float*)out2p + s0;
      const float* p1 = (const float*)out2p + s1;
      float4 a0 = *(const float4*)p0, a1 = *(const float4*)(p0 + 4);
      float4 c0 = *(const float4*)p1, c1 = *(const float4*)(p1 + 4);
      v0[0] = a0.x; v0[1] = a0.y; v0[2] = a0.z; v0[3] = a0.w;
      v0[4] = a1.x; v0[5] = a1.y; v0[6] = a1.z; v0[7] = a1.w;
      v1[0] = c0.x; v1[1] = c0.y; v1[2] = c0.z; v1[3] = c0.w;
      v1[4] = c1.x; v1[5] = c1.y; v1[6] = c1.z; v1[7] = c1.w;
    } else {
      const unsigned short* p0 = (const unsigned short*)out2p + s0;
      const unsigned short* p1 = (const unsigned short*)out2p + s1;
      uint4 u0 = *(const uint4*)p0, u1 = *(const uint4*)p1;
      unsigned short e0[8], e1[8];
      *(uint4*)&e0[0] = u0; *(uint4*)&e1[0] = u1;
#pragma unroll
      for (int j = 0; j < 8; j++) { v0[j] = bf2f(e0[j]); v1[j] = bf2f(e1[j]); }
    }
    float r[16];
#pragma unroll
    for (int i = 0; i < 8; i++) {
      r[2 * i]     = fmaxf(fmaf(v0[i], sc, sh), 0.f);
      r[2 * i + 1] = fmaxf(fmaf(v1[i], sc, sh), 0.f);
    }
    size_t ob = (size_t)(b * 128 + m) * 16384 + (size_t)yy * 128 + (size_t)(xh0 * 2);
    if (f) {
      float* op = (float*)out + ob;
#pragma unroll
      for (int v4 = 0; v4 < 4; v4++)
        ((float4*)op)[v4] = make_float4(r[4 * v4], r[4 * v4 + 1], r[4 * v4 + 2], r[4 * v4 + 3]);
    } else {
      unsigned short* op = (unsigned short*)out + ob;
      unsigned int w_[8];
#pragma unroll
      for (int i = 0; i < 8; i++) w_[i] = pk2(r[2 * i], r[2 * i + 1]);
      *(uint4*)(op)     = make_uint4(w_[0], w_[1], w_[2], w_[3]);
      *(uint4*)(op + 8) = make_uint4(w_[4], w_[5], w_[6], w_[7]);
    }
  }
}

// ---------- K4 fallback: fp32 VALU transposed conv ----------
__global__ __launch_bounds__(256) void k_ctconv(
    const unsigned short* __restrict__ h1n, const float* __restrict__ wctT,
    void* __restrict__ out2) {
  const int f = g_isf32;
  const int y = blockIdx.x, b = blockIdx.y;
  const int t = threadIdx.x;
  const int og = t >> 3, xg = t & 7;
  __shared__ float hs[2 * 32 * 68];
  int kr0, kr1, r0, r1;
  if ((y & 1) == 0) { kr0 = 1; r0 = y >> 1; kr1 = 3; r1 = (y >> 1) - 1; }
  else              { kr0 = 0; r0 = (y + 1) >> 1; kr1 = 2; r1 = (y - 1) >> 1; }
  float acc[4][16];
#pragma unroll
  for (int j = 0; j < 4; j++)
#pragma unroll
    for (int i = 0; i < 16; i++) acc[j][i] = 0.f;

  for (int ihc = 0; ihc < 4; ihc++) {
    __syncthreads();
    for (int e = t; e < 2 * 32 * 64; e += 256) {
      int rr = e >> 11, rem = e & 2047, il = rem >> 6, w = rem & 63;
      int i = ihc * 32 + il;
      int row = rr ? r1 : r0;
      float v = 0.f;
      if (row >= 0 && row < 64)
        v = bf2f(h1n[(size_t)((b * 128 + i) * 64 + row) * 64 + w]);
      hs[(rr * 32 + il) * 68 + w + 1] = v;
    }
    for (int e = t; e < 64; e += 256) {
      int base = e * 68;
      hs[base] = 0.f; hs[base + 65] = 0.f; hs[base + 66] = 0.f; hs[base + 67] = 0.f;
    }
    __syncthreads();
    for (int il = 0; il < 32; il++) {
      const int i = ihc * 32 + il;
      float br[2][12];
#pragma unroll
      for (int rr = 0; rr < 2; rr++) {
        const float* p = &hs[(rr * 32 + il) * 68 + xg * 8];
        float4 q0 = *(const float4*)(p);
        float4 q1 = *(const float4*)(p + 4);
        float4 q2 = *(const float4*)(p + 8);
        br[rr][0] = q0.x; br[rr][1] = q0.y; br[rr][2] = q0.z; br[rr][3] = q0.w;
        br[rr][4] = q1.x; br[rr][5] = q1.y; br[rr][6] = q1.z; br[rr][7] = q1.w;
        br[rr][8] = q2.x; br[rr][9] = q2.y; br[rr][10] = q2.z; br[rr][11] = q2.w;
      }
      float a[2][4][4];
#pragma unroll
      for (int rr = 0; rr < 2; rr++) {
        const int krr = rr ? kr1 : kr0;
#pragma unroll
        for (int kc = 0; kc < 4; kc++) {
          float4 av = *(const float4*)&wctT[((size_t)(krr * 4 + kc) * 128 + i) * 128 + og * 4];
          a[rr][kc][0] = av.x; a[rr][kc][1] = av.y; a[rr][kc][2] = av.z; a[rr][kc][3] = av.w;
        }
      }
#pragma unroll
      for (int xi = 0; xi < 16; xi++) {
        const int u = xi >> 1;
        const int kcA = (xi & 1) ? 0 : 1;
        const int lwA = (xi & 1) ? u + 2 : u + 1;
        const int kcB = (xi & 1) ? 2 : 3;
        const int lwB = (xi & 1) ? u + 1 : u;
#pragma unroll
        for (int rr = 0; rr < 2; rr++) {
#pragma unroll
          for (int j = 0; j < 4; j++) {
            acc[j][xi] = fmaf(a[rr][kcA][j], br[rr][lwA], acc[j][xi]);
            acc[j][xi] = fmaf(a[rr][kcB][j], br[rr][lwB], acc[j][xi]);
          }
        }
      }
    }
  }
#pragma unroll
  for (int j = 0; j < 4; j++) {
    const int o = og * 4 + j;
    float s = 0.f, q = 0.f;
#pragma unroll
    for (int xi = 0; xi < 16; xi++) { s += acc[j][xi]; q += acc[j][xi] * acc[j][xi]; }
    size_t ofs = (size_t)((b * 128 + o) * 128 + y) * 128 + xg * 16;
    if (f) {
      float* op = (float*)out2 + ofs;
#pragma unroll
      for (int v4 = 0; v4 < 4; v4++)
        ((float4*)op)[v4] = make_float4(acc[j][4 * v4], acc[j][4 * v4 + 1],
                                        acc[j][4 * v4 + 2], acc[j][4 * v4 + 3]);
    } else {
      unsigned int w_[8];
#pragma unroll
      for (int xi = 0; xi < 8; xi++) w_[xi] = pk2(acc[j][2 * xi], acc[j][2 * xi + 1]);
      unsigned short* op = (unsigned short*)out2 + ofs;
      *(uint4*)(op)     = make_uint4(w_[0], w_[1], w_[2], w_[3]);
      *(uint4*)(op + 8) = make_uint4(w_[4], w_[5], w_[6], w_[7]);
    }
#pragma unroll
    for (int m = 1; m < 8; m <<= 1) {
      s += __shfl_xor(s, m, 64);
      q += __shfl_xor(q, m, 64);
    }
    if (xg == 0) { atomicAdd(&g_stats[256 + o], s); atomicAdd(&g_stats[384 + o], q); }
  }
}

// ---------- K5 fallback: BN2 + ReLU in place on d_out ----------
__global__ void k_bn2(void* __restrict__ out2, const void* __restrict__ g2,
                      const void* __restrict__ be2) {
  const int f = g_isf32;
  int gid = blockIdx.x * 256 + threadIdx.x;
  size_t base = (size_t)gid * 8;
  int o = (int)((base >> 14) & 127);
  float mu = g_stats[256 + o] * (1.f / 131072.f);
  float var = g_stats[384 + o] * (1.f / 131072.f) - mu * mu;
  float sc = rsqrtf(var + 1e-5f) * ldi(g2, o, f);
  float sh = ldi(be2, o, f) - mu * sc;
  if (f) {
    float4* op = (float4*)out2 + gid * 2;
    float4 p0 = op[0], p1 = op[1];
    p0.x = fmaxf(fmaf(p0.x, sc, sh), 0.f); p0.y = fmaxf(fmaf(p0.y, sc, sh), 0.f);
    p0.z = fmaxf(fmaf(p0.z, sc, sh), 0.f); p0.w = fmaxf(fmaf(p0.w, sc, sh), 0.f);
    p1.x = fmaxf(fmaf(p1.x, sc, sh), 0.f); p1.y = fmaxf(fmaf(p1.y, sc, sh), 0.f);
    p1.z = fmaxf(fmaf(p1.z, sc, sh), 0.f); p1.w = fmaxf(fmaf(p1.w, sc, sh), 0.f);
    op[0] = p0; op[1] = p1;
  } else {
    unsigned short* ob = (unsigned short*)out2 + base;
    uint4 p = *(const uint4*)ob;
    unsigned int pp[4] = {p.x, p.y, p.z, p.w};
    unsigned int r[4];
#pragma unroll
    for (int i = 0; i < 4; i++) {
      float f0 = fmaxf(fmaf(bf2f((unsigned short)(pp[i] & 0xffff)), sc, sh), 0.f);
      float f1 = fmaxf(fmaf(bf2f((unsigned short)(pp[i] >> 16)), sc, sh), 0.f);
      r[i] = pk2(f0, f1);
    }
    *(uint4*)ob = make_uint4(r[0], r[1], r[2], r[3]);
  }
}

// ---------- launch ----------
extern "C" void kernel_launch(void* const* d_in, const int* in_sizes, int n_in,
                              void* d_out, int out_size, void* d_ws, size_t ws_size,
                              hipStream_t stream) {
  const void* x     = d_in[0];
  const void* w_off = d_in[1];
  const void* b_off = d_in[2];
  const void* w_dcn = d_in[3];
  const void* b_dcn = d_in[4];
  const void* g1    = d_in[5];
  const void* be1   = d_in[6];
  const void* w_ct  = d_in[7];
  const void* g2    = d_in[8];
  const void* be2   = d_in[9];

  char* ws = (char*)d_ws;
  const bool fast = ws_size >= (size_t)166000000;

  unsigned short* h1; float* om; float* wdcnT; float* wctT;
  float* woffT; unsigned short* wdcnA; unsigned short* AparB; unsigned short* h1T;
  void* out2p; unsigned short* xT; unsigned short* woffA;
  if (fast) {
    // fully disjoint fast-path layout (~108 MB total, no aliasing)
    xT    = (unsigned short*)(ws + 0);            //  16,777,216
    h1    = (unsigned short*)(ws + 16777216);     //   8,388,608
    h1T   = (unsigned short*)(ws + 25165824);     //   8,388,608
    out2p = (void*)(ws + 33554432);               // <=67,108,864
    om    = (float*)(ws + 100663296);             //   3,538,944
    wctT  = (float*)(ws + 104202240);             //   1,048,576
    AparB = (unsigned short*)(ws + 105250816);    //     524,288
    wdcnA = (unsigned short*)(ws + 105775104);    //     589,824
    woffA = (unsigned short*)(ws + 106364928);    //     147,456
    woffT = (float*)(ws + 106512384);             //     248,832 (k_prep writes; unused fast)
    wdcnT = (float*)(ws + 106761216);             //   1,179,648 (k_prep writes; unused fast)
  } else {
    h1    = (unsigned short*)(ws + 0);
    om    = (float*)(ws + 8388608);
    wdcnT = (float*)(ws + 11927552);
    wctT  = (float*)(ws + 13107200);
    woffT = (float*)(ws + 14155776);
    wdcnA = (unsigned short*)(ws + 14404608);
    woffA = (unsigned short*)(ws + 14994432);
    AparB = nullptr;
    h1T   = nullptr;
    out2p = nullptr;
    xT    = nullptr;
  }

  k_detect<<<dim3(1), 256, 0, stream>>>((const unsigned short*)x);
  k_prep<<<dim3(3859), 256, 0, stream>>>(w_dcn, w_ct, w_off, wdcnT, wctT, woffT, wdcnA, woffA);
  if (fast) {
    k_xt<<<dim3(64, 4, 8), 256, 0, stream>>>(x, xT);
    k_offmfma<<<dim3(64, 8), 256, 0, stream>>>(xT, woffA, b_off, om);
    k_prep2<<<dim3(1024), 256, 0, stream>>>(wctT, AparB);
    k_dcnf<<<dim3(8, 128), 256, 0, stream>>>(xT, wdcnA, om, b_dcn, h1);
    k_stats1<<<dim3(128, 8), 256, 0, stream>>>(h1);
    k_bn1t<<<dim3(64, 2, 8), 256, 0, stream>>>(h1, g1, be1, h1T);
    k_ctgemm<<<dim3(32, 4, 8), 256, 0, stream>>>(h1T, AparB, out2p);
    k_stats2<<<dim3(128, 32), 256, 0, stream>>>(out2p);
    k_bn2f<<<dim3(128, 8), 256, 0, stream>>>(out2p, g2, be2, d_out);
  } else {
    k_offconv<<<dim3(64, 8), 256, 0, stream>>>(x, b_off, woffT, om);
    k_dcn<<<dim3(64, 8), 256, 0, stream>>>(x, om, wdcnT, b_dcn, h1);
    k_bn1<<<dim3(2048), 256, 0, stream>>>(h1, g1, be1);
    k_ctconv<<<dim3(128, 8), 256, 0, stream>>>(h1, wctT, d_out);
    k_bn2<<<dim3(8192), 256, 0, stream>>>(d_out, g2, be2);
  }
}

// Round 12
// 347.394 us; speedup vs baseline: 1.1440x; 1.0440x over previous
//
#include <hip/hip_runtime.h>
#include <stdint.h>

// ---------- device globals: dtype flag + BN stats ----------
__device__ int   g_isf32;
__device__ float g_stats[512];  // [0:128) s1sum, [128:256) s1sq, [256:384) s2sum, [384:512) s2sq

typedef __attribute__((ext_vector_type(8))) short bf16x8;
typedef __attribute__((ext_vector_type(4))) float f32x4;

// ---------- bf16 helpers ----------
__device__ __forceinline__ float bf2f(unsigned short u) {
  union { unsigned int i; float f; } v; v.i = ((unsigned int)u) << 16; return v.f;
}
__device__ __forceinline__ unsigned short f2bf(float f) {
  union { float f; unsigned int i; } v; v.f = f;
  unsigned int r = v.i + 0x7FFFu + ((v.i >> 16) & 1u);
  return (unsigned short)(r >> 16);
}
__device__ __forceinline__ unsigned int pk2(float a, float b) {
  return (unsigned int)f2bf(a) | ((unsigned int)f2bf(b) << 16);
}
// dtype-flex input load: f ? fp32 : bf16
__device__ __forceinline__ float ldi(const void* p, size_t i, int f) {
  return f ? ((const float*)p)[i] : bf2f(((const unsigned short*)p)[i]);
}

// ---------- K0: dtype detector + stats zeroing ----------
__global__ void k_detect(const unsigned short* __restrict__ x) {
  __shared__ int cnt;
  const int t = threadIdx.x;
  if (t == 0) cnt = 0;
  g_stats[t] = 0.f; g_stats[t + 256] = 0.f;
  __syncthreads();
  int c = 0;
  for (int j = 0; j < 16; j++) {
    unsigned short u = x[t * 16 + j];
    int e = (u >> 7) & 0xFF;
    if (e == 0xFF || (e != 0 && e <= 100)) c++;
  }
  atomicAdd(&cnt, c);
  __syncthreads();
  if (t == 0) g_isf32 = (cnt > 256) ? 1 : 0;
}

// ---------- K_prep: weights -> GEMM-friendly layouts ----------
// jobs: wdcnT 294912 | wctT 262144 | woffT 62208 | wdcnA 294912 | woffA 73728
__global__ void k_prep(const void* __restrict__ w_dcn, const void* __restrict__ w_ct,
                       const void* __restrict__ w_off,
                       float* __restrict__ wdcnT, float* __restrict__ wctT,
                       float* __restrict__ woffT, unsigned short* __restrict__ wdcnA,
                       unsigned short* __restrict__ woffA) {
  const int f = g_isf32;
  int idx = blockIdx.x * 256 + threadIdx.x;
  if (idx < 294912) {
    int k = idx / 32768, c = (idx >> 7) & 255, o = idx & 127;
    wdcnT[idx] = ldi(w_dcn, (size_t)(o * 256 + c) * 9 + k, f);
  }
  int i2 = idx - 294912;
  if (i2 >= 0 && i2 < 262144) {
    int kr = i2 >> 16, kc = (i2 >> 14) & 3, i = (i2 >> 7) & 127, o = i2 & 127;
    wctT[i2] = ldi(w_ct, (size_t)((i * 128 + o) * 4 + kr) * 4 + kc, f);
  }
  int i3 = idx - (294912 + 262144);
  if (i3 >= 0 && i3 < 62208) {
    int ci = i3 / 243, r = i3 - ci * 243, k = r / 27, c = r - (r / 27) * 27;
    woffT[i3] = ldi(w_off, (size_t)(c * 256 + ci) * 9 + k, f);
  }
  int i4 = idx - 619264;
  if (i4 >= 0 && i4 < 294912) {
    int o = i4 / 2304, rem = i4 - o * 2304;
    int k = rem >> 8, c = rem & 255;
    wdcnA[i4] = f2bf(ldi(w_dcn, (size_t)(o * 256 + c) * 9 + k, f));
  }
  int i5 = idx - 914176;
  if (i5 >= 0 && i5 < 73728) {       // woffA[m=32][k = tap*256 + ci] bf16, m>=27 zero
    int m = i5 / 2304, r = i5 - m * 2304;
    int tap = r >> 8, ci = r & 255;
    float v = (m < 27) ? ldi(w_off, (size_t)(m * 256 + ci) * 9 + tap, f) : 0.f;
    woffA[i5] = f2bf(v);
  }
}

// ---------- K_prep2: parity-decomposed ct-conv A matrices (fast path only) ----------
// Apar[par][o][tap*128 + i] bf16, par = py*2+px, tap = a*2+b
__global__ void k_prep2(const float* __restrict__ wctT, unsigned short* __restrict__ Apar) {
  int idx = blockIdx.x * 256 + threadIdx.x;   // 262144
  int par = idx >> 16, rem = idx & 65535;
  int o = rem >> 9, rem2 = rem & 511;
  int tap = rem2 >> 7, i = rem2 & 127;
  int py = par >> 1, px = par & 1, a = tap >> 1, bb = tap & 1;
  int kr = (py == 0) ? (a ? 3 : 1) : (a ? 2 : 0);
  int kc = (px == 0) ? (bb ? 3 : 1) : (bb ? 2 : 0);
  Apar[idx] = f2bf(wctT[((size_t)(kr * 4 + kc) * 128 + i) * 128 + o]);
}

// ---------- K_xt: x (NCHW) -> xT[b][h][w][256] bf16 (channel-last) ----------
// grid (64 h, 4 cq, 8 b); 64x64 LDS transpose tile (k_bn1t pattern).
__global__ __launch_bounds__(256) void k_xt(const void* __restrict__ x,
                                            unsigned short* __restrict__ xT) {
  const int f = g_isf32;
  const int h = blockIdx.x, cq = blockIdx.y, b = blockIdx.z;
  const int t = threadIdx.x;
  __shared__ unsigned short T[64][72];
  {
    int cl = t >> 2, q = t & 3;
    size_t base = ((size_t)((b * 256 + cq * 64 + cl) * 64 + h) << 6) + q * 16;
    unsigned short r[16];
    if (f) {
      const float4* p = (const float4*)((const float*)x + base);
      float4 v0 = p[0], v1 = p[1], v2 = p[2], v3 = p[3];
      float vv[16] = {v0.x, v0.y, v0.z, v0.w, v1.x, v1.y, v1.z, v1.w,
                      v2.x, v2.y, v2.z, v2.w, v3.x, v3.y, v3.z, v3.w};
#pragma unroll
      for (int j = 0; j < 16; j++) r[j] = f2bf(vv[j]);
    } else {
      const unsigned short* p = (const unsigned short*)x + base;
      *(uint4*)&r[0] = *(const uint4*)p;
      *(uint4*)&r[8] = *(const uint4*)(p + 8);
    }
    *(uint4*)&T[cl][q * 16]     = *(uint4*)&r[0];
    *(uint4*)&T[cl][q * 16 + 8] = *(uint4*)&r[8];
  }
  __syncthreads();
  {
    int pl = t >> 2, qc = t & 3;
    unsigned short r[16];
#pragma unroll
    for (int j = 0; j < 16; j++) r[j] = T[qc * 16 + j][pl];
    unsigned short* op = xT + ((size_t)((b * 64 + h) * 64 + pl) << 8) + cq * 64 + qc * 16;
    *(uint4*)op       = *(uint4*)&r[0];
    *(uint4*)(op + 8) = *(uint4*)&r[8];
  }
}

// ---------- K1 (fast): offset conv as MFMA GEMM ----------
// om[27][4096] = woffA[32][2304] x im2col(x).  grid (64 h, 8 b), 4 waves.
__global__ __launch_bounds__(256) void k_offmfma(
    const unsigned short* __restrict__ xT,
    const unsigned short* __restrict__ woffA,
    const void* __restrict__ b_off, float* __restrict__ om) {
  const int f = g_isf32;
  const int h = blockIdx.x, b = blockIdx.y;
  const int t = threadIdx.x;
  const int wv = t >> 6, L = t & 63, quad = L >> 4, l15 = L & 15;
  __shared__ unsigned short Bs[3][66][40];   // [row h-1..h+1][w-pad -1..64][ci 32 pad40]
  f32x4 acc[2] = {};
  const int sl = t >> 6, sw = t & 63;        // staging assignment (t<192)

  for (int cq = 0; cq < 8; cq++) {
    __syncthreads();
    if (t < 192) {
      int row = h - 1 + sl;
      uint4 q0 = make_uint4(0, 0, 0, 0), q1 = q0, q2 = q0, q3 = q0;
      if (row >= 0 && row < 64) {
        const unsigned short* src = xT + ((size_t)((b * 64 + row) * 64 + sw) << 8) + cq * 32;
        q0 = *(const uint4*)(src);
        q1 = *(const uint4*)(src + 8);
        q2 = *(const uint4*)(src + 16);
        q3 = *(const uint4*)(src + 24);
      }
      unsigned short* d = &Bs[sl][sw + 1][0];
      *(uint4*)(d)      = q0; *(uint4*)(d + 8)  = q1;
      *(uint4*)(d + 16) = q2; *(uint4*)(d + 24) = q3;
    } else if (t < 198) {
      int idx = t - 192;
      int zs = idx >> 1, zc = (idx & 1) ? 65 : 0;
      unsigned short* d = &Bs[zs][zc][0];
      uint4 z = make_uint4(0, 0, 0, 0);
      *(uint4*)(d) = z; *(uint4*)(d + 8) = z; *(uint4*)(d + 16) = z; *(uint4*)(d + 24) = z;
    }
    __syncthreads();
#pragma unroll
    for (int tap = 0; tap < 9; tap++) {
      const int dy = tap / 3, dx = tap - dy * 3;
      const int kb = tap * 256 + cq * 32 + quad * 8;
      bf16x8 a0 = *(const bf16x8*)(woffA + (size_t)l15 * 2304 + kb);
      bf16x8 a1 = *(const bf16x8*)(woffA + (size_t)(l15 + 16) * 2304 + kb);
      bf16x8 bv = *(const bf16x8*)&Bs[dy][wv * 16 + l15 + dx][quad * 8];
      acc[0] = __builtin_amdgcn_mfma_f32_16x16x32_bf16(a0, bv, acc[0], 0, 0, 0);
      acc[1] = __builtin_amdgcn_mfma_f32_16x16x32_bf16(a1, bv, acc[1], 0, 0, 0);
    }
  }
  const int w = wv * 16 + l15;
#pragma unroll
  for (int tm = 0; tm < 2; tm++) {
#pragma unroll
    for (int r = 0; r < 4; r++) {
      int m = tm * 16 + quad * 4 + r;
      if (m < 27) {
        float bo = ldi(b_off, m, f);
        om[(size_t)((b * 27 + m) * 64 + h) * 64 + w] = acc[tm][r] + bo;
      }
    }
  }
}

// ---------- K1 fallback: 3x3 offset conv, pad 1.  om (8,27,64,64) fp32 ----------
__global__ __launch_bounds__(256) void k_offconv(
    const void* __restrict__ x, const void* __restrict__ b_off,
    const float* __restrict__ woffT, float* __restrict__ om) {
  const int f = g_isf32;
  const int h = blockIdx.x, b = blockIdx.y;
  const int t = threadIdx.x;
  const int cg = t & 31, wg = t >> 5;
  const int w0 = wg * 8;
  __shared__ float xs[32 * 204];
  float acc[8];
#pragma unroll
  for (int i = 0; i < 8; i++) acc[i] = 0.f;

  for (int cb = 0; cb < 256; cb += 32) {
    __syncthreads();
    for (int e = t; e < 32 * 192; e += 256) {
      int ci = e / 192, r = e - ci * 192;
      int dh = r >> 6, w = r & 63;
      int row = h + dh - 1;
      float v = 0.f;
      if (row >= 0 && row < 64)
        v = ldi(x, ((size_t)((b * 256 + cb + ci) * 64 + row) << 6) + w, f);
      xs[ci * 204 + dh * 68 + w + 1] = v;
    }
    for (int e = t; e < 96; e += 256) {
      int base = (e / 3) * 204 + (e - (e / 3) * 3) * 68;
      xs[base] = 0.f; xs[base + 65] = 0.f; xs[base + 66] = 0.f; xs[base + 67] = 0.f;
    }
    __syncthreads();

    for (int ci = 0; ci < 32; ci++) {
      float xr[3][12];
#pragma unroll
      for (int dh = 0; dh < 3; dh++) {
        const float* p = &xs[ci * 204 + dh * 68 + w0];
        float4 q0 = *(const float4*)(p);
        float4 q1 = *(const float4*)(p + 4);
        float4 q2 = *(const float4*)(p + 8);
        xr[dh][0] = q0.x; xr[dh][1] = q0.y; xr[dh][2] = q0.z; xr[dh][3] = q0.w;
        xr[dh][4] = q1.x; xr[dh][5] = q1.y; xr[dh][6] = q1.z; xr[dh][7] = q1.w;
        xr[dh][8] = q2.x; xr[dh][9] = q2.y; xr[dh][10] = q2.z; xr[dh][11] = q2.w;
      }
      if (cg < 27) {
        const float* wp = &woffT[(size_t)(cb + ci) * 243 + cg];
#pragma unroll
        for (int k = 0; k < 9; k++) {
          float wk = wp[k * 27];
          const int dh = k / 3, dx = k - (k / 3) * 3;
#pragma unroll
          for (int wi = 0; wi < 8; wi++)
            acc[wi] = fmaf(wk, xr[dh][wi + dx], acc[wi]);
        }
      }
    }
  }
  if (cg < 27) {
    float bo = ldi(b_off, cg, f);
    float* op = &om[(size_t)((b * 27 + cg) * 64 + h) * 64 + w0];
#pragma unroll
    for (int wi = 0; wi < 8; wi++) op[wi] = acc[wi] + bo;
  }
}

// ---------- K2 (fast): FUSED deformable sampling + MFMA GEMM, K-step 64 ----------
// h1[b](128,4096) = wdcnA(128,2304) x S_virtual(2304,4096).  grid (8 b, 128 nt).
// R9 skeleton (LDS-staged A, reg prefetch between LDS-write and MFMA, 2 barriers
// per step) with K-step doubled to 64: 36 steps, half the barriers/gathers,
// 8 MFMA per barrier.  [2][44] inner pad keeps 2-way LDS bank aliasing.
__global__ __launch_bounds__(256) void k_dcnf(
    const unsigned short* __restrict__ xT,   // [b][64][64][256] bf16
    const unsigned short* __restrict__ A,    // wdcnA [128][2304] bf16
    const float* __restrict__ om,            // [b][27][4096] f32
    const void* __restrict__ b_dcn,
    unsigned short* __restrict__ h1) {       // [b][128][4096] bf16
  const int f = g_isf32;
  const int b = blockIdx.x, nt = blockIdx.y;   // b fastest -> XCD pinning
  const int t = threadIdx.x;
  const int wv = t >> 6, L = t & 63, quad = L >> 4, l15 = L & 15;
  const int wm = wv * 32;                      // wave's 32 output-channel rows
  __shared__ unsigned short As[128][2][44];
  __shared__ unsigned short Bs[32][2][44];
  __shared__ float          Wg[9][32][4];
  __shared__ unsigned short Wi[9][32][4];
  f32x4 acc[2][2] = {};
  const int p0 = nt * 32;

  // precompute per-(tap, pos) bilinear weights + clamped corner indices
  for (int e = t; e < 9 * 32; e += 256) {
    int k = e >> 5, p = e & 31;
    int pos = p0 + p;
    int hh = pos >> 6, ww = pos & 63;
    const float* ob = om + (size_t)(b * 27) * 4096 + pos;
    float oy = ob[(size_t)k * 4096];
    float ox = ob[(size_t)(k + 9) * 4096];
    float mm = ob[(size_t)(k + 18) * 4096];
    float msk = 1.f / (1.f + expf(-mm));
    float py = oy + (float)(hh - 1 + k / 3);
    float px = ox + (float)(ww - 1 + (k - (k / 3) * 3));
    float y0f = floorf(py), x0f = floorf(px);
    float ly = py - y0f, lx = px - x0f;
    int y0 = (int)y0f, x0 = (int)x0f;
    int y1 = y0 + 1, x1 = x0 + 1;
    float fy0 = (y0 >= 0 && y0 < 64) ? 1.f : 0.f;
    float fy1 = (y1 >= 0 && y1 < 64) ? 1.f : 0.f;
    float fx0 = (x0 >= 0 && x0 < 64) ? 1.f : 0.f;
    float fx1 = (x1 >= 0 && x1 < 64) ? 1.f : 0.f;
    int y0c = min(max(y0, 0), 63), y1c = min(max(y1, 0), 63);
    int x0c = min(max(x0, 0), 63), x1c = min(max(x1, 0), 63);
    Wg[k][p][0] = (1.f - ly) * (1.f - lx) * msk * fy0 * fx0;
    Wg[k][p][1] = (1.f - ly) * lx * msk * fy0 * fx1;
    Wg[k][p][2] = ly * (1.f - lx) * msk * fy1 * fx0;
    Wg[k][p][3] = ly * lx * msk * fy1 * fx1;
    Wi[k][p][0] = (unsigned short)(y0c * 64 + x0c);
    Wi[k][p][1] = (unsigned short)(y0c * 64 + x1c);
    Wi[k][p][2] = (unsigned short)(y1c * 64 + x0c);
    Wi[k][p][3] = (unsigned short)(y1c * 64 + x1c);
  }
  __syncthreads();   // Wg/Wi ready before first prefetch

  const unsigned short* xb = xT + ((size_t)b << 20);   // b * 4096 * 256
  const int sp = t >> 3, qc8 = t & 7;                  // pos 0..31, 8-ch segment
  const int ksubB = qc8 >> 2, offB = (qc8 & 3) * 8;
  const int arow = t >> 1, ksubA = t & 1;
  const unsigned short* aprow = A + (size_t)arow * 2304 + ksubA * 32;

  // pipeline registers
  uint4 pa0, pa1, pa2, pa3;
  uint4 pu0, pu1, pu2, pu3;
  float4 pg;

#define DCNF_ISSUE(S) {                                                   \
    int tap_ = (S) >> 2, cq_ = (S) & 3;                                   \
    int kb_ = tap_ * 256 + cq_ * 64;                                      \
    pa0 = *(const uint4*)(aprow + kb_);                                   \
    pa1 = *(const uint4*)(aprow + kb_ + 8);                               \
    pa2 = *(const uint4*)(aprow + kb_ + 16);                              \
    pa3 = *(const uint4*)(aprow + kb_ + 24);                              \
    pg  = *(const float4*)&Wg[tap_][sp][0];                               \
    uint2 wi2_ = *(const uint2*)&Wi[tap_][sp][0];                         \
    int i0_ = wi2_.x & 0xffff, i1_ = wi2_.x >> 16;                        \
    int i2_ = wi2_.y & 0xffff, i3_ = wi2_.y >> 16;                        \
    int cb_ = cq_ * 64 + qc8 * 8;                                         \
    pu0 = *(const uint4*)(xb + ((size_t)i0_ << 8) + cb_);                 \
    pu1 = *(const uint4*)(xb + ((size_t)i1_ << 8) + cb_);                 \
    pu2 = *(const uint4*)(xb + ((size_t)i2_ << 8) + cb_);                 \
    pu3 = *(const uint4*)(xb + ((size_t)i3_ << 8) + cb_);                 \
  }

  DCNF_ISSUE(0);
  for (int s = 0; s < 36; s++) {
    __syncthreads();   // previous MFMA reads done -> LDS writable
    // write A-tile (64B/thread) from prefetch regs
    *(uint4*)&As[arow][ksubA][0]  = pa0;
    *(uint4*)&As[arow][ksubA][8]  = pa1;
    *(uint4*)&As[arow][ksubA][16] = pa2;
    *(uint4*)&As[arow][ksubA][24] = pa3;
    // combine prefetched corners (8 ch) -> Bs
    {
      unsigned short e0[8], e1[8], e2[8], e3[8];
      *(uint4*)e0 = pu0; *(uint4*)e1 = pu1; *(uint4*)e2 = pu2; *(uint4*)e3 = pu3;
      float g0 = pg.x, g1 = pg.y, g2 = pg.z, g3 = pg.w;
      unsigned int r[4];
#pragma unroll
      for (int j = 0; j < 4; j++) {
        float va = g0 * bf2f(e0[2 * j])     + g1 * bf2f(e1[2 * j])
                 + g2 * bf2f(e2[2 * j])     + g3 * bf2f(e3[2 * j]);
        float vb = g0 * bf2f(e0[2 * j + 1]) + g1 * bf2f(e1[2 * j + 1])
                 + g2 * bf2f(e2[2 * j + 1]) + g3 * bf2f(e3[2 * j + 1]);
        r[j] = pk2(va, vb);
      }
      *(uint4*)&Bs[sp][ksubB][offB] = make_uint4(r[0], r[1], r[2], r[3]);
    }
    if (s < 35) DCNF_ISSUE(s + 1);   // prefetch next step (latency hides under MFMA)
    __syncthreads();   // LDS ready
    const int ar = quad * 8;
#pragma unroll
    for (int ks = 0; ks < 2; ks++) {
      bf16x8 af0 = *(const bf16x8*)&As[wm + l15][ks][ar];
      bf16x8 af1 = *(const bf16x8*)&As[wm + 16 + l15][ks][ar];
      bf16x8 b0  = *(const bf16x8*)&Bs[l15][ks][ar];
      bf16x8 b1  = *(const bf16x8*)&Bs[16 + l15][ks][ar];
      acc[0][0] = __builtin_amdgcn_mfma_f32_16x16x32_bf16(af0, b0, acc[0][0], 0, 0, 0);
      acc[0][1] = __builtin_amdgcn_mfma_f32_16x16x32_bf16(af0, b1, acc[0][1], 0, 0, 0);
      acc[1][0] = __builtin_amdgcn_mfma_f32_16x16x32_bf16(af1, b0, acc[1][0], 0, 0, 0);
      acc[1][1] = __builtin_amdgcn_mfma_f32_16x16x32_bf16(af1, b1, acc[1][1], 0, 0, 0);
    }
  }
#undef DCNF_ISSUE

#pragma unroll
  for (int tm = 0; tm < 2; tm++) {
#pragma unroll
    for (int r = 0; r < 4; r++) {
      int m = wm + tm * 16 + quad * 4 + r;
      float bd = ldi(b_dcn, m, f);
#pragma unroll
      for (int tn = 0; tn < 2; tn++) {
        float v = acc[tm][tn][r] + bd;
        int n = p0 + tn * 16 + l15;
        h1[(size_t)(b * 128 + m) * 4096 + n] = f2bf(v);
      }
    }
  }
}

// ---------- K_stats1: per-channel sum/sumsq of h1 -> g_stats[0..255] ----------
__global__ __launch_bounds__(256) void k_stats1(const unsigned short* __restrict__ h1) {
  const int m = blockIdx.x, b = blockIdx.y;
  const int t = threadIdx.x;
  const unsigned short* p = h1 + (size_t)(b * 128 + m) * 4096 + t * 16;
  uint4 q0 = *(const uint4*)p;
  uint4 q1 = *(const uint4*)(p + 8);
  unsigned short e[16];
  *(uint4*)&e[0] = q0; *(uint4*)&e[8] = q1;
  float s = 0.f, q = 0.f;
#pragma unroll
  for (int j = 0; j < 16; j++) { float v = bf2f(e[j]); s += v; q += v * v; }
#pragma unroll
  for (int msk = 1; msk < 64; msk <<= 1) {
    s += __shfl_xor(s, msk, 64);
    q += __shfl_xor(q, msk, 64);
  }
  if ((t & 63) == 0) { atomicAdd(&g_stats[m], s); atomicAdd(&g_stats[128 + m], q); }
}

// ---------- K2 fallback: fused sampling + fp32 GEMM ----------
__global__ __launch_bounds__(256) void k_dcn(
    const void* __restrict__ x, const float* __restrict__ om,
    const float* __restrict__ wdcnT, const void* __restrict__ b_dcn,
    unsigned short* __restrict__ h1) {
  const int f = g_isf32;
  const int h = blockIdx.x, b = blockIdx.y;
  const int t = threadIdx.x;
  __shared__ float S[64 * 64];
  __shared__ int   midx[64][4];
  __shared__ float mwgt[64][4];
  const int og = t >> 4, pg = t & 15;
  const int pA = t & 63, cgA = t >> 6;
  float acc[8][4];
#pragma unroll
  for (int j = 0; j < 8; j++)
#pragma unroll
    for (int i = 0; i < 4; i++) acc[j][i] = 0.f;

  for (int k = 0; k < 9; k++) {
    if (t < 64) {
      const int w = t;
      const float* ob = &om[(size_t)(b * 27) * 4096 + h * 64 + w];
      float oy = ob[(size_t)k * 4096];
      float ox = ob[(size_t)(k + 9) * 4096];
      float mm = ob[(size_t)(k + 18) * 4096];
      float msk = 1.f / (1.f + expf(-mm));
      float py = oy + (float)(h - 1 + k / 3);
      float px = ox + (float)(w - 1 + (k - (k / 3) * 3));
      float y0f = floorf(py), x0f = floorf(px);
      float ly = py - y0f, lx = px - x0f;
      int y0 = (int)y0f, x0 = (int)x0f;
      int y1 = y0 + 1, x1 = x0 + 1;
      float fy0 = (y0 >= 0 && y0 < 64) ? 1.f : 0.f;
      float fy1 = (y1 >= 0 && y1 < 64) ? 1.f : 0.f;
      float fx0 = (x0 >= 0 && x0 < 64) ? 1.f : 0.f;
      float fx1 = (x1 >= 0 && x1 < 64) ? 1.f : 0.f;
      int y0c = min(max(y0, 0), 63), y1c = min(max(y1, 0), 63);
      int x0c = min(max(x0, 0), 63), x1c = min(max(x1, 0), 63);
      midx[w][0] = y0c * 64 + x0c;
      midx[w][1] = y0c * 64 + x1c;
      midx[w][2] = y1c * 64 + x0c;
      midx[w][3] = y1c * 64 + x1c;
      mwgt[w][0] = (1.f - ly) * (1.f - lx) * msk * fy0 * fx0;
      mwgt[w][1] = (1.f - ly) * lx * msk * fy0 * fx1;
      mwgt[w][2] = ly * (1.f - lx) * msk * fy1 * fx0;
      mwgt[w][3] = ly * lx * msk * fy1 * fx1;
    }
    for (int ch = 0; ch < 4; ch++) {
      __syncthreads();
      {
        const int i0 = midx[pA][0], i1 = midx[pA][1], i2 = midx[pA][2], i3 = midx[pA][3];
        const float g0 = mwgt[pA][0], g1 = mwgt[pA][1], g2 = mwgt[pA][2], g3 = mwgt[pA][3];
        const size_t cbase = (size_t)(b * 256 + ch * 64 + cgA * 16) * 4096;
        float* Sp = &S[(cgA * 16) * 64 + pA];
#pragma unroll 4
        for (int j = 0; j < 16; j++) {
          const size_t xo = cbase + (size_t)j * 4096;
          float v = g0 * ldi(x, xo + i0, f) + g1 * ldi(x, xo + i1, f)
                  + g2 * ldi(x, xo + i2, f) + g3 * ldi(x, xo + i3, f);
          Sp[j * 64] = v;
        }
      }
      __syncthreads();
      const float* wk = wdcnT + (size_t)k * 32768 + (size_t)(ch * 64) * 128;
#pragma unroll 2
      for (int c2 = 0; c2 < 64; c2++) {
        float4 a0 = *(const float4*)&wk[c2 * 128 + og * 8];
        float4 a1 = *(const float4*)&wk[c2 * 128 + og * 8 + 4];
        float4 s4 = *(const float4*)&S[c2 * 64 + pg * 4];
        float aa[8] = {a0.x, a0.y, a0.z, a0.w, a1.x, a1.y, a1.z, a1.w};
        float ss[4] = {s4.x, s4.y, s4.z, s4.w};
#pragma unroll
        for (int j = 0; j < 8; j++)
#pragma unroll
          for (int i = 0; i < 4; i++)
            acc[j][i] = fmaf(aa[j], ss[i], acc[j][i]);
      }
    }
  }
#pragma unroll
  for (int j = 0; j < 8; j++) {
    const int o = og * 8 + j;
    float bd = ldi(b_dcn, o, f);
    float v0 = acc[j][0] + bd, v1 = acc[j][1] + bd, v2 = acc[j][2] + bd, v3 = acc[j][3] + bd;
    float s = v0 + v1 + v2 + v3;
    float q = v0 * v0 + v1 * v1 + v2 * v2 + v3 * v3;
    uint2 pkv = make_uint2(pk2(v0, v1), pk2(v2, v3));
    *(uint2*)(h1 + (size_t)((b * 128 + o) * 64 + h) * 64 + pg * 4) = pkv;
#pragma unroll
    for (int m = 1; m < 16; m <<= 1) {
      s += __shfl_xor(s, m, 64);
      q += __shfl_xor(q, m, 64);
    }
    if (pg == 0) { atomicAdd(&g_stats[o], s); atomicAdd(&g_stats[128 + o], q); }
  }
}

// ---------- K3 (fast): BN1 + ReLU + transpose  h1[b][ch][pos] -> h1T[b][pos][ch] ----------
__global__ __launch_bounds__(256) void k_bn1t(
    const unsigned short* __restrict__ h1, const void* __restrict__ g1,
    const void* __restrict__ be1, unsigned short* __restrict__ h1T) {
  const int f = g_isf32;
  const int pt = blockIdx.x, chh = blockIdx.y, b = blockIdx.z;
  const int t = threadIdx.x;
  __shared__ unsigned short T[64][72];
  const int c0 = chh * 64, p0 = pt * 64;
  {
    int cl = t >> 2, q = t & 3;
    int o = c0 + cl;
    float mu = g_stats[o] * (1.f / 32768.f);
    float var = g_stats[128 + o] * (1.f / 32768.f) - mu * mu;
    float sc = rsqrtf(var + 1e-5f) * ldi(g1, o, f);
    float sh = ldi(be1, o, f) - mu * sc;
    const unsigned short* hp = h1 + (size_t)(b * 128 + o) * 4096 + p0 + q * 16;
    uint4 q0 = *(const uint4*)hp, q1 = *(const uint4*)(hp + 8);
    unsigned short e[16], r[16];
    *(uint4*)&e[0] = q0; *(uint4*)&e[8] = q1;
#pragma unroll
    for (int j = 0; j < 16; j++)
      r[j] = f2bf(fmaxf(fmaf(bf2f(e[j]), sc, sh), 0.f));
    *(uint4*)&T[cl][q * 16]     = *(uint4*)&r[0];
    *(uint4*)&T[cl][q * 16 + 8] = *(uint4*)&r[8];
  }
  __syncthreads();
  {
    int pl = t >> 2, qc = t & 3;
    unsigned short r[16];
#pragma unroll
    for (int j = 0; j < 16; j++) r[j] = T[qc * 16 + j][pl];
    unsigned short* op = h1T + (size_t)(b * 4096 + p0 + pl) * 128 + c0 + qc * 16;
    *(uint4*)op       = *(uint4*)&r[0];
    *(uint4*)(op + 8) = *(uint4*)&r[8];
  }
}

// ---------- K3 fallback: BN1 + ReLU in place on h1 ----------
__global__ void k_bn1(unsigned short* __restrict__ h1, const void* __restrict__ g1,
                      const void* __restrict__ be1) {
  const int f = g_isf32;
  int gid = blockIdx.x * 256 + threadIdx.x;
  size_t base = (size_t)gid * 8;
  int o = (int)((base >> 12) & 127);
  float mu = g_stats[o] * (1.f / 32768.f);
  float var = g_stats[128 + o] * (1.f / 32768.f) - mu * mu;
  float sc = rsqrtf(var + 1e-5f) * ldi(g1, o, f);
  float sh = ldi(be1, o, f) - mu * sc;
  uint4 p = *(const uint4*)(h1 + base);
  unsigned int pp[4] = {p.x, p.y, p.z, p.w};
  unsigned int r[4];
#pragma unroll
  for (int i = 0; i < 4; i++) {
    float f0 = fmaxf(fmaf(bf2f((unsigned short)(pp[i] & 0xffff)), sc, sh), 0.f);
    float f1 = fmaxf(fmaf(bf2f((unsigned short)(pp[i] >> 16)), sc, sh), 0.f);
    r[i] = pk2(f0, f1);
  }
  *(uint4*)(h1 + base) = make_uint4(r[0], r[1], r[2], r[3]);
}

// ---------- K4 (fast): parity-decomposed transposed conv as MFMA GEMM, pipelined ----------
// grid (nt=32, par=4, b=8).  Register-prefetch of next step's A/B global loads
// issued right after LDS writes (R9 k_dcnf pattern): L2 latency hides under MFMA.
__global__ __launch_bounds__(256) void k_ctgemm(
    const unsigned short* __restrict__ h1T,  // [b][4096 pos][128 ch]
    const unsigned short* __restrict__ Apar,
    void* __restrict__ out2p) {
  const int f = g_isf32;
  const int nt = blockIdx.x, par = blockIdx.y, b = blockIdx.z;
  const int py = par >> 1, px = par & 1;
  const int t = threadIdx.x;
  const int wv = t >> 6, L = t & 63;
  const int quad = L >> 4, l15 = L & 15;
  const int wm = (wv >> 1) * 64, wn = (wv & 1) * 64;
  __shared__ unsigned short As[128][40];
  __shared__ unsigned short Bs[128][40];
  f32x4 acc[4][4] = {};
  const int y0 = nt * 2;
  const unsigned short* Ap = Apar + (size_t)par * 128 * 512;
  const unsigned short* hb = h1T + (size_t)b * 4096 * 128;
  const int sp = t >> 1, shalf = t & 1;
  const int srr = sp >> 6, sx = sp & 63;
  const int am = t >> 1, aseg = t & 1;

  uint4 pA0, pA1, pB0, pB1;

#define CT_ISSUE(STEP) {                                                  \
    int kk_ = (STEP) * 32;                                                \
    int tap_ = kk_ >> 7, ic_ = kk_ & 127;                                 \
    int a_ = tap_ >> 1, bb_ = tap_ & 1;                                   \
    int ya_ = (py == 0) ? (a_ ? -1 : 0) : (a_ ? 0 : 1);                   \
    int xb_ = (px == 0) ? (bb_ ? -1 : 0) : (bb_ ? 0 : 1);                 \
    const unsigned short* ap_ = Ap + (size_t)am * 512 + kk_ + aseg * 16;  \
    pA0 = *(const uint4*)(ap_);                                           \
    pA1 = *(const uint4*)(ap_ + 8);                                       \
    int srcy_ = y0 + srr + ya_;                                           \
    int srcx_ = sx + xb_;                                                 \
    pB0 = make_uint4(0, 0, 0, 0); pB1 = pB0;                              \
    if (srcy_ >= 0 && srcy_ < 64 && srcx_ >= 0 && srcx_ < 64) {           \
      const unsigned short* hp_ = hb + ((size_t)(srcy_ * 64 + srcx_)) * 128 + ic_ + shalf * 16; \
      pB0 = *(const uint4*)(hp_);                                         \
      pB1 = *(const uint4*)(hp_ + 8);                                     \
    }                                                                     \
  }

  CT_ISSUE(0);
  for (int step = 0; step < 16; step++) {
    __syncthreads();                     // prev MFMA done reading LDS
    *(uint4*)&As[am][aseg * 16]     = pA0;
    *(uint4*)&As[am][aseg * 16 + 8] = pA1;
    *(uint4*)&Bs[sp][shalf * 16]     = pB0;
    *(uint4*)&Bs[sp][shalf * 16 + 8] = pB1;
    if (step < 15) CT_ISSUE(step + 1);   // prefetch; latency hides under MFMA
    __syncthreads();
    const int ar = quad * 8;
    bf16x8 af[4], bfr[4];
#pragma unroll
    for (int tm = 0; tm < 4; tm++) af[tm]  = *(const bf16x8*)&As[wm + tm * 16 + l15][ar];
#pragma unroll
    for (int tn = 0; tn < 4; tn++) bfr[tn] = *(const bf16x8*)&Bs[wn + tn * 16 + l15][ar];
#pragma unroll
    for (int tm = 0; tm < 4; tm++)
#pragma unroll
      for (int tn = 0; tn < 4; tn++)
        acc[tm][tn] = __builtin_amdgcn_mfma_f32_16x16x32_bf16(af[tm], bfr[tn], acc[tm][tn], 0, 0, 0);
  }
#undef CT_ISSUE

  const size_t obase = (size_t)((par * 8 + b) * 128) * 4096;
#pragma unroll
  for (int tm = 0; tm < 4; tm++) {
#pragma unroll
    for (int r = 0; r < 4; r++) {
      int m = wm + tm * 16 + quad * 4 + r;
#pragma unroll
      for (int tn = 0; tn < 4; tn++) {
        float v = acc[tm][tn][r];
        int n = wn + tn * 16 + l15;
        size_t ofs = obase + (size_t)m * 4096 + (size_t)((y0 + (n >> 6)) * 64 + (n & 63));
        if (f) ((float*)out2p)[ofs] = v;
        else   ((unsigned short*)out2p)[ofs] = f2bf(v);
      }
    }
  }
}

// ---------- K_stats2: per-channel sum/sumsq of out2p -> g_stats[256..511] ----------
__global__ __launch_bounds__(256) void k_stats2(const void* __restrict__ out2p) {
  const int f = g_isf32;
  const int m = blockIdx.x, pb = blockIdx.y;
  const int t = threadIdx.x;
  size_t base = ((size_t)pb * 128 + m) * 4096 + (size_t)t * 16;
  float s = 0.f, q = 0.f;
  if (f) {
    const float* p = (const float*)out2p + base;
#pragma unroll
    for (int j = 0; j < 4; j++) {
      float4 v = *(const float4*)(p + j * 4);
      s += v.x + v.y + v.z + v.w;
      q += v.x * v.x + v.y * v.y + v.z * v.z + v.w * v.w;
    }
  } else {
    const unsigned short* p = (const unsigned short*)out2p + base;
    uint4 q0 = *(const uint4*)p, q1 = *(const uint4*)(p + 8);
    unsigned short e[16];
    *(uint4*)&e[0] = q0; *(uint4*)&e[8] = q1;
#pragma unroll
    for (int j = 0; j < 16; j++) { float v = bf2f(e[j]); s += v; q += v * v; }
  }
#pragma unroll
  for (int msk = 1; msk < 64; msk <<= 1) {
    s += __shfl_xor(s, msk, 64);
    q += __shfl_xor(q, msk, 64);
  }
  if ((t & 63) == 0) { atomicAdd(&g_stats[256 + m], s); atomicAdd(&g_stats[384 + m], q); }
}

// ---------- K5 (fast): BN2 + ReLU + parity de-interleave -> d_out ----------
__global__ __launch_bounds__(256) void k_bn2f(
    const void* __restrict__ out2p, const void* __restrict__ g2,
    const void* __restrict__ be2, void* __restrict__ out) {
  const int f = g_isf32;
  const int m = blockIdx.x, b = blockIdx.y;
  const int t = threadIdx.x;
  float mu = g_stats[256 + m] * (1.f / 131072.f);
  float var = g_stats[384 + m] * (1.f / 131072.f) - mu * mu;
  float sc = rsqrtf(var + 1e-5f) * ldi(g2, m, f);
  float sh = ldi(be2, m, f) - mu * sc;
  const int row8 = t >> 3, xseg = t & 7;
  const int xh0 = xseg * 8;
#pragma unroll
  for (int pss = 0; pss < 4; pss++) {
    int yy = pss * 32 + row8;
    int y = yy >> 1, py = yy & 1;
    size_t s0 = ((size_t)((py * 2 + 0) * 8 + b) * 128 + m) * 4096 + (size_t)(y * 64 + xh0);
    size_t s1 = ((size_t)((py * 2 + 1) * 8 + b) * 128 + m) * 4096 + (size_t)(y * 64 + xh0);
    float v0[8], v1[8];
    if (f) {
      const float* p0 = (const float*)out2p + s0;
      const float* p1 = (const float*)out2p + s1;
      float4 a0 = *(const float4*)p0, a1 = *(const float4*)(p0 + 4);
      float4 c0 = *(const float4*)p1, c1 = *(const float4*)(p1 + 4);
      v0[0] = a0.x; v0[1] = a0.y; v0[2] = a0.z; v0[3] = a0.w;
      v0[4] = a1.x; v0[5] = a1.y; v0[6] = a1.z; v0[7] = a1.w;
      v1[0] = c0.x; v1[1] = c0.y; v1[2] = c0.z; v1[3] = c0.w;
      v1[4] = c1.x; v1[5] = c1.y; v1[6] = c1.z; v1[7] = c1.w;
    } else {
      const unsigned short* p0 = (const unsigned short*)out2p + s0;
      const unsigned short* p1 = (const unsigned short*)out2p + s1;
      uint4 u0 = *(const uint4*)p0, u1 = *(const uint4*)p1;
      unsigned short e0[8], e1[8];
      *(uint4*)&e0[0] = u0; *(uint4*)&e1[0] = u1;
#pragma unroll
      for (int j = 0; j < 8; j++) { v0[j] = bf2f(e0[j]); v1[j] = bf2f(e1[j]); }
    }
    float r[16];
#pragma unroll
    for (int i = 0; i < 8; i++) {
      r[2 * i]     = fmaxf(fmaf(v0[i], sc, sh), 0.f);
      r[2 * i + 1] = fmaxf(fmaf(v1[i], sc, sh), 0.f);
    }
    size_t ob = (size_t)(b * 128 + m) * 16384 + (size_t)yy * 128 + (size_t)(xh0 * 2);
    if (f) {
      float* op = (float*)out + ob;
#pragma unroll
      for (int v4 = 0; v4 < 4; v4++)
        ((float4*)op)[v4] = make_float4(r[4 * v4], r[4 * v4 + 1], r[4 * v4 + 2], r[4 * v4 + 3]);
    } else {
      unsigned short* op = (unsigned short*)out + ob;
      unsigned int w_[8];
#pragma unroll
      for (int i = 0; i < 8; i++) w_[i] = pk2(r[2 * i], r[2 * i + 1]);
      *(uint4*)(op)     = make_uint4(w_[0], w_[1], w_[2], w_[3]);
      *(uint4*)(op + 8) = make_uint4(w_[4], w_[5], w_[6], w_[7]);
    }
  }
}

// ---------- K4 fallback: fp32 VALU transposed conv ----------
__global__ __launch_bounds__(256) void k_ctconv(
    const unsigned short* __restrict__ h1n, const float* __restrict__ wctT,
    void* __restrict__ out2) {
  const int f = g_isf32;
  const int y = blockIdx.x, b = blockIdx.y;
  const int t = threadIdx.x;
  const int og = t >> 3, xg = t & 7;
  __shared__ float hs[2 * 32 * 68];
  int kr0, kr1, r0, r1;
  if ((y & 1) == 0) { kr0 = 1; r0 = y >> 1; kr1 = 3; r1 = (y >> 1) - 1; }
  else              { kr0 = 0; r0 = (y + 1) >> 1; kr1 = 2; r1 = (y - 1) >> 1; }
  float acc[4][16];
#pragma unroll
  for (int j = 0; j < 4; j++)
#pragma unroll
    for (int i = 0; i < 16; i++) acc[j][i] = 0.f;

  for (int ihc = 0; ihc < 4; ihc++) {
    __syncthreads();
    for (int e = t; e < 2 * 32 * 64; e += 256) {
      int rr = e >> 11, rem = e & 2047, il = rem >> 6, w = rem & 63;
      int i = ihc * 32 + il;
      int row = rr ? r1 : r0;
      float v = 0.f;
      if (row >= 0 && row < 64)
        v = bf2f(h1n[(size_t)((b * 128 + i) * 64 + row) * 64 + w]);
      hs[(rr * 32 + il) * 68 + w + 1] = v;
    }
    for (int e = t; e < 64; e += 256) {
      int base = e * 68;
      hs[base] = 0.f; hs[base + 65] = 0.f; hs[base + 66] = 0.f; hs[base + 67] = 0.f;
    }
    __syncthreads();
    for (int il = 0; il < 32; il++) {
      const int i = ihc * 32 + il;
      float br[2][12];
#pragma unroll
      for (int rr = 0; rr < 2; rr++) {
        const float* p = &hs[(rr * 32 + il) * 68 + xg * 8];
        float4 q0 = *(const float4*)(p);
        float4 q1 = *(const float4*)(p + 4);
        float4 q2 = *(const float4*)(p + 8);
        br[rr][0] = q0.x; br[rr][1] = q0.y; br[rr][2] = q0.z; br[rr][3] = q0.w;
        br[rr][4] = q1.x; br[rr][5] = q1.y; br[rr][6] = q1.z; br[rr][7] = q1.w;
        br[rr][8] = q2.x; br[rr][9] = q2.y; br[rr][10] = q2.z; br[rr][11] = q2.w;
      }
      float a[2][4][4];
#pragma unroll
      for (int rr = 0; rr < 2; rr++) {
        const int krr = rr ? kr1 : kr0;
#pragma unroll
        for (int kc = 0; kc < 4; kc++) {
          float4 av = *(const float4*)&wctT[((size_t)(krr * 4 + kc) * 128 + i) * 128 + og * 4];
          a[rr][kc][0] = av.x; a[rr][kc][1] = av.y; a[rr][kc][2] = av.z; a[rr][kc][3] = av.w;
        }
      }
#pragma unroll
      for (int xi = 0; xi < 16; xi++) {
        const int u = xi >> 1;
        const int kcA = (xi & 1) ? 0 : 1;
        const int lwA = (xi & 1) ? u + 2 : u + 1;
        const int kcB = (xi & 1) ? 2 : 3;
        const int lwB = (xi & 1) ? u + 1 : u;
#pragma unroll
        for (int rr = 0; rr < 2; rr++) {
#pragma unroll
          for (int j = 0; j < 4; j++) {
            acc[j][xi] = fmaf(a[rr][kcA][j], br[rr][lwA], acc[j][xi]);
            acc[j][xi] = fmaf(a[rr][kcB][j], br[rr][lwB], acc[j][xi]);
          }
        }
      }
    }
  }
#pragma unroll
  for (int j = 0; j < 4; j++) {
    const int o = og * 4 + j;
    float s = 0.f, q = 0.f;
#pragma unroll
    for (int xi = 0; xi < 16; xi++) { s += acc[j][xi]; q += acc[j][xi] * acc[j][xi]; }
    size_t ofs = (size_t)((b * 128 + o) * 128 + y) * 128 + xg * 16;
    if (f) {
      float* op = (float*)out2 + ofs;
#pragma unroll
      for (int v4 = 0; v4 < 4; v4++)
        ((float4*)op)[v4] = make_float4(acc[j][4 * v4], acc[j][4 * v4 + 1],
                                        acc[j][4 * v4 + 2], acc[j][4 * v4 + 3]);
    } else {
      unsigned int w_[8];
#pragma unroll
      for (int xi = 0; xi < 8; xi++) w_[xi] = pk2(acc[j][2 * xi], acc[j][2 * xi + 1]);
      unsigned short* op = (unsigned short*)out2 + ofs;
      *(uint4*)(op)     = make_uint4(w_[0], w_[1], w_[2], w_[3]);
      *(uint4*)(op + 8) = make_uint4(w_[4], w_[5], w_[6], w_[7]);
    }
#pragma unroll
    for (int m = 1; m < 8; m <<= 1) {
      s += __shfl_xor(s, m, 64);
      q += __shfl_xor(q, m, 64);
    }
    if (xg == 0) { atomicAdd(&g_stats[256 + o], s); atomicAdd(&g_stats[384 + o], q); }
  }
}

// ---------- K5 fallback: BN2 + ReLU in place on d_out ----------
__global__ void k_bn2(void* __restrict__ out2, const void* __restrict__ g2,
                      const void* __restrict__ be2) {
  const int f = g_isf32;
  int gid = blockIdx.x * 256 + threadIdx.x;
  size_t base = (size_t)gid * 8;
  int o = (int)((base >> 14) & 127);
  float mu = g_stats[256 + o] * (1.f / 131072.f);
  float var = g_stats[384 + o] * (1.f / 131072.f) - mu * mu;
  float sc = rsqrtf(var + 1e-5f) * ldi(g2, o, f);
  float sh = ldi(be2, o, f) - mu * sc;
  if (f) {
    float4* op = (float4*)out2 + gid * 2;
    float4 p0 = op[0], p1 = op[1];
    p0.x = fmaxf(fmaf(p0.x, sc, sh), 0.f); p0.y = fmaxf(fmaf(p0.y, sc, sh), 0.f);
    p0.z = fmaxf(fmaf(p0.z, sc, sh), 0.f); p0.w = fmaxf(fmaf(p0.w, sc, sh), 0.f);
    p1.x = fmaxf(fmaf(p1.x, sc, sh), 0.f); p1.y = fmaxf(fmaf(p1.y, sc, sh), 0.f);
    p1.z = fmaxf(fmaf(p1.z, sc, sh), 0.f); p1.w = fmaxf(fmaf(p1.w, sc, sh), 0.f);
    op[0] = p0; op[1] = p1;
  } else {
    unsigned short* ob = (unsigned short*)out2 + base;
    uint4 p = *(const uint4*)ob;
    unsigned int pp[4] = {p.x, p.y, p.z, p.w};
    unsigned int r[4];
#pragma unroll
    for (int i = 0; i < 4; i++) {
      float f0 = fmaxf(fmaf(bf2f((unsigned short)(pp[i] & 0xffff)), sc, sh), 0.f);
      float f1 = fmaxf(fmaf(bf2f((unsigned short)(pp[i] >> 16)), sc, sh), 0.f);
      r[i] = pk2(f0, f1);
    }
    *(uint4*)ob = make_uint4(r[0], r[1], r[2], r[3]);
  }
}

// ---------- launch ----------
extern "C" void kernel_launch(void* const* d_in, const int* in_sizes, int n_in,
                              void* d_out, int out_size, void* d_ws, size_t ws_size,
                              hipStream_t stream) {
  const void* x     = d_in[0];
  const void* w_off = d_in[1];
  const void* b_off = d_in[2];
  const void* w_dcn = d_in[3];
  const void* b_dcn = d_in[4];
  const void* g1    = d_in[5];
  const void* be1   = d_in[6];
  const void* w_ct  = d_in[7];
  const void* g2    = d_in[8];
  const void* be2   = d_in[9];

  char* ws = (char*)d_ws;
  const bool fast = ws_size >= (size_t)166000000;

  unsigned short* h1; float* om; float* wdcnT; float* wctT;
  float* woffT; unsigned short* wdcnA; unsigned short* AparB; unsigned short* h1T;
  void* out2p; unsigned short* xT; unsigned short* woffA;
  if (fast) {
    // fully disjoint fast-path layout (~108 MB total, no aliasing)
    xT    = (unsigned short*)(ws + 0);            //  16,777,216
    h1    = (unsigned short*)(ws + 16777216);     //   8,388,608
    h1T   = (unsigned short*)(ws + 25165824);     //   8,388,608
    out2p = (void*)(ws + 33554432);               // <=67,108,864
    om    = (float*)(ws + 100663296);             //   3,538,944
    wctT  = (float*)(ws + 104202240);             //   1,048,576
    AparB = (unsigned short*)(ws + 105250816);    //     524,288
    wdcnA = (unsigned short*)(ws + 105775104);    //     589,824
    woffA = (unsigned short*)(ws + 106364928);    //     147,456
    woffT = (float*)(ws + 106512384);             //     248,832 (k_prep writes; unused fast)
    wdcnT = (float*)(ws + 106761216);             //   1,179,648 (k_prep writes; unused fast)
  } else {
    h1    = (unsigned short*)(ws + 0);
    om    = (float*)(ws + 8388608);
    wdcnT = (float*)(ws + 11927552);
    wctT  = (float*)(ws + 13107200);
    woffT = (float*)(ws + 14155776);
    wdcnA = (unsigned short*)(ws + 14404608);
    woffA = (unsigned short*)(ws + 14994432);
    AparB = nullptr;
    h1T   = nullptr;
    out2p = nullptr;
    xT    = nullptr;
  }

  k_detect<<<dim3(1), 256, 0, stream>>>((const unsigned short*)x);
  k_prep<<<dim3(3859), 256, 0, stream>>>(w_dcn, w_ct, w_off, wdcnT, wctT, woffT, wdcnA, woffA);
  if (fast) {
    k_xt<<<dim3(64, 4, 8), 256, 0, stream>>>(x, xT);
    k_offmfma<<<dim3(64, 8), 256, 0, stream>>>(xT, woffA, b_off, om);
    k_prep2<<<dim3(1024), 256, 0, stream>>>(wctT, AparB);
    k_dcnf<<<dim3(8, 128), 256, 0, stream>>>(xT, wdcnA, om, b_dcn, h1);
    k_stats1<<<dim3(128, 8), 256, 0, stream>>>(h1);
    k_bn1t<<<dim3(64, 2, 8), 256, 0, stream>>>(h1, g1, be1, h1T);
    k_ctgemm<<<dim3(32, 4, 8), 256, 0, stream>>>(h1T, AparB, out2p);
    k_stats2<<<dim3(128, 32), 256, 0, stream>>>(out2p);
    k_bn2f<<<dim3(128, 8), 256, 0, stream>>>(out2p, g2, be2, d_out);
  } else {
    k_offconv<<<dim3(64, 8), 256, 0, stream>>>(x, b_off, woffT, om);
    k_dcn<<<dim3(64, 8), 256, 0, stream>>>(x, om, wdcnT, b_dcn, h1);
    k_bn1<<<dim3(2048), 256, 0, stream>>>(h1, g1, be1);
    k_ctconv<<<dim3(128, 8), 256, 0, stream>>>(h1, wctT, d_out);
    k_bn2<<<dim3(8192), 256, 0, stream>>>(d_out, g2, be2);
  }
}

// Round 13
// 347.026 us; speedup vs baseline: 1.1452x; 1.0011x over previous
//
#include <hip/hip_runtime.h>
#include <stdint.h>

// ---------- device globals: dtype flag + BN stats ----------
__device__ int   g_isf32;
__device__ float g_stats[512];  // [0:128) s1sum, [128:256) s1sq, [256:384) s2sum, [384:512) s2sq

typedef __attribute__((ext_vector_type(8))) short bf16x8;
typedef __attribute__((ext_vector_type(4))) float f32x4;

// ---------- bf16 helpers ----------
__device__ __forceinline__ float bf2f(unsigned short u) {
  union { unsigned int i; float f; } v; v.i = ((unsigned int)u) << 16; return v.f;
}
__device__ __forceinline__ unsigned short f2bf(float f) {
  union { float f; unsigned int i; } v; v.f = f;
  unsigned int r = v.i + 0x7FFFu + ((v.i >> 16) & 1u);
  return (unsigned short)(r >> 16);
}
__device__ __forceinline__ unsigned int pk2(float a, float b) {
  return (unsigned int)f2bf(a) | ((unsigned int)f2bf(b) << 16);
}
// dtype-flex input load: f ? fp32 : bf16
__device__ __forceinline__ float ldi(const void* p, size_t i, int f) {
  return f ? ((const float*)p)[i] : bf2f(((const unsigned short*)p)[i]);
}

// ---------- K0: dtype detector + stats zeroing ----------
__global__ void k_detect(const unsigned short* __restrict__ x) {
  __shared__ int cnt;
  const int t = threadIdx.x;
  if (t == 0) cnt = 0;
  g_stats[t] = 0.f; g_stats[t + 256] = 0.f;
  __syncthreads();
  int c = 0;
  for (int j = 0; j < 16; j++) {
    unsigned short u = x[t * 16 + j];
    int e = (u >> 7) & 0xFF;
    if (e == 0xFF || (e != 0 && e <= 100)) c++;
  }
  atomicAdd(&cnt, c);
  __syncthreads();
  if (t == 0) g_isf32 = (cnt > 256) ? 1 : 0;
}

// ---------- K_prep: weights -> GEMM-friendly layouts ----------
// jobs: wdcnT 294912 | wctT 262144 | woffT 62208 | wdcnA 294912 | woffA 73728
__global__ void k_prep(const void* __restrict__ w_dcn, const void* __restrict__ w_ct,
                       const void* __restrict__ w_off,
                       float* __restrict__ wdcnT, float* __restrict__ wctT,
                       float* __restrict__ woffT, unsigned short* __restrict__ wdcnA,
                       unsigned short* __restrict__ woffA) {
  const int f = g_isf32;
  int idx = blockIdx.x * 256 + threadIdx.x;
  if (idx < 294912) {
    int k = idx / 32768, c = (idx >> 7) & 255, o = idx & 127;
    wdcnT[idx] = ldi(w_dcn, (size_t)(o * 256 + c) * 9 + k, f);
  }
  int i2 = idx - 294912;
  if (i2 >= 0 && i2 < 262144) {
    int kr = i2 >> 16, kc = (i2 >> 14) & 3, i = (i2 >> 7) & 127, o = i2 & 127;
    wctT[i2] = ldi(w_ct, (size_t)((i * 128 + o) * 4 + kr) * 4 + kc, f);
  }
  int i3 = idx - (294912 + 262144);
  if (i3 >= 0 && i3 < 62208) {
    int ci = i3 / 243, r = i3 - ci * 243, k = r / 27, c = r - (r / 27) * 27;
    woffT[i3] = ldi(w_off, (size_t)(c * 256 + ci) * 9 + k, f);
  }
  int i4 = idx - 619264;
  if (i4 >= 0 && i4 < 294912) {
    int o = i4 / 2304, rem = i4 - o * 2304;
    int k = rem >> 8, c = rem & 255;
    wdcnA[i4] = f2bf(ldi(w_dcn, (size_t)(o * 256 + c) * 9 + k, f));
  }
  int i5 = idx - 914176;
  if (i5 >= 0 && i5 < 73728) {       // woffA[m=32][k = tap*256 + ci] bf16, m>=27 zero
    int m = i5 / 2304, r = i5 - m * 2304;
    int tap = r >> 8, ci = r & 255;
    float v = (m < 27) ? ldi(w_off, (size_t)(m * 256 + ci) * 9 + tap, f) : 0.f;
    woffA[i5] = f2bf(v);
  }
}

// ---------- K_prep2: parity-decomposed ct-conv A matrices (fast path only) ----------
// Apar[par][o][tap*128 + i] bf16, par = py*2+px, tap = a*2+b
__global__ void k_prep2(const float* __restrict__ wctT, unsigned short* __restrict__ Apar) {
  int idx = blockIdx.x * 256 + threadIdx.x;   // 262144
  int par = idx >> 16, rem = idx & 65535;
  int o = rem >> 9, rem2 = rem & 511;
  int tap = rem2 >> 7, i = rem2 & 127;
  int py = par >> 1, px = par & 1, a = tap >> 1, bb = tap & 1;
  int kr = (py == 0) ? (a ? 3 : 1) : (a ? 2 : 0);
  int kc = (px == 0) ? (bb ? 3 : 1) : (bb ? 2 : 0);
  Apar[idx] = f2bf(wctT[((size_t)(kr * 4 + kc) * 128 + i) * 128 + o]);
}

// ---------- K_xt: x (NCHW) -> xT[b][h][w][256] bf16 (channel-last) ----------
// grid (64 h, 4 cq, 8 b); 64x64 LDS transpose tile (k_bn1t pattern).
__global__ __launch_bounds__(256) void k_xt(const void* __restrict__ x,
                                            unsigned short* __restrict__ xT) {
  const int f = g_isf32;
  const int h = blockIdx.x, cq = blockIdx.y, b = blockIdx.z;
  const int t = threadIdx.x;
  __shared__ unsigned short T[64][72];
  {
    int cl = t >> 2, q = t & 3;
    size_t base = ((size_t)((b * 256 + cq * 64 + cl) * 64 + h) << 6) + q * 16;
    unsigned short r[16];
    if (f) {
      const float4* p = (const float4*)((const float*)x + base);
      float4 v0 = p[0], v1 = p[1], v2 = p[2], v3 = p[3];
      float vv[16] = {v0.x, v0.y, v0.z, v0.w, v1.x, v1.y, v1.z, v1.w,
                      v2.x, v2.y, v2.z, v2.w, v3.x, v3.y, v3.z, v3.w};
#pragma unroll
      for (int j = 0; j < 16; j++) r[j] = f2bf(vv[j]);
    } else {
      const unsigned short* p = (const unsigned short*)x + base;
      *(uint4*)&r[0] = *(const uint4*)p;
      *(uint4*)&r[8] = *(const uint4*)(p + 8);
    }
    *(uint4*)&T[cl][q * 16]     = *(uint4*)&r[0];
    *(uint4*)&T[cl][q * 16 + 8] = *(uint4*)&r[8];
  }
  __syncthreads();
  {
    int pl = t >> 2, qc = t & 3;
    unsigned short r[16];
#pragma unroll
    for (int j = 0; j < 16; j++) r[j] = T[qc * 16 + j][pl];
    unsigned short* op = xT + ((size_t)((b * 64 + h) * 64 + pl) << 8) + cq * 64 + qc * 16;
    *(uint4*)op       = *(uint4*)&r[0];
    *(uint4*)(op + 8) = *(uint4*)&r[8];
  }
}

// ---------- K1 (fast): offset conv as MFMA GEMM ----------
// om[27][4096] = woffA[32][2304] x im2col(x).  grid (64 h, 8 b), 4 waves.
__global__ __launch_bounds__(256) void k_offmfma(
    const unsigned short* __restrict__ xT,
    const unsigned short* __restrict__ woffA,
    const void* __restrict__ b_off, float* __restrict__ om) {
  const int f = g_isf32;
  const int h = blockIdx.x, b = blockIdx.y;
  const int t = threadIdx.x;
  const int wv = t >> 6, L = t & 63, quad = L >> 4, l15 = L & 15;
  __shared__ unsigned short Bs[3][66][40];   // [row h-1..h+1][w-pad -1..64][ci 32 pad40]
  f32x4 acc[2] = {};
  const int sl = t >> 6, sw = t & 63;        // staging assignment (t<192)

  for (int cq = 0; cq < 8; cq++) {
    __syncthreads();
    if (t < 192) {
      int row = h - 1 + sl;
      uint4 q0 = make_uint4(0, 0, 0, 0), q1 = q0, q2 = q0, q3 = q0;
      if (row >= 0 && row < 64) {
        const unsigned short* src = xT + ((size_t)((b * 64 + row) * 64 + sw) << 8) + cq * 32;
        q0 = *(const uint4*)(src);
        q1 = *(const uint4*)(src + 8);
        q2 = *(const uint4*)(src + 16);
        q3 = *(const uint4*)(src + 24);
      }
      unsigned short* d = &Bs[sl][sw + 1][0];
      *(uint4*)(d)      = q0; *(uint4*)(d + 8)  = q1;
      *(uint4*)(d + 16) = q2; *(uint4*)(d + 24) = q3;
    } else if (t < 198) {
      int idx = t - 192;
      int zs = idx >> 1, zc = (idx & 1) ? 65 : 0;
      unsigned short* d = &Bs[zs][zc][0];
      uint4 z = make_uint4(0, 0, 0, 0);
      *(uint4*)(d) = z; *(uint4*)(d + 8) = z; *(uint4*)(d + 16) = z; *(uint4*)(d + 24) = z;
    }
    __syncthreads();
#pragma unroll
    for (int tap = 0; tap < 9; tap++) {
      const int dy = tap / 3, dx = tap - dy * 3;
      const int kb = tap * 256 + cq * 32 + quad * 8;
      bf16x8 a0 = *(const bf16x8*)(woffA + (size_t)l15 * 2304 + kb);
      bf16x8 a1 = *(const bf16x8*)(woffA + (size_t)(l15 + 16) * 2304 + kb);
      bf16x8 bv = *(const bf16x8*)&Bs[dy][wv * 16 + l15 + dx][quad * 8];
      acc[0] = __builtin_amdgcn_mfma_f32_16x16x32_bf16(a0, bv, acc[0], 0, 0, 0);
      acc[1] = __builtin_amdgcn_mfma_f32_16x16x32_bf16(a1, bv, acc[1], 0, 0, 0);
    }
  }
  const int w = wv * 16 + l15;
#pragma unroll
  for (int tm = 0; tm < 2; tm++) {
#pragma unroll
    for (int r = 0; r < 4; r++) {
      int m = tm * 16 + quad * 4 + r;
      if (m < 27) {
        float bo = ldi(b_off, m, f);
        om[(size_t)((b * 27 + m) * 64 + h) * 64 + w] = acc[tm][r] + bo;
      }
    }
  }
}

// ---------- K1 fallback: 3x3 offset conv, pad 1.  om (8,27,64,64) fp32 ----------
__global__ __launch_bounds__(256) void k_offconv(
    const void* __restrict__ x, const void* __restrict__ b_off,
    const float* __restrict__ woffT, float* __restrict__ om) {
  const int f = g_isf32;
  const int h = blockIdx.x, b = blockIdx.y;
  const int t = threadIdx.x;
  const int cg = t & 31, wg = t >> 5;
  const int w0 = wg * 8;
  __shared__ float xs[32 * 204];
  float acc[8];
#pragma unroll
  for (int i = 0; i < 8; i++) acc[i] = 0.f;

  for (int cb = 0; cb < 256; cb += 32) {
    __syncthreads();
    for (int e = t; e < 32 * 192; e += 256) {
      int ci = e / 192, r = e - ci * 192;
      int dh = r >> 6, w = r & 63;
      int row = h + dh - 1;
      float v = 0.f;
      if (row >= 0 && row < 64)
        v = ldi(x, ((size_t)((b * 256 + cb + ci) * 64 + row) << 6) + w, f);
      xs[ci * 204 + dh * 68 + w + 1] = v;
    }
    for (int e = t; e < 96; e += 256) {
      int base = (e / 3) * 204 + (e - (e / 3) * 3) * 68;
      xs[base] = 0.f; xs[base + 65] = 0.f; xs[base + 66] = 0.f; xs[base + 67] = 0.f;
    }
    __syncthreads();

    for (int ci = 0; ci < 32; ci++) {
      float xr[3][12];
#pragma unroll
      for (int dh = 0; dh < 3; dh++) {
        const float* p = &xs[ci * 204 + dh * 68 + w0];
        float4 q0 = *(const float4*)(p);
        float4 q1 = *(const float4*)(p + 4);
        float4 q2 = *(const float4*)(p + 8);
        xr[dh][0] = q0.x; xr[dh][1] = q0.y; xr[dh][2] = q0.z; xr[dh][3] = q0.w;
        xr[dh][4] = q1.x; xr[dh][5] = q1.y; xr[dh][6] = q1.z; xr[dh][7] = q1.w;
        xr[dh][8] = q2.x; xr[dh][9] = q2.y; xr[dh][10] = q2.z; xr[dh][11] = q2.w;
      }
      if (cg < 27) {
        const float* wp = &woffT[(size_t)(cb + ci) * 243 + cg];
#pragma unroll
        for (int k = 0; k < 9; k++) {
          float wk = wp[k * 27];
          const int dh = k / 3, dx = k - (k / 3) * 3;
#pragma unroll
          for (int wi = 0; wi < 8; wi++)
            acc[wi] = fmaf(wk, xr[dh][wi + dx], acc[wi]);
        }
      }
    }
  }
  if (cg < 27) {
    float bo = ldi(b_off, cg, f);
    float* op = &om[(size_t)((b * 27 + cg) * 64 + h) * 64 + w0];
#pragma unroll
    for (int wi = 0; wi < 8; wi++) op[wi] = acc[wi] + bo;
  }
}

// ---------- K2 (fast): FUSED deformable sampling + MFMA GEMM, K-step 64 ----------
// h1[b](128,4096) = wdcnA(128,2304) x S_virtual(2304,4096).  grid (8 b, 128 nt).
// R9 skeleton (LDS-staged A, reg prefetch between LDS-write and MFMA, 2 barriers
// per step) with K-step 64: 36 steps, 8 MFMA per barrier.  [2][44] pad.
__global__ __launch_bounds__(256) void k_dcnf(
    const unsigned short* __restrict__ xT,   // [b][64][64][256] bf16
    const unsigned short* __restrict__ A,    // wdcnA [128][2304] bf16
    const float* __restrict__ om,            // [b][27][4096] f32
    const void* __restrict__ b_dcn,
    unsigned short* __restrict__ h1) {       // [b][128][4096] bf16
  const int f = g_isf32;
  const int b = blockIdx.x, nt = blockIdx.y;   // b fastest -> XCD pinning
  const int t = threadIdx.x;
  const int wv = t >> 6, L = t & 63, quad = L >> 4, l15 = L & 15;
  const int wm = wv * 32;                      // wave's 32 output-channel rows
  __shared__ unsigned short As[128][2][44];
  __shared__ unsigned short Bs[32][2][44];
  __shared__ float          Wg[9][32][4];
  __shared__ unsigned short Wi[9][32][4];
  f32x4 acc[2][2] = {};
  const int p0 = nt * 32;

  // precompute per-(tap, pos) bilinear weights + clamped corner indices
  for (int e = t; e < 9 * 32; e += 256) {
    int k = e >> 5, p = e & 31;
    int pos = p0 + p;
    int hh = pos >> 6, ww = pos & 63;
    const float* ob = om + (size_t)(b * 27) * 4096 + pos;
    float oy = ob[(size_t)k * 4096];
    float ox = ob[(size_t)(k + 9) * 4096];
    float mm = ob[(size_t)(k + 18) * 4096];
    float msk = 1.f / (1.f + expf(-mm));
    float py = oy + (float)(hh - 1 + k / 3);
    float px = ox + (float)(ww - 1 + (k - (k / 3) * 3));
    float y0f = floorf(py), x0f = floorf(px);
    float ly = py - y0f, lx = px - x0f;
    int y0 = (int)y0f, x0 = (int)x0f;
    int y1 = y0 + 1, x1 = x0 + 1;
    float fy0 = (y0 >= 0 && y0 < 64) ? 1.f : 0.f;
    float fy1 = (y1 >= 0 && y1 < 64) ? 1.f : 0.f;
    float fx0 = (x0 >= 0 && x0 < 64) ? 1.f : 0.f;
    float fx1 = (x1 >= 0 && x1 < 64) ? 1.f : 0.f;
    int y0c = min(max(y0, 0), 63), y1c = min(max(y1, 0), 63);
    int x0c = min(max(x0, 0), 63), x1c = min(max(x1, 0), 63);
    Wg[k][p][0] = (1.f - ly) * (1.f - lx) * msk * fy0 * fx0;
    Wg[k][p][1] = (1.f - ly) * lx * msk * fy0 * fx1;
    Wg[k][p][2] = ly * (1.f - lx) * msk * fy1 * fx0;
    Wg[k][p][3] = ly * lx * msk * fy1 * fx1;
    Wi[k][p][0] = (unsigned short)(y0c * 64 + x0c);
    Wi[k][p][1] = (unsigned short)(y0c * 64 + x1c);
    Wi[k][p][2] = (unsigned short)(y1c * 64 + x0c);
    Wi[k][p][3] = (unsigned short)(y1c * 64 + x1c);
  }
  __syncthreads();   // Wg/Wi ready before first prefetch

  const unsigned short* xb = xT + ((size_t)b << 20);   // b * 4096 * 256
  const int sp = t >> 3, qc8 = t & 7;                  // pos 0..31, 8-ch segment
  const int ksubB = qc8 >> 2, offB = (qc8 & 3) * 8;
  const int arow = t >> 1, ksubA = t & 1;
  const unsigned short* aprow = A + (size_t)arow * 2304 + ksubA * 32;

  // pipeline registers
  uint4 pa0, pa1, pa2, pa3;
  uint4 pu0, pu1, pu2, pu3;
  float4 pg;

#define DCNF_ISSUE(S) {                                                   \
    int tap_ = (S) >> 2, cq_ = (S) & 3;                                   \
    int kb_ = tap_ * 256 + cq_ * 64;                                      \
    pa0 = *(const uint4*)(aprow + kb_);                                   \
    pa1 = *(const uint4*)(aprow + kb_ + 8);                               \
    pa2 = *(const uint4*)(aprow + kb_ + 16);                              \
    pa3 = *(const uint4*)(aprow + kb_ + 24);                              \
    pg  = *(const float4*)&Wg[tap_][sp][0];                               \
    uint2 wi2_ = *(const uint2*)&Wi[tap_][sp][0];                         \
    int i0_ = wi2_.x & 0xffff, i1_ = wi2_.x >> 16;                        \
    int i2_ = wi2_.y & 0xffff, i3_ = wi2_.y >> 16;                        \
    int cb_ = cq_ * 64 + qc8 * 8;                                         \
    pu0 = *(const uint4*)(xb + ((size_t)i0_ << 8) + cb_);                 \
    pu1 = *(const uint4*)(xb + ((size_t)i1_ << 8) + cb_);                 \
    pu2 = *(const uint4*)(xb + ((size_t)i2_ << 8) + cb_);                 \
    pu3 = *(const uint4*)(xb + ((size_t)i3_ << 8) + cb_);                 \
  }

  DCNF_ISSUE(0);
  for (int s = 0; s < 36; s++) {
    __syncthreads();   // previous MFMA reads done -> LDS writable
    // write A-tile (64B/thread) from prefetch regs
    *(uint4*)&As[arow][ksubA][0]  = pa0;
    *(uint4*)&As[arow][ksubA][8]  = pa1;
    *(uint4*)&As[arow][ksubA][16] = pa2;
    *(uint4*)&As[arow][ksubA][24] = pa3;
    // combine prefetched corners (8 ch) -> Bs
    {
      unsigned short e0[8], e1[8], e2[8], e3[8];
      *(uint4*)e0 = pu0; *(uint4*)e1 = pu1; *(uint4*)e2 = pu2; *(uint4*)e3 = pu3;
      float g0 = pg.x, g1 = pg.y, g2 = pg.z, g3 = pg.w;
      unsigned int r[4];
#pragma unroll
      for (int j = 0; j < 4; j++) {
        float va = g0 * bf2f(e0[2 * j])     + g1 * bf2f(e1[2 * j])
                 + g2 * bf2f(e2[2 * j])     + g3 * bf2f(e3[2 * j]);
        float vb = g0 * bf2f(e0[2 * j + 1]) + g1 * bf2f(e1[2 * j + 1])
                 + g2 * bf2f(e2[2 * j + 1]) + g3 * bf2f(e3[2 * j + 1]);
        r[j] = pk2(va, vb);
      }
      *(uint4*)&Bs[sp][ksubB][offB] = make_uint4(r[0], r[1], r[2], r[3]);
    }
    if (s < 35) DCNF_ISSUE(s + 1);   // prefetch next step (latency hides under MFMA)
    __syncthreads();   // LDS ready
    const int ar = quad * 8;
#pragma unroll
    for (int ks = 0; ks < 2; ks++) {
      bf16x8 af0 = *(const bf16x8*)&As[wm + l15][ks][ar];
      bf16x8 af1 = *(const bf16x8*)&As[wm + 16 + l15][ks][ar];
      bf16x8 b0  = *(const bf16x8*)&Bs[l15][ks][ar];
      bf16x8 b1  = *(const bf16x8*)&Bs[16 + l15][ks][ar];
      acc[0][0] = __builtin_amdgcn_mfma_f32_16x16x32_bf16(af0, b0, acc[0][0], 0, 0, 0);
      acc[0][1] = __builtin_amdgcn_mfma_f32_16x16x32_bf16(af0, b1, acc[0][1], 0, 0, 0);
      acc[1][0] = __builtin_amdgcn_mfma_f32_16x16x32_bf16(af1, b0, acc[1][0], 0, 0, 0);
      acc[1][1] = __builtin_amdgcn_mfma_f32_16x16x32_bf16(af1, b1, acc[1][1], 0, 0, 0);
    }
  }
#undef DCNF_ISSUE

#pragma unroll
  for (int tm = 0; tm < 2; tm++) {
#pragma unroll
    for (int r = 0; r < 4; r++) {
      int m = wm + tm * 16 + quad * 4 + r;
      float bd = ldi(b_dcn, m, f);
#pragma unroll
      for (int tn = 0; tn < 2; tn++) {
        float v = acc[tm][tn][r] + bd;
        int n = p0 + tn * 16 + l15;
        h1[(size_t)(b * 128 + m) * 4096 + n] = f2bf(v);
      }
    }
  }
}

// ---------- K_stats1: per-channel sum/sumsq of h1 -> g_stats[0..255] ----------
__global__ __launch_bounds__(256) void k_stats1(const unsigned short* __restrict__ h1) {
  const int m = blockIdx.x, b = blockIdx.y;
  const int t = threadIdx.x;
  const unsigned short* p = h1 + (size_t)(b * 128 + m) * 4096 + t * 16;
  uint4 q0 = *(const uint4*)p;
  uint4 q1 = *(const uint4*)(p + 8);
  unsigned short e[16];
  *(uint4*)&e[0] = q0; *(uint4*)&e[8] = q1;
  float s = 0.f, q = 0.f;
#pragma unroll
  for (int j = 0; j < 16; j++) { float v = bf2f(e[j]); s += v; q += v * v; }
#pragma unroll
  for (int msk = 1; msk < 64; msk <<= 1) {
    s += __shfl_xor(s, msk, 64);
    q += __shfl_xor(q, msk, 64);
  }
  if ((t & 63) == 0) { atomicAdd(&g_stats[m], s); atomicAdd(&g_stats[128 + m], q); }
}

// ---------- K2 fallback: fused sampling + fp32 GEMM ----------
__global__ __launch_bounds__(256) void k_dcn(
    const void* __restrict__ x, const float* __restrict__ om,
    const float* __restrict__ wdcnT, const void* __restrict__ b_dcn,
    unsigned short* __restrict__ h1) {
  const int f = g_isf32;
  const int h = blockIdx.x, b = blockIdx.y;
  const int t = threadIdx.x;
  __shared__ float S[64 * 64];
  __shared__ int   midx[64][4];
  __shared__ float mwgt[64][4];
  const int og = t >> 4, pg = t & 15;
  const int pA = t & 63, cgA = t >> 6;
  float acc[8][4];
#pragma unroll
  for (int j = 0; j < 8; j++)
#pragma unroll
    for (int i = 0; i < 4; i++) acc[j][i] = 0.f;

  for (int k = 0; k < 9; k++) {
    if (t < 64) {
      const int w = t;
      const float* ob = &om[(size_t)(b * 27) * 4096 + h * 64 + w];
      float oy = ob[(size_t)k * 4096];
      float ox = ob[(size_t)(k + 9) * 4096];
      float mm = ob[(size_t)(k + 18) * 4096];
      float msk = 1.f / (1.f + expf(-mm));
      float py = oy + (float)(h - 1 + k / 3);
      float px = ox + (float)(w - 1 + (k - (k / 3) * 3));
      float y0f = floorf(py), x0f = floorf(px);
      float ly = py - y0f, lx = px - x0f;
      int y0 = (int)y0f, x0 = (int)x0f;
      int y1 = y0 + 1, x1 = x0 + 1;
      float fy0 = (y0 >= 0 && y0 < 64) ? 1.f : 0.f;
      float fy1 = (y1 >= 0 && y1 < 64) ? 1.f : 0.f;
      float fx0 = (x0 >= 0 && x0 < 64) ? 1.f : 0.f;
      float fx1 = (x1 >= 0 && x1 < 64) ? 1.f : 0.f;
      int y0c = min(max(y0, 0), 63), y1c = min(max(y1, 0), 63);
      int x0c = min(max(x0, 0), 63), x1c = min(max(x1, 0), 63);
      midx[w][0] = y0c * 64 + x0c;
      midx[w][1] = y0c * 64 + x1c;
      midx[w][2] = y1c * 64 + x0c;
      midx[w][3] = y1c * 64 + x1c;
      mwgt[w][0] = (1.f - ly) * (1.f - lx) * msk * fy0 * fx0;
      mwgt[w][1] = (1.f - ly) * lx * msk * fy0 * fx1;
      mwgt[w][2] = ly * (1.f - lx) * msk * fy1 * fx0;
      mwgt[w][3] = ly * lx * msk * fy1 * fx1;
    }
    for (int ch = 0; ch < 4; ch++) {
      __syncthreads();
      {
        const int i0 = midx[pA][0], i1 = midx[pA][1], i2 = midx[pA][2], i3 = midx[pA][3];
        const float g0 = mwgt[pA][0], g1 = mwgt[pA][1], g2 = mwgt[pA][2], g3 = mwgt[pA][3];
        const size_t cbase = (size_t)(b * 256 + ch * 64 + cgA * 16) * 4096;
        float* Sp = &S[(cgA * 16) * 64 + pA];
#pragma unroll 4
        for (int j = 0; j < 16; j++) {
          const size_t xo = cbase + (size_t)j * 4096;
          float v = g0 * ldi(x, xo + i0, f) + g1 * ldi(x, xo + i1, f)
                  + g2 * ldi(x, xo + i2, f) + g3 * ldi(x, xo + i3, f);
          Sp[j * 64] = v;
        }
      }
      __syncthreads();
      const float* wk = wdcnT + (size_t)k * 32768 + (size_t)(ch * 64) * 128;
#pragma unroll 2
      for (int c2 = 0; c2 < 64; c2++) {
        float4 a0 = *(const float4*)&wk[c2 * 128 + og * 8];
        float4 a1 = *(const float4*)&wk[c2 * 128 + og * 8 + 4];
        float4 s4 = *(const float4*)&S[c2 * 64 + pg * 4];
        float aa[8] = {a0.x, a0.y, a0.z, a0.w, a1.x, a1.y, a1.z, a1.w};
        float ss[4] = {s4.x, s4.y, s4.z, s4.w};
#pragma unroll
        for (int j = 0; j < 8; j++)
#pragma unroll
          for (int i = 0; i < 4; i++)
            acc[j][i] = fmaf(aa[j], ss[i], acc[j][i]);
      }
    }
  }
#pragma unroll
  for (int j = 0; j < 8; j++) {
    const int o = og * 8 + j;
    float bd = ldi(b_dcn, o, f);
    float v0 = acc[j][0] + bd, v1 = acc[j][1] + bd, v2 = acc[j][2] + bd, v3 = acc[j][3] + bd;
    float s = v0 + v1 + v2 + v3;
    float q = v0 * v0 + v1 * v1 + v2 * v2 + v3 * v3;
    uint2 pkv = make_uint2(pk2(v0, v1), pk2(v2, v3));
    *(uint2*)(h1 + (size_t)((b * 128 + o) * 64 + h) * 64 + pg * 4) = pkv;
#pragma unroll
    for (int m = 1; m < 16; m <<= 1) {
      s += __shfl_xor(s, m, 64);
      q += __shfl_xor(q, m, 64);
    }
    if (pg == 0) { atomicAdd(&g_stats[o], s); atomicAdd(&g_stats[128 + o], q); }
  }
}

// ---------- K3 (fast): BN1 + ReLU + transpose  h1[b][ch][pos] -> h1T[b][pos][ch] ----------
__global__ __launch_bounds__(256) void k_bn1t(
    const unsigned short* __restrict__ h1, const void* __restrict__ g1,
    const void* __restrict__ be1, unsigned short* __restrict__ h1T) {
  const int f = g_isf32;
  const int pt = blockIdx.x, chh = blockIdx.y, b = blockIdx.z;
  const int t = threadIdx.x;
  __shared__ unsigned short T[64][72];
  const int c0 = chh * 64, p0 = pt * 64;
  {
    int cl = t >> 2, q = t & 3;
    int o = c0 + cl;
    float mu = g_stats[o] * (1.f / 32768.f);
    float var = g_stats[128 + o] * (1.f / 32768.f) - mu * mu;
    float sc = rsqrtf(var + 1e-5f) * ldi(g1, o, f);
    float sh = ldi(be1, o, f) - mu * sc;
    const unsigned short* hp = h1 + (size_t)(b * 128 + o) * 4096 + p0 + q * 16;
    uint4 q0 = *(const uint4*)hp, q1 = *(const uint4*)(hp + 8);
    unsigned short e[16], r[16];
    *(uint4*)&e[0] = q0; *(uint4*)&e[8] = q1;
#pragma unroll
    for (int j = 0; j < 16; j++)
      r[j] = f2bf(fmaxf(fmaf(bf2f(e[j]), sc, sh), 0.f));
    *(uint4*)&T[cl][q * 16]     = *(uint4*)&r[0];
    *(uint4*)&T[cl][q * 16 + 8] = *(uint4*)&r[8];
  }
  __syncthreads();
  {
    int pl = t >> 2, qc = t & 3;
    unsigned short r[16];
#pragma unroll
    for (int j = 0; j < 16; j++) r[j] = T[qc * 16 + j][pl];
    unsigned short* op = h1T + (size_t)(b * 4096 + p0 + pl) * 128 + c0 + qc * 16;
    *(uint4*)op       = *(uint4*)&r[0];
    *(uint4*)(op + 8) = *(uint4*)&r[8];
  }
}

// ---------- K3 fallback: BN1 + ReLU in place on h1 ----------
__global__ void k_bn1(unsigned short* __restrict__ h1, const void* __restrict__ g1,
                      const void* __restrict__ be1) {
  const int f = g_isf32;
  int gid = blockIdx.x * 256 + threadIdx.x;
  size_t base = (size_t)gid * 8;
  int o = (int)((base >> 12) & 127);
  float mu = g_stats[o] * (1.f / 32768.f);
  float var = g_stats[128 + o] * (1.f / 32768.f) - mu * mu;
  float sc = rsqrtf(var + 1e-5f) * ldi(g1, o, f);
  float sh = ldi(be1, o, f) - mu * sc;
  uint4 p = *(const uint4*)(h1 + base);
  unsigned int pp[4] = {p.x, p.y, p.z, p.w};
  unsigned int r[4];
#pragma unroll
  for (int i = 0; i < 4; i++) {
    float f0 = fmaxf(fmaf(bf2f((unsigned short)(pp[i] & 0xffff)), sc, sh), 0.f);
    float f1 = fmaxf(fmaf(bf2f((unsigned short)(pp[i] >> 16)), sc, sh), 0.f);
    r[i] = pk2(f0, f1);
  }
  *(uint4*)(h1 + base) = make_uint4(r[0], r[1], r[2], r[3]);
}

// ---------- K4 (fast): parity-decomposed transposed conv as MFMA GEMM, K-step 64 ----------
// grid (nt=32, par=4, b=8).  R9 reg-prefetch + R12 K-doubling: 8 steps, 16
// barriers, 32 MFMA per step.  [2][36] pad -> conflict-free ds_read_b128.
__global__ __launch_bounds__(256) void k_ctgemm(
    const unsigned short* __restrict__ h1T,  // [b][4096 pos][128 ch]
    const unsigned short* __restrict__ Apar,
    void* __restrict__ out2p) {
  const int f = g_isf32;
  const int nt = blockIdx.x, par = blockIdx.y, b = blockIdx.z;
  const int py = par >> 1, px = par & 1;
  const int t = threadIdx.x;
  const int wv = t >> 6, L = t & 63;
  const int quad = L >> 4, l15 = L & 15;
  const int wm = (wv >> 1) * 64, wn = (wv & 1) * 64;
  __shared__ unsigned short As[128][2][36];
  __shared__ unsigned short Bs[128][2][36];
  f32x4 acc[4][4] = {};
  const int y0 = nt * 2;
  const unsigned short* Ap = Apar + (size_t)par * 128 * 512;
  const unsigned short* hb = h1T + (size_t)b * 4096 * 128;
  const int sp = t >> 1, shalf = t & 1;   // row 0..127, 32-wide k half
  const int srr = sp >> 6, sx = sp & 63;

  uint4 pA0, pA1, pA2, pA3, pB0, pB1, pB2, pB3;

#define CT_ISSUE(STEP) {                                                  \
    int kk_ = (STEP) * 64;                                                \
    int tap_ = kk_ >> 7, ic_ = kk_ & 127;                                 \
    int a_ = tap_ >> 1, bb_ = tap_ & 1;                                   \
    int ya_ = (py == 0) ? (a_ ? -1 : 0) : (a_ ? 0 : 1);                   \
    int xb_ = (px == 0) ? (bb_ ? -1 : 0) : (bb_ ? 0 : 1);                 \
    const unsigned short* ap_ = Ap + (size_t)sp * 512 + kk_ + shalf * 32; \
    pA0 = *(const uint4*)(ap_);                                           \
    pA1 = *(const uint4*)(ap_ + 8);                                       \
    pA2 = *(const uint4*)(ap_ + 16);                                      \
    pA3 = *(const uint4*)(ap_ + 24);                                      \
    int srcy_ = y0 + srr + ya_;                                           \
    int srcx_ = sx + xb_;                                                 \
    pB0 = make_uint4(0, 0, 0, 0); pB1 = pB0; pB2 = pB0; pB3 = pB0;        \
    if (srcy_ >= 0 && srcy_ < 64 && srcx_ >= 0 && srcx_ < 64) {           \
      const unsigned short* hp_ = hb + ((size_t)(srcy_ * 64 + srcx_)) * 128 + ic_ + shalf * 32; \
      pB0 = *(const uint4*)(hp_);                                         \
      pB1 = *(const uint4*)(hp_ + 8);                                     \
      pB2 = *(const uint4*)(hp_ + 16);                                    \
      pB3 = *(const uint4*)(hp_ + 24);                                    \
    }                                                                     \
  }

  CT_ISSUE(0);
  for (int step = 0; step < 8; step++) {
    __syncthreads();                     // prev MFMA done reading LDS
    *(uint4*)&As[sp][shalf][0]  = pA0;
    *(uint4*)&As[sp][shalf][8]  = pA1;
    *(uint4*)&As[sp][shalf][16] = pA2;
    *(uint4*)&As[sp][shalf][24] = pA3;
    *(uint4*)&Bs[sp][shalf][0]  = pB0;
    *(uint4*)&Bs[sp][shalf][8]  = pB1;
    *(uint4*)&Bs[sp][shalf][16] = pB2;
    *(uint4*)&Bs[sp][shalf][24] = pB3;
    if (step < 7) CT_ISSUE(step + 1);    // prefetch; latency hides under MFMA
    __syncthreads();
    const int ar = quad * 8;
#pragma unroll
    for (int ks = 0; ks < 2; ks++) {
      bf16x8 af[4], bfr[4];
#pragma unroll
      for (int tm = 0; tm < 4; tm++) af[tm]  = *(const bf16x8*)&As[wm + tm * 16 + l15][ks][ar];
#pragma unroll
      for (int tn = 0; tn < 4; tn++) bfr[tn] = *(const bf16x8*)&Bs[wn + tn * 16 + l15][ks][ar];
#pragma unroll
      for (int tm = 0; tm < 4; tm++)
#pragma unroll
        for (int tn = 0; tn < 4; tn++)
          acc[tm][tn] = __builtin_amdgcn_mfma_f32_16x16x32_bf16(af[tm], bfr[tn], acc[tm][tn], 0, 0, 0);
    }
  }
#undef CT_ISSUE

  const size_t obase = (size_t)((par * 8 + b) * 128) * 4096;
#pragma unroll
  for (int tm = 0; tm < 4; tm++) {
#pragma unroll
    for (int r = 0; r < 4; r++) {
      int m = wm + tm * 16 + quad * 4 + r;
#pragma unroll
      for (int tn = 0; tn < 4; tn++) {
        float v = acc[tm][tn][r];
        int n = wn + tn * 16 + l15;
        size_t ofs = obase + (size_t)m * 4096 + (size_t)((y0 + (n >> 6)) * 64 + (n & 63));
        if (f) ((float*)out2p)[ofs] = v;
        else   ((unsigned short*)out2p)[ofs] = f2bf(v);
      }
    }
  }
}

// ---------- K_stats2: per-channel sum/sumsq of out2p -> g_stats[256..511] ----------
__global__ __launch_bounds__(256) void k_stats2(const void* __restrict__ out2p) {
  const int f = g_isf32;
  const int m = blockIdx.x, pb = blockIdx.y;
  const int t = threadIdx.x;
  size_t base = ((size_t)pb * 128 + m) * 4096 + (size_t)t * 16;
  float s = 0.f, q = 0.f;
  if (f) {
    const float* p = (const float*)out2p + base;
#pragma unroll
    for (int j = 0; j < 4; j++) {
      float4 v = *(const float4*)(p + j * 4);
      s += v.x + v.y + v.z + v.w;
      q += v.x * v.x + v.y * v.y + v.z * v.z + v.w * v.w;
    }
  } else {
    const unsigned short* p = (const unsigned short*)out2p + base;
    uint4 q0 = *(const uint4*)p, q1 = *(const uint4*)(p + 8);
    unsigned short e[16];
    *(uint4*)&e[0] = q0; *(uint4*)&e[8] = q1;
#pragma unroll
    for (int j = 0; j < 16; j++) { float v = bf2f(e[j]); s += v; q += v * v; }
  }
#pragma unroll
  for (int msk = 1; msk < 64; msk <<= 1) {
    s += __shfl_xor(s, msk, 64);
    q += __shfl_xor(q, msk, 64);
  }
  if ((t & 63) == 0) { atomicAdd(&g_stats[256 + m], s); atomicAdd(&g_stats[384 + m], q); }
}

// ---------- K5 (fast): BN2 + ReLU + parity de-interleave -> d_out ----------
__global__ __launch_bounds__(256) void k_bn2f(
    const void* __restrict__ out2p, const void* __restrict__ g2,
    const void* __restrict__ be2, void* __restrict__ out) {
  const int f = g_isf32;
  const int m = blockIdx.x, b = blockIdx.y;
  const int t = threadIdx.x;
  float mu = g_stats[256 + m] * (1.f / 131072.f);
  float var = g_stats[384 + m] * (1.f / 131072.f) - mu * mu;
  float sc = rsqrtf(var + 1e-5f) * ldi(g2, m, f);
  float sh = ldi(be2, m, f) - mu * sc;
  const int row8 = t >> 3, xseg = t & 7;
  const int xh0 = xseg * 8;
#pragma unroll
  for (int pss = 0; pss < 4; pss++) {
    int yy = pss * 32 + row8;
    int y = yy >> 1, py = yy & 1;
    size_t s0 = ((size_t)((py * 2 + 0) * 8 + b) * 128 + m) * 4096 + (size_t)(y * 64 + xh0);
    size_t s1 = ((size_t)((py * 2 + 1) * 8 + b) * 128 + m) * 4096 + (size_t)(y * 64 + xh0);
    float v0[8], v1[8];
    if (f) {
      const float* p0 = (const float*)out2p + s0;
      const float* p1 = (const float*)out2p + s1;
      float4 a0 = *(const float4*)p0, a1 = *(const float4*)(p0 + 4);
      float4 c0 = *(const float4*)p1, c1 = *(const float4*)(p1 + 4);
      v0[0] = a0.x; v0[1] = a0.y; v0[2] = a0.z; v0[3] = a0.w;
      v0[4] = a1.x; v0[5] = a1.y; v0[6] = a1.z; v0[7] = a1.w;
      v1[0] = c0.x; v1[1] = c0.y; v1[2] = c0.z; v1[3] = c0.w;
      v1[4] = c1.x; v1[5] = c1.y; v1[6] = c1.z; v1[7] = c1.w;
    } else {
      const unsigned short* p0 = (const unsigned short*)out2p + s0;
      const unsigned short* p1 = (const unsigned short*)out2p + s1;
      uint4 u0 = *(const uint4*)p0, u1 = *(const uint4*)p1;
      unsigned short e0[8], e1[8];
      *(uint4*)&e0[0] = u0; *(uint4*)&e1[0] = u1;
#pragma unroll
      for (int j = 0; j < 8; j++) { v0[j] = bf2f(e0[j]); v1[j] = bf2f(e1[j]); }
    }
    float r[16];
#pragma unroll
    for (int i = 0; i < 8; i++) {
      r[2 * i]     = fmaxf(fmaf(v0[i], sc, sh), 0.f);
      r[2 * i + 1] = fmaxf(fmaf(v1[i], sc, sh), 0.f);
    }
    size_t ob = (size_t)(b * 128 + m) * 16384 + (size_t)yy * 128 + (size_t)(xh0 * 2);
    if (f) {
      float* op = (float*)out + ob;
#pragma unroll
      for (int v4 = 0; v4 < 4; v4++)
        ((float4*)op)[v4] = make_float4(r[4 * v4], r[4 * v4 + 1], r[4 * v4 + 2], r[4 * v4 + 3]);
    } else {
      unsigned short* op = (unsigned short*)out + ob;
      unsigned int w_[8];
#pragma unroll
      for (int i = 0; i < 8; i++) w_[i] = pk2(r[2 * i], r[2 * i + 1]);
      *(uint4*)(op)     = make_uint4(w_[0], w_[1], w_[2], w_[3]);
      *(uint4*)(op + 8) = make_uint4(w_[4], w_[5], w_[6], w_[7]);
    }
  }
}

// ---------- K4 fallback: fp32 VALU transposed conv ----------
__global__ __launch_bounds__(256) void k_ctconv(
    const unsigned short* __restrict__ h1n, const float* __restrict__ wctT,
    void* __restrict__ out2) {
  const int f = g_isf32;
  const int y = blockIdx.x, b = blockIdx.y;
  const int t = threadIdx.x;
  const int og = t >> 3, xg = t & 7;
  __shared__ float hs[2 * 32 * 68];
  int kr0, kr1, r0, r1;
  if ((y & 1) == 0) { kr0 = 1; r0 = y >> 1; kr1 = 3; r1 = (y >> 1) - 1; }
  else              { kr0 = 0; r0 = (y + 1) >> 1; kr1 = 2; r1 = (y - 1) >> 1; }
  float acc[4][16];
#pragma unroll
  for (int j = 0; j < 4; j++)
#pragma unroll
    for (int i = 0; i < 16; i++) acc[j][i] = 0.f;

  for (int ihc = 0; ihc < 4; ihc++) {
    __syncthreads();
    for (int e = t; e < 2 * 32 * 64; e += 256) {
      int rr = e >> 11, rem = e & 2047, il = rem >> 6, w = rem & 63;
      int i = ihc * 32 + il;
      int row = rr ? r1 : r0;
      float v = 0.f;
      if (row >= 0 && row < 64)
        v = bf2f(h1n[(size_t)((b * 128 + i) * 64 + row) * 64 + w]);
      hs[(rr * 32 + il) * 68 + w + 1] = v;
    }
    for (int e = t; e < 64; e += 256) {
      int base = e * 68;
      hs[base] = 0.f; hs[base + 65] = 0.f; hs[base + 66] = 0.f; hs[base + 67] = 0.f;
    }
    __syncthreads();
    for (int il = 0; il < 32; il++) {
      const int i = ihc * 32 + il;
      float br[2][12];
#pragma unroll
      for (int rr = 0; rr < 2; rr++) {
        const float* p = &hs[(rr * 32 + il) * 68 + xg * 8];
        float4 q0 = *(const float4*)(p);
        float4 q1 = *(const float4*)(p + 4);
        float4 q2 = *(const float4*)(p + 8);
        br[rr][0] = q0.x; br[rr][1] = q0.y; br[rr][2] = q0.z; br[rr][3] = q0.w;
        br[rr][4] = q1.x; br[rr][5] = q1.y; br[rr][6] = q1.z; br[rr][7] = q1.w;
        br[rr][8] = q2.x; br[rr][9] = q2.y; br[rr][10] = q2.z; br[rr][11] = q2.w;
      }
      float a[2][4][4];
#pragma unroll
      for (int rr = 0; rr < 2; rr++) {
        const int krr = rr ? kr1 : kr0;
#pragma unroll
        for (int kc = 0; kc < 4; kc++) {
          float4 av = *(const float4*)&wctT[((size_t)(krr * 4 + kc) * 128 + i) * 128 + og * 4];
          a[rr][kc][0] = av.x; a[rr][kc][1] = av.y; a[rr][kc][2] = av.z; a[rr][kc][3] = av.w;
        }
      }
#pragma unroll
      for (int xi = 0; xi < 16; xi++) {
        const int u = xi >> 1;
        const int kcA = (xi & 1) ? 0 : 1;
        const int lwA = (xi & 1) ? u + 2 : u + 1;
        const int kcB = (xi & 1) ? 2 : 3;
        const int lwB = (xi & 1) ? u + 1 : u;
#pragma unroll
        for (int rr = 0; rr < 2; rr++) {
#pragma unroll
          for (int j = 0; j < 4; j++) {
            acc[j][xi] = fmaf(a[rr][kcA][j], br[rr][lwA], acc[j][xi]);
            acc[j][xi] = fmaf(a[rr][kcB][j], br[rr][lwB], acc[j][xi]);
          }
        }
      }
    }
  }
#pragma unroll
  for (int j = 0; j < 4; j++) {
    const int o = og * 4 + j;
    float s = 0.f, q = 0.f;
#pragma unroll
    for (int xi = 0; xi < 16; xi++) { s += acc[j][xi]; q += acc[j][xi] * acc[j][xi]; }
    size_t ofs = (size_t)((b * 128 + o) * 128 + y) * 128 + xg * 16;
    if (f) {
      float* op = (float*)out2 + ofs;
#pragma unroll
      for (int v4 = 0; v4 < 4; v4++)
        ((float4*)op)[v4] = make_float4(acc[j][4 * v4], acc[j][4 * v4 + 1],
                                        acc[j][4 * v4 + 2], acc[j][4 * v4 + 3]);
    } else {
      unsigned int w_[8];
#pragma unroll
      for (int xi = 0; xi < 8; xi++) w_[xi] = pk2(acc[j][2 * xi], acc[j][2 * xi + 1]);
      unsigned short* op = (unsigned short*)out2 + ofs;
      *(uint4*)(op)     = make_uint4(w_[0], w_[1], w_[2], w_[3]);
      *(uint4*)(op + 8) = make_uint4(w_[4], w_[5], w_[6], w_[7]);
    }
#pragma unroll
    for (int m = 1; m < 8; m <<= 1) {
      s += __shfl_xor(s, m, 64);
      q += __shfl_xor(q, m, 64);
    }
    if (xg == 0) { atomicAdd(&g_stats[256 + o], s); atomicAdd(&g_stats[384 + o], q); }
  }
}

// ---------- K5 fallback: BN2 + ReLU in place on d_out ----------
__global__ void k_bn2(void* __restrict__ out2, const void* __restrict__ g2,
                      const void* __restrict__ be2) {
  const int f = g_isf32;
  int gid = blockIdx.x * 256 + threadIdx.x;
  size_t base = (size_t)gid * 8;
  int o = (int)((base >> 14) & 127);
  float mu = g_stats[256 + o] * (1.f / 131072.f);
  float var = g_stats[384 + o] * (1.f / 131072.f) - mu * mu;
  float sc = rsqrtf(var + 1e-5f) * ldi(g2, o, f);
  float sh = ldi(be2, o, f) - mu * sc;
  if (f) {
    float4* op = (float4*)out2 + gid * 2;
    float4 p0 = op[0], p1 = op[1];
    p0.x = fmaxf(fmaf(p0.x, sc, sh), 0.f); p0.y = fmaxf(fmaf(p0.y, sc, sh), 0.f);
    p0.z = fmaxf(fmaf(p0.z, sc, sh), 0.f); p0.w = fmaxf(fmaf(p0.w, sc, sh), 0.f);
    p1.x = fmaxf(fmaf(p1.x, sc, sh), 0.f); p1.y = fmaxf(fmaf(p1.y, sc, sh), 0.f);
    p1.z = fmaxf(fmaf(p1.z, sc, sh), 0.f); p1.w = fmaxf(fmaf(p1.w, sc, sh), 0.f);
    op[0] = p0; op[1] = p1;
  } else {
    unsigned short* ob = (unsigned short*)out2 + base;
    uint4 p = *(const uint4*)ob;
    unsigned int pp[4] = {p.x, p.y, p.z, p.w};
    unsigned int r[4];
#pragma unroll
    for (int i = 0; i < 4; i++) {
      float f0 = fmaxf(fmaf(bf2f((unsigned short)(pp[i] & 0xffff)), sc, sh), 0.f);
      float f1 = fmaxf(fmaf(bf2f((unsigned short)(pp[i] >> 16)), sc, sh), 0.f);
      r[i] = pk2(f0, f1);
    }
    *(uint4*)ob = make_uint4(r[0], r[1], r[2], r[3]);
  }
}

// ---------- launch ----------
extern "C" void kernel_launch(void* const* d_in, const int* in_sizes, int n_in,
                              void* d_out, int out_size, void* d_ws, size_t ws_size,
                              hipStream_t stream) {
  const void* x     = d_in[0];
  const void* w_off = d_in[1];
  const void* b_off = d_in[2];
  const void* w_dcn = d_in[3];
  const void* b_dcn = d_in[4];
  const void* g1    = d_in[5];
  const void* be1   = d_in[6];
  const void* w_ct  = d_in[7];
  const void* g2    = d_in[8];
  const void* be2   = d_in[9];

  char* ws = (char*)d_ws;
  const bool fast = ws_size >= (size_t)166000000;

  unsigned short* h1; float* om; float* wdcnT; float* wctT;
  float* woffT; unsigned short* wdcnA; unsigned short* AparB; unsigned short* h1T;
  void* out2p; unsigned short* xT; unsigned short* woffA;
  if (fast) {
    // fully disjoint fast-path layout (~108 MB total, no aliasing)
    xT    = (unsigned short*)(ws + 0);            //  16,777,216
    h1    = (unsigned short*)(ws + 16777216);     //   8,388,608
    h1T   = (unsigned short*)(ws + 25165824);     //   8,388,608
    out2p = (void*)(ws + 33554432);               // <=67,108,864
    om    = (float*)(ws + 100663296);             //   3,538,944
    wctT  = (float*)(ws + 104202240);             //   1,048,576
    AparB = (unsigned short*)(ws + 105250816);    //     524,288
    wdcnA = (unsigned short*)(ws + 105775104);    //     589,824
    woffA = (unsigned short*)(ws + 106364928);    //     147,456
    woffT = (float*)(ws + 106512384);             //     248,832 (k_prep writes; unused fast)
    wdcnT = (float*)(ws + 106761216);             //   1,179,648 (k_prep writes; unused fast)
  } else {
    h1    = (unsigned short*)(ws + 0);
    om    = (float*)(ws + 8388608);
    wdcnT = (float*)(ws + 11927552);
    wctT  = (float*)(ws + 13107200);
    woffT = (float*)(ws + 14155776);
    wdcnA = (unsigned short*)(ws + 14404608);
    woffA = (unsigned short*)(ws + 14994432);
    AparB = nullptr;
    h1T   = nullptr;
    out2p = nullptr;
    xT    = nullptr;
  }

  k_detect<<<dim3(1), 256, 0, stream>>>((const unsigned short*)x);
  k_prep<<<dim3(3859), 256, 0, stream>>>(w_dcn, w_ct, w_off, wdcnT, wctT, woffT, wdcnA, woffA);
  if (fast) {
    k_xt<<<dim3(64, 4, 8), 256, 0, stream>>>(x, xT);
    k_offmfma<<<dim3(64, 8), 256, 0, stream>>>(xT, woffA, b_off, om);
    k_prep2<<<dim3(1024), 256, 0, stream>>>(wctT, AparB);
    k_dcnf<<<dim3(8, 128), 256, 0, stream>>>(xT, wdcnA, om, b_dcn, h1);
    k_stats1<<<dim3(128, 8), 256, 0, stream>>>(h1);
    k_bn1t<<<dim3(64, 2, 8), 256, 0, stream>>>(h1, g1, be1, h1T);
    k_ctgemm<<<dim3(32, 4, 8), 256, 0, stream>>>(h1T, AparB, out2p);
    k_stats2<<<dim3(128, 32), 256, 0, stream>>>(out2p);
    k_bn2f<<<dim3(128, 8), 256, 0, stream>>>(out2p, g2, be2, d_out);
  } else {
    k_offconv<<<dim3(64, 8), 256, 0, stream>>>(x, b_off, woffT, om);
    k_dcn<<<dim3(64, 8), 256, 0, stream>>>(x, om, wdcnT, b_dcn, h1);
    k_bn1<<<dim3(2048), 256, 0, stream>>>(h1, g1, be1);
    k_ctconv<<<dim3(128, 8), 256, 0, stream>>>(h1, wctT, d_out);
    k_bn2<<<dim3(8192), 256, 0, stream>>>(d_out, g2, be2);
  }
}